// Round 6
// baseline (3766.346 us; speedup 1.0000x reference)
//
#include <hip/hip_runtime.h>
#include <math.h>

#define D_MODEL  4096
#define D_HIDDEN 32768
#define BATCH    2048
#define KSEL     128
#define NDEAD    2048
#define TIECAP   256

typedef short s16x8 __attribute__((ext_vector_type(8)));
typedef float f32x4 __attribute__((ext_vector_type(4)));

// -------------------- helpers --------------------
__device__ __forceinline__ unsigned int fkey(float f) {
    unsigned int u = __float_as_uint(f);
    return (u & 0x80000000u) ? ~u : (u | 0x80000000u);
}
__device__ __forceinline__ unsigned short f2bf(float f) {  // RTNE
    unsigned int u = __float_as_uint(f);
    u += 0x7FFFu + ((u >> 16) & 1u);
    return (unsigned short)(u >> 16);
}
__device__ __forceinline__ float bf2f(unsigned short h) {
    return __uint_as_float(((unsigned int)h) << 16);
}
// per-16-bit-lane order-preserving key transform (packed pair)
__device__ __forceinline__ unsigned int key16x2(unsigned int u) {
    const unsigned int s = (u >> 15) & 0x10001u;
    const unsigned int mask = s * 0xFFFFu;
    return (u ^ mask) | (~mask & 0x80008000u);
}
__device__ __forceinline__ float unkey16(unsigned int k) {  // 16-bit key -> float
    const unsigned int u = (k & 0x8000u) ? (k & 0x7FFFu) : (~k & 0xFFFFu);
    return __uint_as_float(u << 16);
}
__device__ __forceinline__ void async_copy16(void* lds_dst, const void* gsrc) {
    __builtin_amdgcn_global_load_lds(
        (const __attribute__((address_space(1))) unsigned int*)gsrc,
        (__attribute__((address_space(3))) unsigned int*)lds_dst,
        16, 0, 0);
}

// -------------------- LayerNorm (fp64 stats) --------------------
__global__ __launch_bounds__(256) void ln_kernel(const float* __restrict__ x,
        double* __restrict__ mu, double* __restrict__ stdv, double* __restrict__ sinv)
{
    const int row = blockIdx.x;
    const int tid = threadIdx.x;
    const float* xr = x + (size_t)row * D_MODEL;
    float xv[16];
#pragma unroll
    for (int i = 0; i < 16; ++i) xv[i] = xr[tid + 256 * i];
    double s = 0.0;
#pragma unroll
    for (int i = 0; i < 16; ++i) s += (double)xv[i];
    __shared__ double red[4];
    __shared__ double sh_mu;
    const int lane = tid & 63, wid = tid >> 6;
#pragma unroll
    for (int off = 32; off > 0; off >>= 1) s += __shfl_down(s, off, 64);
    if (lane == 0) red[wid] = s;
    __syncthreads();
    if (tid == 0) sh_mu = (red[0] + red[1] + red[2] + red[3]) / (double)D_MODEL;
    __syncthreads();
    const double m = sh_mu;
    double s2 = 0.0;
#pragma unroll
    for (int i = 0; i < 16; ++i) { double d = (double)xv[i] - m; s2 += d * d; }
#pragma unroll
    for (int off = 32; off > 0; off >>= 1) s2 += __shfl_down(s2, off, 64);
    __syncthreads();
    if (lane == 0) red[wid] = s2;
    __syncthreads();
    if (tid == 0) {
        double var = (red[0] + red[1] + red[2] + red[3]) / (double)(D_MODEL - 1);
        double sd = sqrt(var);
        mu[row] = m;
        stdv[row] = sd;
        sinv[row] = 1.0 / (sd + 1e-5);
    }
}

// -------------------- dead-mask scan --------------------
__global__ void dead_scan_kernel(const unsigned char* __restrict__ mask8,
                                 int* __restrict__ dead_idx, int* __restrict__ dead_cnt,
                                 const int* __restrict__ num_dead_in, float* __restrict__ out_last)
{
    const int lane = threadIdx.x; // 64 threads, one wave
    int c = 0;
    for (int j = lane; j < D_HIDDEN; j += 64) c += (mask8[j] != 0);
#pragma unroll
    for (int off = 32; off > 0; off >>= 1) c += __shfl_down(c, off, 64);
    const int total_u8 = __shfl(c, 0, 64);
    const bool u8mode = (total_u8 == NDEAD);
    const int* mask32 = (const int*)mask8;
    int cnt = 0;
    for (int base = 0; base < D_HIDDEN; base += 64) {
        const int j = base + lane;
        const bool d = u8mode ? (mask8[j] != 0) : (mask32[j] != 0);
        const unsigned long long b = __ballot(d);
        const int pre = __popcll(b & ((1ull << lane) - 1ull));
        if (d && (cnt + pre) < NDEAD) dead_idx[cnt + pre] = j;
        cnt += __popcll(b);
    }
    const int cc = cnt > NDEAD ? NDEAD : cnt;
    if (lane == 0) {
        *dead_cnt = cc;
        *out_last = (float)(*num_dead_in);
    }
    for (int t = cc + lane; t < NDEAD; t += 64) dead_idx[t] = 0;
}

// -------------------- A: xc -> bf16 --------------------
__global__ __launch_bounds__(256) void asplit_kernel(
    const float* __restrict__ x, const double* __restrict__ mu, const double* __restrict__ sinv,
    const float* __restrict__ b_pre, unsigned short* __restrict__ Ahp)
{
    const int row = blockIdx.x, tid = threadIdx.x;
    const double m = mu[row], si = sinv[row];
    const float* xr = x + (size_t)row * D_MODEL;
#pragma unroll
    for (int i = 0; i < 4; ++i) {
        const int j = (i * 256 + tid) * 4;
        const float4 xv = *(const float4*)(xr + j);
        const float4 bp = *(const float4*)(b_pre + j);
        float v[4];
        v[0] = (float)(((double)xv.x - m) * si) - bp.x;
        v[1] = (float)(((double)xv.y - m) * si) - bp.y;
        v[2] = (float)(((double)xv.z - m) * si) - bp.z;
        v[3] = (float)(((double)xv.w - m) * si) - bp.w;
        uint2 hw;
        hw.x = (unsigned)f2bf(v[0]) | ((unsigned)f2bf(v[1]) << 16);
        hw.y = (unsigned)f2bf(v[2]) | ((unsigned)f2bf(v[3]) << 16);
        *(uint2*)(Ahp + (size_t)row * D_MODEL + j) = hw;
    }
}

// -------------------- B: w_enc[k][n] -> Bh[n][k] bf16 --------------------
__global__ __launch_bounds__(256) void bsplit_kernel(
    const float* __restrict__ w_enc, unsigned short* __restrict__ Bhp)
{
    __shared__ float t[32][33];
    const int bk = blockIdx.x * 32;
    const int bn = blockIdx.y * 32;
    const int tid = threadIdx.x;
    const int lr = tid >> 3, lc4 = (tid & 7) * 4;
    const float4 v = *(const float4*)(w_enc + (size_t)(bk + lr) * D_HIDDEN + bn + lc4);
    t[lr][lc4 + 0] = v.x; t[lr][lc4 + 1] = v.y; t[lr][lc4 + 2] = v.z; t[lr][lc4 + 3] = v.w;
    __syncthreads();
    float o[4];
#pragma unroll
    for (int j = 0; j < 4; ++j) o[j] = t[lc4 + j][lr];
    uint2 hw;
    hw.x = (unsigned)f2bf(o[0]) | ((unsigned)f2bf(o[1]) << 16);
    hw.y = (unsigned)f2bf(o[2]) | ((unsigned)f2bf(o[3]) << 16);
    *(uint2*)(Bhp + (size_t)(bn + lr) * D_MODEL + bk + lc4) = hw;
}

// -------------------- w_enc transpose to fp32 [n][k] --------------------
__global__ __launch_bounds__(256) void wencT_kernel(
    const float* __restrict__ w_enc, float* __restrict__ wT)
{
    __shared__ float t[32][33];
    const int bk = blockIdx.x * 32;
    const int bn = blockIdx.y * 32;
    const int tid = threadIdx.x;
    const int lr = tid >> 3, lc4 = (tid & 7) * 4;
    const float4 v = *(const float4*)(w_enc + (size_t)(bk + lr) * D_HIDDEN + bn + lc4);
    t[lr][lc4 + 0] = v.x; t[lr][lc4 + 1] = v.y; t[lr][lc4 + 2] = v.z; t[lr][lc4 + 3] = v.w;
    __syncthreads();
    const int j = tid >> 3, i4 = (tid & 7) * 4;
    float4 o;
    o.x = t[i4 + 0][j]; o.y = t[i4 + 1][j]; o.z = t[i4 + 2][j]; o.w = t[i4 + 3][j];
    *(float4*)(wT + (size_t)(bn + j) * D_MODEL + bk + i4) = o;
}

// -------------------- bf16 MFMA GEMM: 128x128 tile, BK=32, LDS dbuf ---------
template<int EPI>
__global__ __launch_bounds__(256) void mm_kernel(
    const unsigned short* __restrict__ A, const unsigned short* __restrict__ B,
    const int kdim, const int ntiles_x,
    const float* __restrict__ bias_n,
    const double* __restrict__ muv, const double* __restrict__ stdvv,
    void* __restrict__ outp, const long ostride)
{
    __shared__ unsigned short lds[2 * 2 * 128 * 32];  // [buf][plane A/B][row][32]
    const int tid = threadIdx.x;
    const int lane = tid & 63, wid = tid >> 6;
    // XCD-aware block swizzle (gridDim.x % 8 == 0)
    const int cpx = gridDim.x >> 3;
    const int orig = blockIdx.x;
    const int wg = (orig & 7) * cpx + (orig >> 3);
    const int m0 = (wg % ntiles_x) * 128;
    const int n0 = (wg / ntiles_x) * 128;
    const int wm = (wid >> 1) * 64, wn = (wid & 1) * 64;
    const int fr = lane & 15, kq = lane >> 4;
    const int swr = (fr >> 1) & 3;                    // read-side quad XOR
    const int qg = (lane & 3) ^ ((lane >> 3) & 3);    // write-side source quad
    const int qo = (kq ^ swr) * 8;

    f32x4 acc[4][4];
#pragma unroll
    for (int i = 0; i < 4; ++i)
#pragma unroll
        for (int j = 0; j < 4; ++j) acc[i][j] = (f32x4){0.f, 0.f, 0.f, 0.f};

    const unsigned short* srcs[4];
    int d0[4];
#pragma unroll
    for (int j = 0; j < 4; ++j) {
        const int s = wid * 4 + j;
        const int pl = s >> 3, sr = s & 7;
        const int r = sr * 16 + (lane >> 2);
        srcs[j] = (pl ? B : A) + (size_t)((pl ? n0 : m0) + r) * kdim + qg * 8;
        d0[j] = pl * 4096 + sr * 512;
    }

    const int NT = kdim >> 5;
#pragma unroll
    for (int j = 0; j < 4; ++j) async_copy16(lds + d0[j], srcs[j]);
    __syncthreads();

    for (int t = 0; t < NT; ++t) {
        const int cur = t & 1;
        if (t + 1 < NT) {
            const int k1 = (t + 1) << 5;
            const int boff = (cur ^ 1) * 8192;
#pragma unroll
            for (int j = 0; j < 4; ++j) async_copy16(lds + boff + d0[j], srcs[j] + k1);
        }
        const unsigned short* la = lds + cur * 8192;
        const unsigned short* lb = la + 4096;
        s16x8 a[4], b[4];
#pragma unroll
        for (int i = 0; i < 4; ++i) {
            a[i] = *(const s16x8*)(la + (wm + i * 16 + fr) * 32 + qo);
            b[i] = *(const s16x8*)(lb + (wn + i * 16 + fr) * 32 + qo);
        }
#pragma unroll
        for (int mi = 0; mi < 4; ++mi)
#pragma unroll
            for (int ni = 0; ni < 4; ++ni)
                acc[mi][ni] = __builtin_amdgcn_mfma_f32_16x16x32_bf16(a[mi], b[ni], acc[mi][ni], 0, 0, 0);
        __syncthreads();
    }

#pragma unroll
    for (int ni = 0; ni < 4; ++ni) {
        const int col = n0 + wn + ni * 16 + fr;
        const float be = bias_n[col];
#pragma unroll
        for (int mi = 0; mi < 4; ++mi) {
            const int rb = m0 + wm + mi * 16 + kq * 4;
            if (EPI == 0) {
                unsigned short* O = (unsigned short*)outp;
#pragma unroll
                for (int r = 0; r < 4; ++r)
                    O[(size_t)(rb + r) * ostride + col] = f2bf(acc[mi][ni][r] + be);
            } else {
                float* O = (float*)outp;
#pragma unroll
                for (int r = 0; r < 4; ++r) {
                    const int m = rb + r;
                    O[(size_t)m * ostride + col] =
                        (acc[mi][ni][r] + be) * (float)stdvv[m] + (float)muv[m];
                }
            }
        }
    }
}

// -------------------- per-row top-128: register-resident keys, parallel scans ----
__global__ __launch_bounds__(256) void topk_kernel(
    const unsigned short* __restrict__ p16,
    const float* __restrict__ x, const double* __restrict__ mu, const double* __restrict__ sinv,
    const float* __restrict__ b_pre, const float* __restrict__ wT, const float* __restrict__ b_enc,
    int* __restrict__ topk_idx, float* __restrict__ topk_val)
{
    const int row = blockIdx.x;
    const int tid = threadIdx.x;
    const int lane = tid & 63, wid = tid >> 6;
    const unsigned short* pr = p16 + (size_t)row * D_HIDDEN;

    __shared__ unsigned int hist[4][256];     // per-wave histogram copies
    __shared__ unsigned int csum[256];
    __shared__ int sh_b1, sh_k16;
    __shared__ unsigned int sh_above;
    __shared__ int sh_sel, sh_tie;
    __shared__ int tie_idx[TIECAP];
    __shared__ double tie_val[TIECAP];
    __shared__ unsigned char tie_sel[TIECAP];

    // load this thread's 128 keys into registers (single global sweep)
    uint4 kr[16];
#pragma unroll
    for (int i = 0; i < 16; ++i) {
        uint4 w = *(const uint4*)(pr + (i * 256 + tid) * 8);
        w.x = key16x2(w.x); w.y = key16x2(w.y); w.z = key16x2(w.z); w.w = key16x2(w.w);
        kr[i] = w;
    }
#pragma unroll
    for (int wv = 0; wv < 4; ++wv) hist[wv][tid] = 0u;
    __syncthreads();
    // pass 1: high byte of key16
#pragma unroll
    for (int i = 0; i < 16; ++i) {
        const unsigned int u[4] = {kr[i].x, kr[i].y, kr[i].z, kr[i].w};
#pragma unroll
        for (int e = 0; e < 4; ++e) {
            atomicAdd(&hist[wid][(u[e] >> 8) & 255u], 1u);
            atomicAdd(&hist[wid][(u[e] >> 24) & 255u], 1u);
        }
    }
    __syncthreads();
    csum[tid] = hist[0][tid] + hist[1][tid] + hist[2][tid] + hist[3][tid];
    __syncthreads();
    // parallel suffix scan: csum[d] = count of keys with high byte >= d
#pragma unroll
    for (int off = 1; off < 256; off <<= 1) {
        const unsigned int v = (tid + off < 256) ? csum[tid + off] : 0u;
        __syncthreads();
        csum[tid] += v;
        __syncthreads();
    }
    if (csum[tid] >= KSEL && (tid == 255 || csum[tid + 1] < KSEL)) {
        sh_b1 = tid;
        sh_above = (tid == 255) ? 0u : csum[tid + 1];
    }
#pragma unroll
    for (int wv = 0; wv < 4; ++wv) hist[wv][tid] = 0u;
    __syncthreads();
    const unsigned int b1 = (unsigned int)sh_b1;
    const unsigned int above = sh_above;
    // pass 2: low byte within bin b1
#pragma unroll
    for (int i = 0; i < 16; ++i) {
        const unsigned int u[4] = {kr[i].x, kr[i].y, kr[i].z, kr[i].w};
#pragma unroll
        for (int e = 0; e < 4; ++e) {
            const unsigned int k0 = u[e] & 0xFFFFu, k1 = u[e] >> 16;
            if ((k0 >> 8) == b1) atomicAdd(&hist[wid][k0 & 255u], 1u);
            if ((k1 >> 8) == b1) atomicAdd(&hist[wid][k1 & 255u], 1u);
        }
    }
    __syncthreads();
    csum[tid] = hist[0][tid] + hist[1][tid] + hist[2][tid] + hist[3][tid];
    __syncthreads();
#pragma unroll
    for (int off = 1; off < 256; off <<= 1) {
        const unsigned int v = (tid + off < 256) ? csum[tid + off] : 0u;
        __syncthreads();
        csum[tid] += v;
        __syncthreads();
    }
    if (above + csum[tid] >= KSEL && (tid == 255 || above + csum[tid + 1] < KSEL)) {
        sh_k16 = (int)((b1 << 8) | (unsigned int)tid);
        sh_sel = 0; sh_tie = 0;
    }
    __syncthreads();
    const unsigned int K16 = (unsigned int)sh_k16;
    const float vc = unkey16(K16);           // approx rank-128 value (bf16 grid)
    const float DLT = 1.3e-2f;               // bounds |p16 - exact| near cutoff
    const float sureT = vc + 2.f * DLT;
    const float candT = vc - 2.f * DLT;
    const unsigned int sK = fkey(sureT) >> 16;
    const unsigned int cK = fkey(candT) >> 16;

    int* oidx = topk_idx + row * KSEL;
    float* oval = topk_val + row * KSEL;
    // classification from register keys
#pragma unroll
    for (int i = 0; i < 16; ++i) {
        const int j0 = (i * 256 + tid) * 8;
        const unsigned int u[4] = {kr[i].x, kr[i].y, kr[i].z, kr[i].w};
#pragma unroll
        for (int e = 0; e < 8; ++e) {
            const unsigned int k = (e & 1) ? (u[e >> 1] >> 16) : (u[e >> 1] & 0xFFFFu);
            if (k < cK) continue;
            const float v = unkey16(k);
            if (k > sK && v > sureT) {
                const int pos = atomicAdd(&sh_sel, 1);
                oidx[pos] = j0 + e;
                oval[pos] = v > 0.f ? v : 0.f;
            } else if (v >= candT) {
                const int t = atomicAdd(&sh_tie, 1);
                if (t < TIECAP) tie_idx[t] = j0 + e;
            }
        }
    }
    __syncthreads();
    const int G = sh_sel;
    int T = sh_tie; if (T > TIECAP) T = TIECAP;
    const int R = KSEL - G;

    // exact fp64 recompute of candidates, wave-parallel, coalesced wT rows
    const double m_ = mu[row], si = sinv[row];
    const float* xr = x + (size_t)row * D_MODEL;
    for (int t = wid; t < T; t += 4) {
        const int col = tie_idx[t];
        const float* wr = wT + (size_t)col * D_MODEL;
        double s = 0.0;
        for (int k = lane * 4; k < D_MODEL; k += 256) {
            const float4 xv = *(const float4*)(xr + k);
            const float4 bp = *(const float4*)(b_pre + k);
            const float4 wv4 = *(const float4*)(wr + k);
            s += (((double)xv.x - m_) * si - (double)bp.x) * (double)wv4.x;
            s += (((double)xv.y - m_) * si - (double)bp.y) * (double)wv4.y;
            s += (((double)xv.z - m_) * si - (double)bp.z) * (double)wv4.z;
            s += (((double)xv.w - m_) * si - (double)bp.w) * (double)wv4.w;
        }
#pragma unroll
        for (int off = 32; off > 0; off >>= 1) s += __shfl_down(s, off, 64);
        if (lane == 0) tie_val[t] = s + (double)b_enc[col];
    }
    __syncthreads();
    if (tid == 0) {
        for (int t = 0; t < T; ++t) tie_sel[t] = 0;
        const int take = R < T ? R : T;
        for (int r = 0; r < take; ++r) {
            int best = -1;
            for (int t = 0; t < T; ++t) {
                if (tie_sel[t]) continue;
                if (best < 0 || tie_val[t] > tie_val[best] ||
                    (tie_val[t] == tie_val[best] && tie_idx[t] < tie_idx[best])) best = t;
            }
            tie_sel[best] = 1;
            const float ev = (float)tie_val[best];
            oidx[G + r] = tie_idx[best];
            oval[G + r] = ev > 0.f ? ev : 0.f;
        }
        for (int r = take; r < R; ++r) { oidx[G + r] = (T > 0) ? tie_idx[0] : 0; oval[G + r] = 0.f; }
    }
}

// -------------------- w_dec -> bf16 row-major copy --------------------
__global__ __launch_bounds__(256) void wdec2bf_kernel(
    const float* __restrict__ w_dec, unsigned short* __restrict__ wd16)
{
    const size_t gid = (size_t)blockIdx.x * 256 + threadIdx.x;
    const size_t base = gid * 8;
    const float4 a = *(const float4*)(w_dec + base);
    const float4 b = *(const float4*)(w_dec + base + 4);
    uint4 o;
    o.x = (unsigned)f2bf(a.x) | ((unsigned)f2bf(a.y) << 16);
    o.y = (unsigned)f2bf(a.z) | ((unsigned)f2bf(a.w) << 16);
    o.z = (unsigned)f2bf(b.x) | ((unsigned)f2bf(b.y) << 16);
    o.w = (unsigned)f2bf(b.z) | ((unsigned)f2bf(b.w) << 16);
    *(uint4*)(wd16 + base) = o;
}

// -------------------- sparse decode: recons (bf16 w_dec) --------------------
__global__ __launch_bounds__(256) void decode_kernel(
    const int* __restrict__ topk_idx, const float* __restrict__ topk_val,
    const unsigned short* __restrict__ wd16, const float* __restrict__ b_pre,
    const double* __restrict__ mu, const double* __restrict__ stdv,
    float* __restrict__ out0)
{
    const int row = blockIdx.x;
    const int tid = threadIdx.x;
    __shared__ int sidx[KSEL];
    __shared__ float sval[KSEL];
    if (tid < KSEL) {
        sidx[tid] = topk_idx[row * KSEL + tid];
        sval[tid] = topk_val[row * KSEL + tid];
    }
    __syncthreads();
    float acc[16];
#pragma unroll
    for (int i = 0; i < 16; ++i) acc[i] = 0.f;
    const int dbase = tid * 16;
    for (int k = 0; k < KSEL; ++k) {
        const float v = sval[k];
        if (v == 0.f) continue;
        const uint4* wr = (const uint4*)(wd16 + (size_t)sidx[k] * D_MODEL + dbase);
        const uint4 w0 = wr[0], w1 = wr[1];
        const unsigned int u[8] = {w0.x, w0.y, w0.z, w0.w, w1.x, w1.y, w1.z, w1.w};
#pragma unroll
        for (int i = 0; i < 8; ++i) {
            acc[2 * i]     += v * __uint_as_float(u[i] << 16);
            acc[2 * i + 1] += v * __uint_as_float(u[i] & 0xFFFF0000u);
        }
    }
    const float st = (float)stdv[row];
    const float mm = (float)mu[row];
    float* o = out0 + (size_t)row * D_MODEL + dbase;
#pragma unroll
    for (int i = 0; i < 16; ++i) {
        o[i] = (acc[i] + b_pre[dbase + i]) * st + mm;
    }
}

// -------------------- aux A gather+relu (bf16 passthrough) --------------------
__global__ __launch_bounds__(256) void auxg_kernel(
    const unsigned short* __restrict__ p16, const int* __restrict__ dead_idx,
    const int* __restrict__ dead_cnt, unsigned short* __restrict__ Ahd)
{
    const int r = blockIdx.x;
    const int tid = threadIdx.x;
    const int dc = *dead_cnt;
#pragma unroll
    for (int i = 0; i < 8; ++i) {
        const int c = i * 256 + tid;
        unsigned short v = 0;
        if (c < dc) {
            const unsigned short u = p16[(size_t)r * D_HIDDEN + dead_idx[c]];
            v = (u & 0x8000u) ? (unsigned short)0 : u;   // relu on bf16 bits
        }
        Ahd[(size_t)r * NDEAD + c] = v;
    }
}

// -------------------- aux B gather+transpose (bf16) --------------------
__global__ __launch_bounds__(256) void auxb_kernel(
    const float* __restrict__ w_dec, const int* __restrict__ dead_idx,
    unsigned short* __restrict__ Bhd)
{
    __shared__ float t[32][33];
    const int k0 = blockIdx.x * 32;
    const int n0 = blockIdx.y * 32;
    const int tid = threadIdx.x;
    const int i = tid >> 3, j4 = (tid & 7) * 4;
    const int srow = dead_idx[k0 + i];
    const float4 v = *(const float4*)(w_dec + (size_t)srow * D_MODEL + n0 + j4);
    t[i][j4 + 0] = v.x; t[i][j4 + 1] = v.y; t[i][j4 + 2] = v.z; t[i][j4 + 3] = v.w;
    __syncthreads();
    const int j = tid >> 3, i4 = (tid & 7) * 4;
    uint2 hw;
    hw.x = (unsigned)f2bf(t[i4 + 0][j]) | ((unsigned)f2bf(t[i4 + 1][j]) << 16);
    hw.y = (unsigned)f2bf(t[i4 + 2][j]) | ((unsigned)f2bf(t[i4 + 3][j]) << 16);
    *(uint2*)(Bhd + (size_t)(n0 + j) * NDEAD + k0 + i4) = hw;
}

// -------------------- launch --------------------
extern "C" void kernel_launch(void* const* d_in, const int* in_sizes, int n_in,
                              void* d_out, int out_size, void* d_ws, size_t ws_size,
                              hipStream_t stream)
{
    (void)in_sizes; (void)n_in; (void)out_size; (void)ws_size;
    const float* x      = (const float*)d_in[0];
    const float* w_enc  = (const float*)d_in[1];
    const float* w_dec  = (const float*)d_in[2];
    const float* b_enc  = (const float*)d_in[3];
    const float* b_pre  = (const float*)d_in[4];
    const unsigned char* dead_mask = (const unsigned char*)d_in[5];
    const int* num_dead = (const int*)d_in[6];
    float* out = (float*)d_out;

    char* base = (char*)d_ws;
    char* w = base;
    auto alloc = [&](size_t bytes) -> char* {
        char* p = w;
        w += (bytes + 255) & ~(size_t)255;
        return p;
    };
    unsigned short* p16 = (unsigned short*)alloc((size_t)BATCH * D_HIDDEN * 2); // 128 MB
    double* mu       = (double*)alloc((size_t)BATCH * 8);
    double* stdv     = (double*)alloc((size_t)BATCH * 8);
    double* sinv     = (double*)alloc((size_t)BATCH * 8);
    int* topk_idx    = (int*)alloc((size_t)BATCH * KSEL * 4);
    float* topk_val  = (float*)alloc((size_t)BATCH * KSEL * 4);
    int* dead_idx    = (int*)alloc((size_t)NDEAD * 4);
    int* dead_cnt    = (int*)alloc(256);
    unsigned short* Ahp = (unsigned short*)alloc((size_t)BATCH * D_MODEL * 2);    // 16 MB
    char* region     = alloc((size_t)D_HIDDEN * D_MODEL * 4);                     // 512 MB

    // time-multiplexed region:
    unsigned short* Bhp = (unsigned short*)region;                 // 256 MB, enc phase
    float* wT   = (float*)region;                                  // 512 MB, topk phase
    unsigned short* wd16 = (unsigned short*)region;                // 256 MB, decode phase
    unsigned short* Bhd  = (unsigned short*)(region + (size_t)D_HIDDEN * D_MODEL * 2); // 16 MB
    unsigned short* Ahd  = Ahp;                                    // 8 MB (Ahp dead after enc)

    float* out0 = out;                                   // recons
    float* out1 = out + (size_t)BATCH * D_MODEL;         // auxk
    float* out_last = out + (size_t)2 * BATCH * D_MODEL; // num_dead

    ln_kernel<<<BATCH, 256, 0, stream>>>(x, mu, stdv, sinv);
    dead_scan_kernel<<<1, 64, 0, stream>>>(dead_mask, dead_idx, dead_cnt, num_dead, out_last);
    asplit_kernel<<<BATCH, 256, 0, stream>>>(x, mu, sinv, b_pre, Ahp);
    bsplit_kernel<<<dim3(D_MODEL / 32, D_HIDDEN / 32), 256, 0, stream>>>(w_enc, Bhp);
    mm_kernel<0><<<(BATCH / 128) * (D_HIDDEN / 128), 256, 0, stream>>>(
        Ahp, Bhp, D_MODEL, BATCH / 128, b_enc, nullptr, nullptr, p16, (long)D_HIDDEN);
    wencT_kernel<<<dim3(D_MODEL / 32, D_HIDDEN / 32), 256, 0, stream>>>(w_enc, wT);
    topk_kernel<<<BATCH, 256, 0, stream>>>(p16, x, mu, sinv, b_pre, wT, b_enc, topk_idx, topk_val);
    auxg_kernel<<<BATCH, 256, 0, stream>>>(p16, dead_idx, dead_cnt, Ahd);
    auxb_kernel<<<dim3(NDEAD / 32, D_MODEL / 32), 256, 0, stream>>>(w_dec, dead_idx, Bhd);
    wdec2bf_kernel<<<(int)(((size_t)D_HIDDEN * D_MODEL) / (256 * 8)), 256, 0, stream>>>(w_dec, wd16);
    decode_kernel<<<BATCH, 256, 0, stream>>>(topk_idx, topk_val, wd16, b_pre, mu, stdv, out0);
    mm_kernel<1><<<(BATCH / 128) * (D_MODEL / 128), 256, 0, stream>>>(
        Ahd, Bhd, NDEAD, BATCH / 128, b_pre, mu, stdv, out1, (long)D_MODEL);
}

// Round 7
// 2841.243 us; speedup vs baseline: 1.3256x; 1.3256x over previous
//
#include <hip/hip_runtime.h>
#include <math.h>

#define D_MODEL  4096
#define D_HIDDEN 32768
#define BATCH    2048
#define KSEL     128
#define NDEAD    2048
#define TIECAP   256

typedef short s16x8 __attribute__((ext_vector_type(8)));
typedef float f32x4 __attribute__((ext_vector_type(4)));

// -------------------- helpers --------------------
__device__ __forceinline__ unsigned int fkey(float f) {
    unsigned int u = __float_as_uint(f);
    return (u & 0x80000000u) ? ~u : (u | 0x80000000u);
}
__device__ __forceinline__ unsigned short f2bf(float f) {  // RTNE
    unsigned int u = __float_as_uint(f);
    u += 0x7FFFu + ((u >> 16) & 1u);
    return (unsigned short)(u >> 16);
}
__device__ __forceinline__ float bf2f(unsigned short h) {
    return __uint_as_float(((unsigned int)h) << 16);
}
// per-16-bit-lane order-preserving key transform (packed pair)
__device__ __forceinline__ unsigned int key16x2(unsigned int u) {
    const unsigned int s = (u >> 15) & 0x10001u;
    const unsigned int mask = s * 0xFFFFu;
    return (u ^ mask) | (~mask & 0x80008000u);
}
__device__ __forceinline__ float unkey16(unsigned int k) {  // 16-bit key -> float
    const unsigned int u = (k & 0x8000u) ? (k & 0x7FFFu) : (~k & 0xFFFFu);
    return __uint_as_float(u << 16);
}
__device__ __forceinline__ void async_copy16(void* lds_dst, const void* gsrc) {
    __builtin_amdgcn_global_load_lds(
        (const __attribute__((address_space(1))) unsigned int*)gsrc,
        (__attribute__((address_space(3))) unsigned int*)lds_dst,
        16, 0, 0);
}

// -------------------- LayerNorm (fp64 stats) --------------------
__global__ __launch_bounds__(256) void ln_kernel(const float* __restrict__ x,
        double* __restrict__ mu, double* __restrict__ stdv, double* __restrict__ sinv)
{
    const int row = blockIdx.x;
    const int tid = threadIdx.x;
    const float* xr = x + (size_t)row * D_MODEL;
    float xv[16];
#pragma unroll
    for (int i = 0; i < 16; ++i) xv[i] = xr[tid + 256 * i];
    double s = 0.0;
#pragma unroll
    for (int i = 0; i < 16; ++i) s += (double)xv[i];
    __shared__ double red[4];
    __shared__ double sh_mu;
    const int lane = tid & 63, wid = tid >> 6;
#pragma unroll
    for (int off = 32; off > 0; off >>= 1) s += __shfl_down(s, off, 64);
    if (lane == 0) red[wid] = s;
    __syncthreads();
    if (tid == 0) sh_mu = (red[0] + red[1] + red[2] + red[3]) / (double)D_MODEL;
    __syncthreads();
    const double m = sh_mu;
    double s2 = 0.0;
#pragma unroll
    for (int i = 0; i < 16; ++i) { double d = (double)xv[i] - m; s2 += d * d; }
#pragma unroll
    for (int off = 32; off > 0; off >>= 1) s2 += __shfl_down(s2, off, 64);
    __syncthreads();
    if (lane == 0) red[wid] = s2;
    __syncthreads();
    if (tid == 0) {
        double var = (red[0] + red[1] + red[2] + red[3]) / (double)(D_MODEL - 1);
        double sd = sqrt(var);
        mu[row] = m;
        stdv[row] = sd;
        sinv[row] = 1.0 / (sd + 1e-5);
    }
}

// -------------------- dead-mask scan --------------------
__global__ void dead_scan_kernel(const unsigned char* __restrict__ mask8,
                                 int* __restrict__ dead_idx, int* __restrict__ dead_cnt,
                                 const int* __restrict__ num_dead_in, float* __restrict__ out_last)
{
    const int lane = threadIdx.x; // 64 threads, one wave
    int c = 0;
    for (int j = lane; j < D_HIDDEN; j += 64) c += (mask8[j] != 0);
#pragma unroll
    for (int off = 32; off > 0; off >>= 1) c += __shfl_down(c, off, 64);
    const int total_u8 = __shfl(c, 0, 64);
    const bool u8mode = (total_u8 == NDEAD);
    const int* mask32 = (const int*)mask8;
    int cnt = 0;
    for (int base = 0; base < D_HIDDEN; base += 64) {
        const int j = base + lane;
        const bool d = u8mode ? (mask8[j] != 0) : (mask32[j] != 0);
        const unsigned long long b = __ballot(d);
        const int pre = __popcll(b & ((1ull << lane) - 1ull));
        if (d && (cnt + pre) < NDEAD) dead_idx[cnt + pre] = j;
        cnt += __popcll(b);
    }
    const int cc = cnt > NDEAD ? NDEAD : cnt;
    if (lane == 0) {
        *dead_cnt = cc;
        *out_last = (float)(*num_dead_in);
    }
    for (int t = cc + lane; t < NDEAD; t += 64) dead_idx[t] = 0;
}

// -------------------- A: xc -> bf16 --------------------
__global__ __launch_bounds__(256) void asplit_kernel(
    const float* __restrict__ x, const double* __restrict__ mu, const double* __restrict__ sinv,
    const float* __restrict__ b_pre, unsigned short* __restrict__ Ahp)
{
    const int row = blockIdx.x, tid = threadIdx.x;
    const double m = mu[row], si = sinv[row];
    const float* xr = x + (size_t)row * D_MODEL;
#pragma unroll
    for (int i = 0; i < 4; ++i) {
        const int j = (i * 256 + tid) * 4;
        const float4 xv = *(const float4*)(xr + j);
        const float4 bp = *(const float4*)(b_pre + j);
        float v[4];
        v[0] = (float)(((double)xv.x - m) * si) - bp.x;
        v[1] = (float)(((double)xv.y - m) * si) - bp.y;
        v[2] = (float)(((double)xv.z - m) * si) - bp.z;
        v[3] = (float)(((double)xv.w - m) * si) - bp.w;
        uint2 hw;
        hw.x = (unsigned)f2bf(v[0]) | ((unsigned)f2bf(v[1]) << 16);
        hw.y = (unsigned)f2bf(v[2]) | ((unsigned)f2bf(v[3]) << 16);
        *(uint2*)(Ahp + (size_t)row * D_MODEL + j) = hw;
    }
}

// -------------------- B: w_enc[k][n] -> Bh[n][k] bf16 --------------------
__global__ __launch_bounds__(256) void bsplit_kernel(
    const float* __restrict__ w_enc, unsigned short* __restrict__ Bhp)
{
    __shared__ float t[32][33];
    const int bk = blockIdx.x * 32;
    const int bn = blockIdx.y * 32;
    const int tid = threadIdx.x;
    const int lr = tid >> 3, lc4 = (tid & 7) * 4;
    const float4 v = *(const float4*)(w_enc + (size_t)(bk + lr) * D_HIDDEN + bn + lc4);
    t[lr][lc4 + 0] = v.x; t[lr][lc4 + 1] = v.y; t[lr][lc4 + 2] = v.z; t[lr][lc4 + 3] = v.w;
    __syncthreads();
    float o[4];
#pragma unroll
    for (int j = 0; j < 4; ++j) o[j] = t[lc4 + j][lr];
    uint2 hw;
    hw.x = (unsigned)f2bf(o[0]) | ((unsigned)f2bf(o[1]) << 16);
    hw.y = (unsigned)f2bf(o[2]) | ((unsigned)f2bf(o[3]) << 16);
    *(uint2*)(Bhp + (size_t)(bn + lr) * D_MODEL + bk + lc4) = hw;
}

// -------------------- w_enc transpose to fp32 [n][k] --------------------
__global__ __launch_bounds__(256) void wencT_kernel(
    const float* __restrict__ w_enc, float* __restrict__ wT)
{
    __shared__ float t[32][33];
    const int bk = blockIdx.x * 32;
    const int bn = blockIdx.y * 32;
    const int tid = threadIdx.x;
    const int lr = tid >> 3, lc4 = (tid & 7) * 4;
    const float4 v = *(const float4*)(w_enc + (size_t)(bk + lr) * D_HIDDEN + bn + lc4);
    t[lr][lc4 + 0] = v.x; t[lr][lc4 + 1] = v.y; t[lr][lc4 + 2] = v.z; t[lr][lc4 + 3] = v.w;
    __syncthreads();
    const int j = tid >> 3, i4 = (tid & 7) * 4;
    float4 o;
    o.x = t[i4 + 0][j]; o.y = t[i4 + 1][j]; o.z = t[i4 + 2][j]; o.w = t[i4 + 3][j];
    *(float4*)(wT + (size_t)(bn + j) * D_MODEL + bk + i4) = o;
}

// -------------------- bf16 MFMA GEMM: 128x128 tile, BK=32, LDS dbuf ---------
template<int EPI>
__global__ __launch_bounds__(256) void mm_kernel(
    const unsigned short* __restrict__ A, const unsigned short* __restrict__ B,
    const int kdim, const int ntiles_x,
    const float* __restrict__ bias_n,
    const double* __restrict__ muv, const double* __restrict__ stdvv,
    void* __restrict__ outp, const long ostride)
{
    __shared__ unsigned short lds[2 * 2 * 128 * 32];  // [buf][plane A/B][row][32]
    const int tid = threadIdx.x;
    const int lane = tid & 63, wid = tid >> 6;
    // XCD-aware block swizzle (gridDim.x % 8 == 0)
    const int cpx = gridDim.x >> 3;
    const int orig = blockIdx.x;
    const int wg = (orig & 7) * cpx + (orig >> 3);
    const int m0 = (wg % ntiles_x) * 128;
    const int n0 = (wg / ntiles_x) * 128;
    const int wm = (wid >> 1) * 64, wn = (wid & 1) * 64;
    const int fr = lane & 15, kq = lane >> 4;
    const int swr = (fr >> 1) & 3;                    // read-side quad XOR
    const int qg = (lane & 3) ^ ((lane >> 3) & 3);    // write-side source quad
    const int qo = (kq ^ swr) * 8;

    f32x4 acc[4][4];
#pragma unroll
    for (int i = 0; i < 4; ++i)
#pragma unroll
        for (int j = 0; j < 4; ++j) acc[i][j] = (f32x4){0.f, 0.f, 0.f, 0.f};

    const unsigned short* srcs[4];
    int d0[4];
#pragma unroll
    for (int j = 0; j < 4; ++j) {
        const int s = wid * 4 + j;
        const int pl = s >> 3, sr = s & 7;
        const int r = sr * 16 + (lane >> 2);
        srcs[j] = (pl ? B : A) + (size_t)((pl ? n0 : m0) + r) * kdim + qg * 8;
        d0[j] = pl * 4096 + sr * 512;
    }

    const int NT = kdim >> 5;
#pragma unroll
    for (int j = 0; j < 4; ++j) async_copy16(lds + d0[j], srcs[j]);
    __syncthreads();

    for (int t = 0; t < NT; ++t) {
        const int cur = t & 1;
        if (t + 1 < NT) {
            const int k1 = (t + 1) << 5;
            const int boff = (cur ^ 1) * 8192;
#pragma unroll
            for (int j = 0; j < 4; ++j) async_copy16(lds + boff + d0[j], srcs[j] + k1);
        }
        const unsigned short* la = lds + cur * 8192;
        const unsigned short* lb = la + 4096;
        s16x8 a[4], b[4];
#pragma unroll
        for (int i = 0; i < 4; ++i) {
            a[i] = *(const s16x8*)(la + (wm + i * 16 + fr) * 32 + qo);
            b[i] = *(const s16x8*)(lb + (wn + i * 16 + fr) * 32 + qo);
        }
#pragma unroll
        for (int mi = 0; mi < 4; ++mi)
#pragma unroll
            for (int ni = 0; ni < 4; ++ni)
                acc[mi][ni] = __builtin_amdgcn_mfma_f32_16x16x32_bf16(a[mi], b[ni], acc[mi][ni], 0, 0, 0);
        __syncthreads();
    }

#pragma unroll
    for (int ni = 0; ni < 4; ++ni) {
        const int col = n0 + wn + ni * 16 + fr;
        const float be = bias_n[col];
#pragma unroll
        for (int mi = 0; mi < 4; ++mi) {
            const int rb = m0 + wm + mi * 16 + kq * 4;
            if (EPI == 0) {
                unsigned short* O = (unsigned short*)outp;
#pragma unroll
                for (int r = 0; r < 4; ++r)
                    O[(size_t)(rb + r) * ostride + col] = f2bf(acc[mi][ni][r] + be);
            } else {
                float* O = (float*)outp;
#pragma unroll
                for (int r = 0; r < 4; ++r) {
                    const int m = rb + r;
                    O[(size_t)m * ostride + col] =
                        (acc[mi][ni][r] + be) * (float)stdvv[m] + (float)muv[m];
                }
            }
        }
    }
}

// -------------------- per-row top-128: register keys + binary-search cutoff ----
__global__ __launch_bounds__(256) void topk_kernel(
    const unsigned short* __restrict__ p16,
    const float* __restrict__ x, const double* __restrict__ mu, const double* __restrict__ sinv,
    const float* __restrict__ b_pre, const float* __restrict__ wT, const float* __restrict__ b_enc,
    int* __restrict__ topk_idx, float* __restrict__ topk_val)
{
    const int row = blockIdx.x;
    const int tid = threadIdx.x;
    const int lane = tid & 63, wid = tid >> 6;
    const unsigned short* pr = p16 + (size_t)row * D_HIDDEN;

    __shared__ int red[4];
    __shared__ int sh_sel, sh_tie;
    __shared__ int tie_idx[TIECAP];
    __shared__ double tie_val[TIECAP];
    __shared__ unsigned char tie_sel[TIECAP];

    // load this thread's 128 keys into registers (single global sweep)
    uint4 kr[16];
#pragma unroll
    for (int i = 0; i < 16; ++i) {
        uint4 w = *(const uint4*)(pr + (i * 256 + tid) * 8);
        w.x = key16x2(w.x); w.y = key16x2(w.y); w.z = key16x2(w.z); w.w = key16x2(w.w);
        kr[i] = w;
    }
    if (tid == 0) { sh_sel = 0; sh_tie = 0; }

    // binary search: smallest t with #(keys > t) < KSEL  -> t = rank-128 key.
    // No histograms, no atomics: branchless register compares + one block reduce per step.
    unsigned int lo = 0, hi = 65535;
    while (lo < hi) {
        const unsigned int mid = (lo + hi) >> 1;
        int c = 0;
#pragma unroll
        for (int i = 0; i < 16; ++i) {
            const unsigned int u[4] = {kr[i].x, kr[i].y, kr[i].z, kr[i].w};
#pragma unroll
            for (int e = 0; e < 4; ++e) {
                c += (int)((u[e] & 0xFFFFu) > mid);
                c += (int)((u[e] >> 16) > mid);
            }
        }
#pragma unroll
        for (int off = 32; off > 0; off >>= 1) c += __shfl_down(c, off, 64);
        if (lane == 0) red[wid] = c;
        __syncthreads();
        const int total = red[0] + red[1] + red[2] + red[3];
        if (total < KSEL) hi = mid; else lo = mid + 1;
        __syncthreads();   // protect red[] before next iteration's write
    }
    const unsigned int K16 = lo;

    const float vc = unkey16(K16);           // rank-128 value on the bf16 grid
    const float DLT = 1.3e-2f;               // bounds |p16 - exact| near cutoff
    const float sureT = vc + 2.f * DLT;
    const float candT = vc - 2.f * DLT;
    const unsigned int sK = fkey(sureT) >> 16;
    const unsigned int cK = fkey(candT) >> 16;

    int* oidx = topk_idx + row * KSEL;
    float* oval = topk_val + row * KSEL;
    // classification from register keys
#pragma unroll
    for (int i = 0; i < 16; ++i) {
        const int j0 = (i * 256 + tid) * 8;
        const unsigned int u[4] = {kr[i].x, kr[i].y, kr[i].z, kr[i].w};
#pragma unroll
        for (int e = 0; e < 8; ++e) {
            const unsigned int k = (e & 1) ? (u[e >> 1] >> 16) : (u[e >> 1] & 0xFFFFu);
            if (k < cK) continue;
            const float v = unkey16(k);
            if (k > sK && v > sureT) {
                const int pos = atomicAdd(&sh_sel, 1);
                oidx[pos] = j0 + e;
                oval[pos] = v > 0.f ? v : 0.f;
            } else if (v >= candT) {
                const int t = atomicAdd(&sh_tie, 1);
                if (t < TIECAP) tie_idx[t] = j0 + e;
            }
        }
    }
    __syncthreads();
    const int G = sh_sel;
    int T = sh_tie; if (T > TIECAP) T = TIECAP;
    const int R = KSEL - G;

    // exact fp64 recompute of candidates, wave-parallel, coalesced wT rows
    const double m_ = mu[row], si = sinv[row];
    const float* xr = x + (size_t)row * D_MODEL;
    for (int t = wid; t < T; t += 4) {
        const int col = tie_idx[t];
        const float* wr = wT + (size_t)col * D_MODEL;
        double s0 = 0.0, s1 = 0.0;
        for (int k = lane * 4; k < D_MODEL; k += 512) {
            {
                const float4 xv = *(const float4*)(xr + k);
                const float4 bp = *(const float4*)(b_pre + k);
                const float4 wv4 = *(const float4*)(wr + k);
                s0 += (((double)xv.x - m_) * si - (double)bp.x) * (double)wv4.x;
                s0 += (((double)xv.y - m_) * si - (double)bp.y) * (double)wv4.y;
                s0 += (((double)xv.z - m_) * si - (double)bp.z) * (double)wv4.z;
                s0 += (((double)xv.w - m_) * si - (double)bp.w) * (double)wv4.w;
            }
            {
                const int k2 = k + 256;
                const float4 xv = *(const float4*)(xr + k2);
                const float4 bp = *(const float4*)(b_pre + k2);
                const float4 wv4 = *(const float4*)(wr + k2);
                s1 += (((double)xv.x - m_) * si - (double)bp.x) * (double)wv4.x;
                s1 += (((double)xv.y - m_) * si - (double)bp.y) * (double)wv4.y;
                s1 += (((double)xv.z - m_) * si - (double)bp.z) * (double)wv4.z;
                s1 += (((double)xv.w - m_) * si - (double)bp.w) * (double)wv4.w;
            }
        }
        double s = s0 + s1;
#pragma unroll
        for (int off = 32; off > 0; off >>= 1) s += __shfl_down(s, off, 64);
        if (lane == 0) tie_val[t] = s + (double)b_enc[col];
    }
    __syncthreads();
    if (tid == 0) {
        for (int t = 0; t < T; ++t) tie_sel[t] = 0;
        const int take = R < T ? R : T;
        for (int r = 0; r < take; ++r) {
            int best = -1;
            for (int t = 0; t < T; ++t) {
                if (tie_sel[t]) continue;
                if (best < 0 || tie_val[t] > tie_val[best] ||
                    (tie_val[t] == tie_val[best] && tie_idx[t] < tie_idx[best])) best = t;
            }
            tie_sel[best] = 1;
            const float ev = (float)tie_val[best];
            oidx[G + r] = tie_idx[best];
            oval[G + r] = ev > 0.f ? ev : 0.f;
        }
        for (int r = take; r < R; ++r) { oidx[G + r] = (T > 0) ? tie_idx[0] : 0; oval[G + r] = 0.f; }
    }
}

// -------------------- w_dec -> bf16 row-major copy --------------------
__global__ __launch_bounds__(256) void wdec2bf_kernel(
    const float* __restrict__ w_dec, unsigned short* __restrict__ wd16)
{
    const size_t gid = (size_t)blockIdx.x * 256 + threadIdx.x;
    const size_t base = gid * 8;
    const float4 a = *(const float4*)(w_dec + base);
    const float4 b = *(const float4*)(w_dec + base + 4);
    uint4 o;
    o.x = (unsigned)f2bf(a.x) | ((unsigned)f2bf(a.y) << 16);
    o.y = (unsigned)f2bf(a.z) | ((unsigned)f2bf(a.w) << 16);
    o.z = (unsigned)f2bf(b.x) | ((unsigned)f2bf(b.y) << 16);
    o.w = (unsigned)f2bf(b.z) | ((unsigned)f2bf(b.w) << 16);
    *(uint4*)(wd16 + base) = o;
}

// -------------------- sparse decode: recons (bf16 w_dec) --------------------
__global__ __launch_bounds__(256) void decode_kernel(
    const int* __restrict__ topk_idx, const float* __restrict__ topk_val,
    const unsigned short* __restrict__ wd16, const float* __restrict__ b_pre,
    const double* __restrict__ mu, const double* __restrict__ stdv,
    float* __restrict__ out0)
{
    const int row = blockIdx.x;
    const int tid = threadIdx.x;
    __shared__ int sidx[KSEL];
    __shared__ float sval[KSEL];
    if (tid < KSEL) {
        sidx[tid] = topk_idx[row * KSEL + tid];
        sval[tid] = topk_val[row * KSEL + tid];
    }
    __syncthreads();
    float acc[16];
#pragma unroll
    for (int i = 0; i < 16; ++i) acc[i] = 0.f;
    const int dbase = tid * 16;
    for (int k = 0; k < KSEL; ++k) {
        const float v = sval[k];
        if (v == 0.f) continue;
        const uint4* wr = (const uint4*)(wd16 + (size_t)sidx[k] * D_MODEL + dbase);
        const uint4 w0 = wr[0], w1 = wr[1];
        const unsigned int u[8] = {w0.x, w0.y, w0.z, w0.w, w1.x, w1.y, w1.z, w1.w};
#pragma unroll
        for (int i = 0; i < 8; ++i) {
            acc[2 * i]     += v * __uint_as_float(u[i] << 16);
            acc[2 * i + 1] += v * __uint_as_float(u[i] & 0xFFFF0000u);
        }
    }
    const float st = (float)stdv[row];
    const float mm = (float)mu[row];
    float* o = out0 + (size_t)row * D_MODEL + dbase;
#pragma unroll
    for (int i = 0; i < 16; ++i) {
        o[i] = (acc[i] + b_pre[dbase + i]) * st + mm;
    }
}

// -------------------- aux A gather+relu (bf16 passthrough) --------------------
__global__ __launch_bounds__(256) void auxg_kernel(
    const unsigned short* __restrict__ p16, const int* __restrict__ dead_idx,
    const int* __restrict__ dead_cnt, unsigned short* __restrict__ Ahd)
{
    const int r = blockIdx.x;
    const int tid = threadIdx.x;
    const int dc = *dead_cnt;
#pragma unroll
    for (int i = 0; i < 8; ++i) {
        const int c = i * 256 + tid;
        unsigned short v = 0;
        if (c < dc) {
            const unsigned short u = p16[(size_t)r * D_HIDDEN + dead_idx[c]];
            v = (u & 0x8000u) ? (unsigned short)0 : u;   // relu on bf16 bits
        }
        Ahd[(size_t)r * NDEAD + c] = v;
    }
}

// -------------------- aux B gather+transpose (bf16) --------------------
__global__ __launch_bounds__(256) void auxb_kernel(
    const float* __restrict__ w_dec, const int* __restrict__ dead_idx,
    unsigned short* __restrict__ Bhd)
{
    __shared__ float t[32][33];
    const int k0 = blockIdx.x * 32;
    const int n0 = blockIdx.y * 32;
    const int tid = threadIdx.x;
    const int i = tid >> 3, j4 = (tid & 7) * 4;
    const int srow = dead_idx[k0 + i];
    const float4 v = *(const float4*)(w_dec + (size_t)srow * D_MODEL + n0 + j4);
    t[i][j4 + 0] = v.x; t[i][j4 + 1] = v.y; t[i][j4 + 2] = v.z; t[i][j4 + 3] = v.w;
    __syncthreads();
    const int j = tid >> 3, i4 = (tid & 7) * 4;
    uint2 hw;
    hw.x = (unsigned)f2bf(t[i4 + 0][j]) | ((unsigned)f2bf(t[i4 + 1][j]) << 16);
    hw.y = (unsigned)f2bf(t[i4 + 2][j]) | ((unsigned)f2bf(t[i4 + 3][j]) << 16);
    *(uint2*)(Bhd + (size_t)(n0 + j) * NDEAD + k0 + i4) = hw;
}

// -------------------- launch --------------------
extern "C" void kernel_launch(void* const* d_in, const int* in_sizes, int n_in,
                              void* d_out, int out_size, void* d_ws, size_t ws_size,
                              hipStream_t stream)
{
    (void)in_sizes; (void)n_in; (void)out_size; (void)ws_size;
    const float* x      = (const float*)d_in[0];
    const float* w_enc  = (const float*)d_in[1];
    const float* w_dec  = (const float*)d_in[2];
    const float* b_enc  = (const float*)d_in[3];
    const float* b_pre  = (const float*)d_in[4];
    const unsigned char* dead_mask = (const unsigned char*)d_in[5];
    const int* num_dead = (const int*)d_in[6];
    float* out = (float*)d_out;

    char* base = (char*)d_ws;
    char* w = base;
    auto alloc = [&](size_t bytes) -> char* {
        char* p = w;
        w += (bytes + 255) & ~(size_t)255;
        return p;
    };
    unsigned short* p16 = (unsigned short*)alloc((size_t)BATCH * D_HIDDEN * 2); // 128 MB
    double* mu       = (double*)alloc((size_t)BATCH * 8);
    double* stdv     = (double*)alloc((size_t)BATCH * 8);
    double* sinv     = (double*)alloc((size_t)BATCH * 8);
    int* topk_idx    = (int*)alloc((size_t)BATCH * KSEL * 4);
    float* topk_val  = (float*)alloc((size_t)BATCH * KSEL * 4);
    int* dead_idx    = (int*)alloc((size_t)NDEAD * 4);
    int* dead_cnt    = (int*)alloc(256);
    unsigned short* Ahp = (unsigned short*)alloc((size_t)BATCH * D_MODEL * 2);    // 16 MB
    char* region     = alloc((size_t)D_HIDDEN * D_MODEL * 4);                     // 512 MB

    // time-multiplexed region:
    unsigned short* Bhp = (unsigned short*)region;                 // 256 MB, enc phase
    float* wT   = (float*)region;                                  // 512 MB, topk phase
    unsigned short* wd16 = (unsigned short*)region;                // 256 MB, decode phase
    unsigned short* Bhd  = (unsigned short*)(region + (size_t)D_HIDDEN * D_MODEL * 2); // 16 MB
    unsigned short* Ahd  = Ahp;                                    // 8 MB (Ahp dead after enc)

    float* out0 = out;                                   // recons
    float* out1 = out + (size_t)BATCH * D_MODEL;         // auxk
    float* out_last = out + (size_t)2 * BATCH * D_MODEL; // num_dead

    ln_kernel<<<BATCH, 256, 0, stream>>>(x, mu, stdv, sinv);
    dead_scan_kernel<<<1, 64, 0, stream>>>(dead_mask, dead_idx, dead_cnt, num_dead, out_last);
    asplit_kernel<<<BATCH, 256, 0, stream>>>(x, mu, sinv, b_pre, Ahp);
    bsplit_kernel<<<dim3(D_MODEL / 32, D_HIDDEN / 32), 256, 0, stream>>>(w_enc, Bhp);
    mm_kernel<0><<<(BATCH / 128) * (D_HIDDEN / 128), 256, 0, stream>>>(
        Ahp, Bhp, D_MODEL, BATCH / 128, b_enc, nullptr, nullptr, p16, (long)D_HIDDEN);
    wencT_kernel<<<dim3(D_MODEL / 32, D_HIDDEN / 32), 256, 0, stream>>>(w_enc, wT);
    topk_kernel<<<BATCH, 256, 0, stream>>>(p16, x, mu, sinv, b_pre, wT, b_enc, topk_idx, topk_val);
    auxg_kernel<<<BATCH, 256, 0, stream>>>(p16, dead_idx, dead_cnt, Ahd);
    auxb_kernel<<<dim3(NDEAD / 32, D_MODEL / 32), 256, 0, stream>>>(w_dec, dead_idx, Bhd);
    wdec2bf_kernel<<<(int)(((size_t)D_HIDDEN * D_MODEL) / (256 * 8)), 256, 0, stream>>>(w_dec, wd16);
    decode_kernel<<<BATCH, 256, 0, stream>>>(topk_idx, topk_val, wd16, b_pre, mu, stdv, out0);
    mm_kernel<1><<<(BATCH / 128) * (D_MODEL / 128), 256, 0, stream>>>(
        Ahd, Bhd, NDEAD, BATCH / 128, b_pre, mu, stdv, out1, (long)D_MODEL);
}

// Round 8
// 2416.500 us; speedup vs baseline: 1.5586x; 1.1758x over previous
//
#include <hip/hip_runtime.h>
#include <math.h>

#define D_MODEL  4096
#define D_HIDDEN 32768
#define BATCH    2048
#define KSEL     128
#define NDEAD    2048
#define TIECAP   256

typedef short s16x8 __attribute__((ext_vector_type(8)));
typedef float f32x4 __attribute__((ext_vector_type(4)));

// -------------------- helpers --------------------
__device__ __forceinline__ unsigned int fkey(float f) {
    unsigned int u = __float_as_uint(f);
    return (u & 0x80000000u) ? ~u : (u | 0x80000000u);
}
__device__ __forceinline__ unsigned short f2bf(float f) {  // RTNE
    unsigned int u = __float_as_uint(f);
    u += 0x7FFFu + ((u >> 16) & 1u);
    return (unsigned short)(u >> 16);
}
__device__ __forceinline__ float bf2f(unsigned short h) {
    return __uint_as_float(((unsigned int)h) << 16);
}
// per-16-bit-lane order-preserving key transform (packed pair)
__device__ __forceinline__ unsigned int key16x2(unsigned int u) {
    const unsigned int s = (u >> 15) & 0x10001u;
    const unsigned int mask = s * 0xFFFFu;
    return (u ^ mask) | (~mask & 0x80008000u);
}
__device__ __forceinline__ float unkey16(unsigned int k) {  // 16-bit key -> float
    const unsigned int u = (k & 0x8000u) ? (k & 0x7FFFu) : (~k & 0xFFFFu);
    return __uint_as_float(u << 16);
}
__device__ __forceinline__ void async_copy16(void* lds_dst, const void* gsrc) {
    __builtin_amdgcn_global_load_lds(
        (const __attribute__((address_space(1))) unsigned int*)gsrc,
        (__attribute__((address_space(3))) unsigned int*)lds_dst,
        16, 0, 0);
}

// -------------------- LayerNorm (fp64 stats) --------------------
__global__ __launch_bounds__(256) void ln_kernel(const float* __restrict__ x,
        double* __restrict__ mu, double* __restrict__ stdv, double* __restrict__ sinv)
{
    const int row = blockIdx.x;
    const int tid = threadIdx.x;
    const float* xr = x + (size_t)row * D_MODEL;
    float xv[16];
#pragma unroll
    for (int i = 0; i < 16; ++i) xv[i] = xr[tid + 256 * i];
    double s = 0.0;
#pragma unroll
    for (int i = 0; i < 16; ++i) s += (double)xv[i];
    __shared__ double red[4];
    __shared__ double sh_mu;
    const int lane = tid & 63, wid = tid >> 6;
#pragma unroll
    for (int off = 32; off > 0; off >>= 1) s += __shfl_down(s, off, 64);
    if (lane == 0) red[wid] = s;
    __syncthreads();
    if (tid == 0) sh_mu = (red[0] + red[1] + red[2] + red[3]) / (double)D_MODEL;
    __syncthreads();
    const double m = sh_mu;
    double s2 = 0.0;
#pragma unroll
    for (int i = 0; i < 16; ++i) { double d = (double)xv[i] - m; s2 += d * d; }
#pragma unroll
    for (int off = 32; off > 0; off >>= 1) s2 += __shfl_down(s2, off, 64);
    __syncthreads();
    if (lane == 0) red[wid] = s2;
    __syncthreads();
    if (tid == 0) {
        double var = (red[0] + red[1] + red[2] + red[3]) / (double)(D_MODEL - 1);
        double sd = sqrt(var);
        mu[row] = m;
        stdv[row] = sd;
        sinv[row] = 1.0 / (sd + 1e-5);
    }
}

// -------------------- dead-mask scan --------------------
__global__ void dead_scan_kernel(const unsigned char* __restrict__ mask8,
                                 int* __restrict__ dead_idx, int* __restrict__ dead_cnt,
                                 const int* __restrict__ num_dead_in, float* __restrict__ out_last)
{
    const int lane = threadIdx.x; // 64 threads, one wave
    int c = 0;
    for (int j = lane; j < D_HIDDEN; j += 64) c += (mask8[j] != 0);
#pragma unroll
    for (int off = 32; off > 0; off >>= 1) c += __shfl_down(c, off, 64);
    const int total_u8 = __shfl(c, 0, 64);
    const bool u8mode = (total_u8 == NDEAD);
    const int* mask32 = (const int*)mask8;
    int cnt = 0;
    for (int base = 0; base < D_HIDDEN; base += 64) {
        const int j = base + lane;
        const bool d = u8mode ? (mask8[j] != 0) : (mask32[j] != 0);
        const unsigned long long b = __ballot(d);
        const int pre = __popcll(b & ((1ull << lane) - 1ull));
        if (d && (cnt + pre) < NDEAD) dead_idx[cnt + pre] = j;
        cnt += __popcll(b);
    }
    const int cc = cnt > NDEAD ? NDEAD : cnt;
    if (lane == 0) {
        *dead_cnt = cc;
        *out_last = (float)(*num_dead_in);
    }
    for (int t = cc + lane; t < NDEAD; t += 64) dead_idx[t] = 0;
}

// -------------------- A: xc -> bf16 --------------------
__global__ __launch_bounds__(256) void asplit_kernel(
    const float* __restrict__ x, const double* __restrict__ mu, const double* __restrict__ sinv,
    const float* __restrict__ b_pre, unsigned short* __restrict__ Ahp)
{
    const int row = blockIdx.x, tid = threadIdx.x;
    const double m = mu[row], si = sinv[row];
    const float* xr = x + (size_t)row * D_MODEL;
#pragma unroll
    for (int i = 0; i < 4; ++i) {
        const int j = (i * 256 + tid) * 4;
        const float4 xv = *(const float4*)(xr + j);
        const float4 bp = *(const float4*)(b_pre + j);
        float v[4];
        v[0] = (float)(((double)xv.x - m) * si) - bp.x;
        v[1] = (float)(((double)xv.y - m) * si) - bp.y;
        v[2] = (float)(((double)xv.z - m) * si) - bp.z;
        v[3] = (float)(((double)xv.w - m) * si) - bp.w;
        uint2 hw;
        hw.x = (unsigned)f2bf(v[0]) | ((unsigned)f2bf(v[1]) << 16);
        hw.y = (unsigned)f2bf(v[2]) | ((unsigned)f2bf(v[3]) << 16);
        *(uint2*)(Ahp + (size_t)row * D_MODEL + j) = hw;
    }
}

// -------------------- B: w_enc[k][n] -> Bh[n][k] bf16 --------------------
__global__ __launch_bounds__(256) void bsplit_kernel(
    const float* __restrict__ w_enc, unsigned short* __restrict__ Bhp)
{
    __shared__ float t[32][33];
    const int bk = blockIdx.x * 32;
    const int bn = blockIdx.y * 32;
    const int tid = threadIdx.x;
    const int lr = tid >> 3, lc4 = (tid & 7) * 4;
    const float4 v = *(const float4*)(w_enc + (size_t)(bk + lr) * D_HIDDEN + bn + lc4);
    t[lr][lc4 + 0] = v.x; t[lr][lc4 + 1] = v.y; t[lr][lc4 + 2] = v.z; t[lr][lc4 + 3] = v.w;
    __syncthreads();
    float o[4];
#pragma unroll
    for (int j = 0; j < 4; ++j) o[j] = t[lc4 + j][lr];
    uint2 hw;
    hw.x = (unsigned)f2bf(o[0]) | ((unsigned)f2bf(o[1]) << 16);
    hw.y = (unsigned)f2bf(o[2]) | ((unsigned)f2bf(o[3]) << 16);
    *(uint2*)(Bhp + (size_t)(bn + lr) * D_MODEL + bk + lc4) = hw;
}

// -------------------- w_enc transpose to fp32 [n][k] --------------------
__global__ __launch_bounds__(256) void wencT_kernel(
    const float* __restrict__ w_enc, float* __restrict__ wT)
{
    __shared__ float t[32][33];
    const int bk = blockIdx.x * 32;
    const int bn = blockIdx.y * 32;
    const int tid = threadIdx.x;
    const int lr = tid >> 3, lc4 = (tid & 7) * 4;
    const float4 v = *(const float4*)(w_enc + (size_t)(bk + lr) * D_HIDDEN + bn + lc4);
    t[lr][lc4 + 0] = v.x; t[lr][lc4 + 1] = v.y; t[lr][lc4 + 2] = v.z; t[lr][lc4 + 3] = v.w;
    __syncthreads();
    const int j = tid >> 3, i4 = (tid & 7) * 4;
    float4 o;
    o.x = t[i4 + 0][j]; o.y = t[i4 + 1][j]; o.z = t[i4 + 2][j]; o.w = t[i4 + 3][j];
    *(float4*)(wT + (size_t)(bn + j) * D_MODEL + bk + i4) = o;
}

// -------------------- bf16 MFMA GEMM: 128x128 tile, BK=32, LDS dbuf ---------
template<int EPI>
__global__ __launch_bounds__(256) void mm_kernel(
    const unsigned short* __restrict__ A, const unsigned short* __restrict__ B,
    const int kdim, const int ntiles_x,
    const float* __restrict__ bias_n,
    const double* __restrict__ muv, const double* __restrict__ stdvv,
    void* __restrict__ outp, const long ostride)
{
    __shared__ unsigned short lds[2 * 2 * 128 * 32];  // [buf][plane A/B][row][32]
    const int tid = threadIdx.x;
    const int lane = tid & 63, wid = tid >> 6;
    // XCD-aware block swizzle (gridDim.x % 8 == 0)
    const int cpx = gridDim.x >> 3;
    const int orig = blockIdx.x;
    const int wg = (orig & 7) * cpx + (orig >> 3);
    const int m0 = (wg % ntiles_x) * 128;
    const int n0 = (wg / ntiles_x) * 128;
    const int wm = (wid >> 1) * 64, wn = (wid & 1) * 64;
    const int fr = lane & 15, kq = lane >> 4;
    const int swr = (fr >> 1) & 3;                    // read-side quad XOR
    const int qg = (lane & 3) ^ ((lane >> 3) & 3);    // write-side source quad
    const int qo = (kq ^ swr) * 8;

    f32x4 acc[4][4];
#pragma unroll
    for (int i = 0; i < 4; ++i)
#pragma unroll
        for (int j = 0; j < 4; ++j) acc[i][j] = (f32x4){0.f, 0.f, 0.f, 0.f};

    const unsigned short* srcs[4];
    int d0[4];
#pragma unroll
    for (int j = 0; j < 4; ++j) {
        const int s = wid * 4 + j;
        const int pl = s >> 3, sr = s & 7;
        const int r = sr * 16 + (lane >> 2);
        srcs[j] = (pl ? B : A) + (size_t)((pl ? n0 : m0) + r) * kdim + qg * 8;
        d0[j] = pl * 4096 + sr * 512;
    }

    const int NT = kdim >> 5;
#pragma unroll
    for (int j = 0; j < 4; ++j) async_copy16(lds + d0[j], srcs[j]);
    __syncthreads();

    for (int t = 0; t < NT; ++t) {
        const int cur = t & 1;
        if (t + 1 < NT) {
            const int k1 = (t + 1) << 5;
            const int boff = (cur ^ 1) * 8192;
#pragma unroll
            for (int j = 0; j < 4; ++j) async_copy16(lds + boff + d0[j], srcs[j] + k1);
        }
        const unsigned short* la = lds + cur * 8192;
        const unsigned short* lb = la + 4096;
        s16x8 a[4], b[4];
#pragma unroll
        for (int i = 0; i < 4; ++i) {
            a[i] = *(const s16x8*)(la + (wm + i * 16 + fr) * 32 + qo);
            b[i] = *(const s16x8*)(lb + (wn + i * 16 + fr) * 32 + qo);
        }
#pragma unroll
        for (int mi = 0; mi < 4; ++mi)
#pragma unroll
            for (int ni = 0; ni < 4; ++ni)
                acc[mi][ni] = __builtin_amdgcn_mfma_f32_16x16x32_bf16(a[mi], b[ni], acc[mi][ni], 0, 0, 0);
        __syncthreads();
    }

#pragma unroll
    for (int ni = 0; ni < 4; ++ni) {
        const int col = n0 + wn + ni * 16 + fr;
        const float be = bias_n[col];
#pragma unroll
        for (int mi = 0; mi < 4; ++mi) {
            const int rb = m0 + wm + mi * 16 + kq * 4;
            if (EPI == 0) {
                unsigned short* O = (unsigned short*)outp;
#pragma unroll
                for (int r = 0; r < 4; ++r)
                    O[(size_t)(rb + r) * ostride + col] = f2bf(acc[mi][ni][r] + be);
            } else {
                float* O = (float*)outp;
#pragma unroll
                for (int r = 0; r < 4; ++r) {
                    const int m = rb + r;
                    O[(size_t)m * ostride + col] =
                        (acc[mi][ni][r] + be) * (float)stdvv[m] + (float)muv[m];
                }
            }
        }
    }
}

// ---------- topk phase 1: register keys + binary-search cutoff + classify ----
__global__ __launch_bounds__(256) void topk_sel_kernel(
    const unsigned short* __restrict__ p16,
    int* __restrict__ topk_idx, float* __restrict__ topk_val,
    int* __restrict__ sure_cnt, int* __restrict__ tie_cnt, int* __restrict__ cand_col)
{
    const int row = blockIdx.x;
    const int tid = threadIdx.x;
    const int lane = tid & 63, wid = tid >> 6;
    const unsigned short* pr = p16 + (size_t)row * D_HIDDEN;

    __shared__ int red[4];
    __shared__ int sh_sel, sh_tie;

    // load this thread's 128 keys into registers (single global sweep)
    uint4 kr[16];
#pragma unroll
    for (int i = 0; i < 16; ++i) {
        uint4 w = *(const uint4*)(pr + (i * 256 + tid) * 8);
        w.x = key16x2(w.x); w.y = key16x2(w.y); w.z = key16x2(w.z); w.w = key16x2(w.w);
        kr[i] = w;
    }
    if (tid == 0) { sh_sel = 0; sh_tie = 0; }

    // binary search: smallest t with #(keys > t) < KSEL  -> t = rank-128 key.
    unsigned int lo = 0, hi = 65535;
    while (lo < hi) {
        const unsigned int mid = (lo + hi) >> 1;
        int c = 0;
#pragma unroll
        for (int i = 0; i < 16; ++i) {
            const unsigned int u[4] = {kr[i].x, kr[i].y, kr[i].z, kr[i].w};
#pragma unroll
            for (int e = 0; e < 4; ++e) {
                c += (int)((u[e] & 0xFFFFu) > mid);
                c += (int)((u[e] >> 16) > mid);
            }
        }
#pragma unroll
        for (int off = 32; off > 0; off >>= 1) c += __shfl_down(c, off, 64);
        if (lane == 0) red[wid] = c;
        __syncthreads();
        const int total = red[0] + red[1] + red[2] + red[3];
        if (total < KSEL) hi = mid; else lo = mid + 1;
        __syncthreads();   // protect red[] before next iteration's write
    }
    const unsigned int K16 = lo;

    const float vc = unkey16(K16);           // rank-128 value on the bf16 grid
    const float DLT = 1.3e-2f;               // bounds |p16 - exact| near cutoff
    const float sureT = vc + 2.f * DLT;
    const float candT = vc - 2.f * DLT;
    const unsigned int sK = fkey(sureT) >> 16;
    const unsigned int cK = fkey(candT) >> 16;

    int* oidx = topk_idx + row * KSEL;
    float* oval = topk_val + row * KSEL;
    int* cc = cand_col + row * TIECAP;
#pragma unroll
    for (int i = 0; i < 16; ++i) {
        const int j0 = (i * 256 + tid) * 8;
        const unsigned int u[4] = {kr[i].x, kr[i].y, kr[i].z, kr[i].w};
#pragma unroll
        for (int e = 0; e < 8; ++e) {
            const unsigned int k = (e & 1) ? (u[e >> 1] >> 16) : (u[e >> 1] & 0xFFFFu);
            if (k < cK) continue;
            const float v = unkey16(k);
            if (k > sK && v > sureT) {
                const int pos = atomicAdd(&sh_sel, 1);
                oidx[pos] = j0 + e;
                oval[pos] = v > 0.f ? v : 0.f;
            } else if (v >= candT) {
                const int t = atomicAdd(&sh_tie, 1);
                if (t < TIECAP) cc[t] = j0 + e;
            }
        }
    }
    __syncthreads();
    if (tid == 0) {
        sure_cnt[row] = sh_sel;
        tie_cnt[row] = sh_tie > TIECAP ? TIECAP : sh_tie;
    }
}

// ---------- topk phase 2: exact fp64 refinement, one wave per candidate ----
__global__ __launch_bounds__(256) void topk_refine_kernel(
    const int* __restrict__ tie_cnt, const int* __restrict__ cand_col,
    double* __restrict__ cand_val,
    const float* __restrict__ x, const double* __restrict__ mu, const double* __restrict__ sinv,
    const float* __restrict__ b_pre, const float* __restrict__ wT, const float* __restrict__ b_enc)
{
    const int row = blockIdx.x;
    const int tid = threadIdx.x;
    const int lane = tid & 63, wid = tid >> 6;
    const int T = tie_cnt[row];
    const int base = (int)blockIdx.y * 4 + wid;   // gridDim.y = 16 -> base in [0,64)
    if (base >= T) return;
    const double m_ = mu[row], si = sinv[row];
    const float* xr = x + (size_t)row * D_MODEL;
    for (int slot = base; slot < T; slot += 64) {
        const int col = cand_col[row * TIECAP + slot];
        const float* wr = wT + (size_t)col * D_MODEL;
        double s0 = 0.0, s1 = 0.0;
        for (int k = lane * 4; k < D_MODEL; k += 512) {
            {
                const float4 xv = *(const float4*)(xr + k);
                const float4 bp = *(const float4*)(b_pre + k);
                const float4 wv4 = *(const float4*)(wr + k);
                s0 += (((double)xv.x - m_) * si - (double)bp.x) * (double)wv4.x;
                s0 += (((double)xv.y - m_) * si - (double)bp.y) * (double)wv4.y;
                s0 += (((double)xv.z - m_) * si - (double)bp.z) * (double)wv4.z;
                s0 += (((double)xv.w - m_) * si - (double)bp.w) * (double)wv4.w;
            }
            {
                const int k2 = k + 256;
                const float4 xv = *(const float4*)(xr + k2);
                const float4 bp = *(const float4*)(b_pre + k2);
                const float4 wv4 = *(const float4*)(wr + k2);
                s1 += (((double)xv.x - m_) * si - (double)bp.x) * (double)wv4.x;
                s1 += (((double)xv.y - m_) * si - (double)bp.y) * (double)wv4.y;
                s1 += (((double)xv.z - m_) * si - (double)bp.z) * (double)wv4.z;
                s1 += (((double)xv.w - m_) * si - (double)bp.w) * (double)wv4.w;
            }
        }
        double s = s0 + s1;
#pragma unroll
        for (int off = 32; off > 0; off >>= 1) s += __shfl_down(s, off, 64);
        if (lane == 0) cand_val[row * TIECAP + slot] = s + (double)b_enc[col];
    }
}

// ---------- topk phase 3: parallel rank among candidates, scatter outputs ----
__global__ __launch_bounds__(256) void topk_fin_kernel(
    const int* __restrict__ sure_cnt, const int* __restrict__ tie_cnt,
    const int* __restrict__ cand_col, const double* __restrict__ cand_val,
    int* __restrict__ topk_idx, float* __restrict__ topk_val)
{
    const int row = blockIdx.x;
    const int tid = threadIdx.x;
    __shared__ double vals[TIECAP];
    __shared__ int cols[TIECAP];
    const int G = sure_cnt[row];
    const int T = tie_cnt[row];
    const int R = KSEL - G;
    if (tid < T) {
        vals[tid] = cand_val[row * TIECAP + tid];
        cols[tid] = cand_col[row * TIECAP + tid];
    }
    __syncthreads();
    int* oidx = topk_idx + row * KSEL;
    float* oval = topk_val + row * KSEL;
    if (tid < T) {
        const double v = vals[tid];
        const int c = cols[tid];
        int rank = 0;
        for (int u = 0; u < T; ++u) {
            const double vu = vals[u];
            rank += (int)((vu > v) || (vu == v && cols[u] < c));
        }
        if (rank < R) {
            oidx[G + rank] = c;
            oval[G + rank] = v > 0.0 ? (float)v : 0.f;
        }
    }
    const int take = R < T ? R : T;
    if (tid >= take && tid < R) {
        oidx[G + tid] = (T > 0) ? cols[0] : 0;
        oval[G + tid] = 0.f;
    }
}

// -------------------- w_dec -> bf16 row-major copy --------------------
__global__ __launch_bounds__(256) void wdec2bf_kernel(
    const float* __restrict__ w_dec, unsigned short* __restrict__ wd16)
{
    const size_t gid = (size_t)blockIdx.x * 256 + threadIdx.x;
    const size_t base = gid * 8;
    const float4 a = *(const float4*)(w_dec + base);
    const float4 b = *(const float4*)(w_dec + base + 4);
    uint4 o;
    o.x = (unsigned)f2bf(a.x) | ((unsigned)f2bf(a.y) << 16);
    o.y = (unsigned)f2bf(a.z) | ((unsigned)f2bf(a.w) << 16);
    o.z = (unsigned)f2bf(b.x) | ((unsigned)f2bf(b.y) << 16);
    o.w = (unsigned)f2bf(b.z) | ((unsigned)f2bf(b.w) << 16);
    *(uint4*)(wd16 + base) = o;
}

// -------------------- sparse decode: recons (bf16 w_dec) --------------------
__global__ __launch_bounds__(256) void decode_kernel(
    const int* __restrict__ topk_idx, const float* __restrict__ topk_val,
    const unsigned short* __restrict__ wd16, const float* __restrict__ b_pre,
    const double* __restrict__ mu, const double* __restrict__ stdv,
    float* __restrict__ out0)
{
    const int row = blockIdx.x;
    const int tid = threadIdx.x;
    __shared__ int sidx[KSEL];
    __shared__ float sval[KSEL];
    if (tid < KSEL) {
        sidx[tid] = topk_idx[row * KSEL + tid];
        sval[tid] = topk_val[row * KSEL + tid];
    }
    __syncthreads();
    float acc[16];
#pragma unroll
    for (int i = 0; i < 16; ++i) acc[i] = 0.f;
    const int dbase = tid * 16;
    for (int k = 0; k < KSEL; ++k) {
        const float v = sval[k];
        if (v == 0.f) continue;
        const uint4* wr = (const uint4*)(wd16 + (size_t)sidx[k] * D_MODEL + dbase);
        const uint4 w0 = wr[0], w1 = wr[1];
        const unsigned int u[8] = {w0.x, w0.y, w0.z, w0.w, w1.x, w1.y, w1.z, w1.w};
#pragma unroll
        for (int i = 0; i < 8; ++i) {
            acc[2 * i]     += v * __uint_as_float(u[i] << 16);
            acc[2 * i + 1] += v * __uint_as_float(u[i] & 0xFFFF0000u);
        }
    }
    const float st = (float)stdv[row];
    const float mm = (float)mu[row];
    float* o = out0 + (size_t)row * D_MODEL + dbase;
#pragma unroll
    for (int i = 0; i < 16; ++i) {
        o[i] = (acc[i] + b_pre[dbase + i]) * st + mm;
    }
}

// -------------------- aux A gather+relu (bf16 passthrough) --------------------
__global__ __launch_bounds__(256) void auxg_kernel(
    const unsigned short* __restrict__ p16, const int* __restrict__ dead_idx,
    const int* __restrict__ dead_cnt, unsigned short* __restrict__ Ahd)
{
    const int r = blockIdx.x;
    const int tid = threadIdx.x;
    const int dc = *dead_cnt;
#pragma unroll
    for (int i = 0; i < 8; ++i) {
        const int c = i * 256 + tid;
        unsigned short v = 0;
        if (c < dc) {
            const unsigned short u = p16[(size_t)r * D_HIDDEN + dead_idx[c]];
            v = (u & 0x8000u) ? (unsigned short)0 : u;   // relu on bf16 bits
        }
        Ahd[(size_t)r * NDEAD + c] = v;
    }
}

// -------------------- aux B gather+transpose (bf16) --------------------
__global__ __launch_bounds__(256) void auxb_kernel(
    const float* __restrict__ w_dec, const int* __restrict__ dead_idx,
    unsigned short* __restrict__ Bhd)
{
    __shared__ float t[32][33];
    const int k0 = blockIdx.x * 32;
    const int n0 = blockIdx.y * 32;
    const int tid = threadIdx.x;
    const int i = tid >> 3, j4 = (tid & 7) * 4;
    const int srow = dead_idx[k0 + i];
    const float4 v = *(const float4*)(w_dec + (size_t)srow * D_MODEL + n0 + j4);
    t[i][j4 + 0] = v.x; t[i][j4 + 1] = v.y; t[i][j4 + 2] = v.z; t[i][j4 + 3] = v.w;
    __syncthreads();
    const int j = tid >> 3, i4 = (tid & 7) * 4;
    uint2 hw;
    hw.x = (unsigned)f2bf(t[i4 + 0][j]) | ((unsigned)f2bf(t[i4 + 1][j]) << 16);
    hw.y = (unsigned)f2bf(t[i4 + 2][j]) | ((unsigned)f2bf(t[i4 + 3][j]) << 16);
    *(uint2*)(Bhd + (size_t)(n0 + j) * NDEAD + k0 + i4) = hw;
}

// -------------------- launch --------------------
extern "C" void kernel_launch(void* const* d_in, const int* in_sizes, int n_in,
                              void* d_out, int out_size, void* d_ws, size_t ws_size,
                              hipStream_t stream)
{
    (void)in_sizes; (void)n_in; (void)out_size; (void)ws_size;
    const float* x      = (const float*)d_in[0];
    const float* w_enc  = (const float*)d_in[1];
    const float* w_dec  = (const float*)d_in[2];
    const float* b_enc  = (const float*)d_in[3];
    const float* b_pre  = (const float*)d_in[4];
    const unsigned char* dead_mask = (const unsigned char*)d_in[5];
    const int* num_dead = (const int*)d_in[6];
    float* out = (float*)d_out;

    char* base = (char*)d_ws;
    char* w = base;
    auto alloc = [&](size_t bytes) -> char* {
        char* p = w;
        w += (bytes + 255) & ~(size_t)255;
        return p;
    };
    unsigned short* p16 = (unsigned short*)alloc((size_t)BATCH * D_HIDDEN * 2); // 128 MB
    double* mu       = (double*)alloc((size_t)BATCH * 8);
    double* stdv     = (double*)alloc((size_t)BATCH * 8);
    double* sinv     = (double*)alloc((size_t)BATCH * 8);
    int* topk_idx    = (int*)alloc((size_t)BATCH * KSEL * 4);
    float* topk_val  = (float*)alloc((size_t)BATCH * KSEL * 4);
    int* dead_idx    = (int*)alloc((size_t)NDEAD * 4);
    int* dead_cnt    = (int*)alloc(256);
    int* sure_cnt    = (int*)alloc((size_t)BATCH * 4);
    int* tie_cnt     = (int*)alloc((size_t)BATCH * 4);
    int* cand_col    = (int*)alloc((size_t)BATCH * TIECAP * 4);      // 2 MB
    double* cand_val = (double*)alloc((size_t)BATCH * TIECAP * 8);   // 4 MB
    unsigned short* Ahp = (unsigned short*)alloc((size_t)BATCH * D_MODEL * 2);    // 16 MB
    char* region     = alloc((size_t)D_HIDDEN * D_MODEL * 4);                     // 512 MB

    // time-multiplexed region:
    unsigned short* Bhp = (unsigned short*)region;                 // 256 MB, enc phase
    float* wT   = (float*)region;                                  // 512 MB, topk phase
    unsigned short* wd16 = (unsigned short*)region;                // 256 MB, decode phase
    unsigned short* Bhd  = (unsigned short*)(region + (size_t)D_HIDDEN * D_MODEL * 2); // 16 MB
    unsigned short* Ahd  = Ahp;                                    // 8 MB (Ahp dead after enc)

    float* out0 = out;                                   // recons
    float* out1 = out + (size_t)BATCH * D_MODEL;         // auxk
    float* out_last = out + (size_t)2 * BATCH * D_MODEL; // num_dead

    ln_kernel<<<BATCH, 256, 0, stream>>>(x, mu, stdv, sinv);
    dead_scan_kernel<<<1, 64, 0, stream>>>(dead_mask, dead_idx, dead_cnt, num_dead, out_last);
    asplit_kernel<<<BATCH, 256, 0, stream>>>(x, mu, sinv, b_pre, Ahp);
    bsplit_kernel<<<dim3(D_MODEL / 32, D_HIDDEN / 32), 256, 0, stream>>>(w_enc, Bhp);
    mm_kernel<0><<<(BATCH / 128) * (D_HIDDEN / 128), 256, 0, stream>>>(
        Ahp, Bhp, D_MODEL, BATCH / 128, b_enc, nullptr, nullptr, p16, (long)D_HIDDEN);
    wencT_kernel<<<dim3(D_MODEL / 32, D_HIDDEN / 32), 256, 0, stream>>>(w_enc, wT);
    topk_sel_kernel<<<BATCH, 256, 0, stream>>>(p16, topk_idx, topk_val, sure_cnt, tie_cnt, cand_col);
    topk_refine_kernel<<<dim3(BATCH, 16), 256, 0, stream>>>(
        tie_cnt, cand_col, cand_val, x, mu, sinv, b_pre, wT, b_enc);
    topk_fin_kernel<<<BATCH, 256, 0, stream>>>(
        sure_cnt, tie_cnt, cand_col, cand_val, topk_idx, topk_val);
    auxg_kernel<<<BATCH, 256, 0, stream>>>(p16, dead_idx, dead_cnt, Ahd);
    auxb_kernel<<<dim3(NDEAD / 32, D_MODEL / 32), 256, 0, stream>>>(w_dec, dead_idx, Bhd);
    wdec2bf_kernel<<<(int)(((size_t)D_HIDDEN * D_MODEL) / (256 * 8)), 256, 0, stream>>>(w_dec, wd16);
    decode_kernel<<<BATCH, 256, 0, stream>>>(topk_idx, topk_val, wd16, b_pre, mu, stdv, out0);
    mm_kernel<1><<<(BATCH / 128) * (D_MODEL / 128), 256, 0, stream>>>(
        Ahd, Bhd, NDEAD, BATCH / 128, b_pre, mu, stdv, out1, (long)D_MODEL);
}

// Round 9
// 2404.591 us; speedup vs baseline: 1.5663x; 1.0050x over previous
//
#include <hip/hip_runtime.h>
#include <math.h>

#define D_MODEL  4096
#define D_HIDDEN 32768
#define BATCH    2048
#define KSEL     128
#define NDEAD    2048
#define TIECAP   256

typedef short s16x8 __attribute__((ext_vector_type(8)));
typedef float f32x4 __attribute__((ext_vector_type(4)));

// -------------------- helpers --------------------
__device__ __forceinline__ unsigned int fkey(float f) {
    unsigned int u = __float_as_uint(f);
    return (u & 0x80000000u) ? ~u : (u | 0x80000000u);
}
__device__ __forceinline__ unsigned short f2bf(float f) {  // RTNE
    unsigned int u = __float_as_uint(f);
    u += 0x7FFFu + ((u >> 16) & 1u);
    return (unsigned short)(u >> 16);
}
__device__ __forceinline__ float bf2f(unsigned short h) {
    return __uint_as_float(((unsigned int)h) << 16);
}
// per-16-bit-lane order-preserving key transform (packed pair)
__device__ __forceinline__ unsigned int key16x2(unsigned int u) {
    const unsigned int s = (u >> 15) & 0x10001u;
    const unsigned int mask = s * 0xFFFFu;
    return (u ^ mask) | (~mask & 0x80008000u);
}
__device__ __forceinline__ float unkey16(unsigned int k) {  // 16-bit key -> float
    const unsigned int u = (k & 0x8000u) ? (k & 0x7FFFu) : (~k & 0xFFFFu);
    return __uint_as_float(u << 16);
}
__device__ __forceinline__ void async_copy16(void* lds_dst, const void* gsrc) {
    __builtin_amdgcn_global_load_lds(
        (const __attribute__((address_space(1))) unsigned int*)gsrc,
        (__attribute__((address_space(3))) unsigned int*)lds_dst,
        16, 0, 0);
}

// -------------------- LayerNorm (fp64 stats) --------------------
__global__ __launch_bounds__(256) void ln_kernel(const float* __restrict__ x,
        double* __restrict__ mu, double* __restrict__ stdv, double* __restrict__ sinv)
{
    const int row = blockIdx.x;
    const int tid = threadIdx.x;
    const float* xr = x + (size_t)row * D_MODEL;
    float xv[16];
#pragma unroll
    for (int i = 0; i < 16; ++i) xv[i] = xr[tid + 256 * i];
    double s = 0.0;
#pragma unroll
    for (int i = 0; i < 16; ++i) s += (double)xv[i];
    __shared__ double red[4];
    __shared__ double sh_mu;
    const int lane = tid & 63, wid = tid >> 6;
#pragma unroll
    for (int off = 32; off > 0; off >>= 1) s += __shfl_down(s, off, 64);
    if (lane == 0) red[wid] = s;
    __syncthreads();
    if (tid == 0) sh_mu = (red[0] + red[1] + red[2] + red[3]) / (double)D_MODEL;
    __syncthreads();
    const double m = sh_mu;
    double s2 = 0.0;
#pragma unroll
    for (int i = 0; i < 16; ++i) { double d = (double)xv[i] - m; s2 += d * d; }
#pragma unroll
    for (int off = 32; off > 0; off >>= 1) s2 += __shfl_down(s2, off, 64);
    __syncthreads();
    if (lane == 0) red[wid] = s2;
    __syncthreads();
    if (tid == 0) {
        double var = (red[0] + red[1] + red[2] + red[3]) / (double)(D_MODEL - 1);
        double sd = sqrt(var);
        mu[row] = m;
        stdv[row] = sd;
        sinv[row] = 1.0 / (sd + 1e-5);
    }
}

// -------------------- dead-mask scan --------------------
__global__ void dead_scan_kernel(const unsigned char* __restrict__ mask8,
                                 int* __restrict__ dead_idx, int* __restrict__ dead_cnt,
                                 const int* __restrict__ num_dead_in, float* __restrict__ out_last)
{
    const int lane = threadIdx.x; // 64 threads, one wave
    int c = 0;
    for (int j = lane; j < D_HIDDEN; j += 64) c += (mask8[j] != 0);
#pragma unroll
    for (int off = 32; off > 0; off >>= 1) c += __shfl_down(c, off, 64);
    const int total_u8 = __shfl(c, 0, 64);
    const bool u8mode = (total_u8 == NDEAD);
    const int* mask32 = (const int*)mask8;
    int cnt = 0;
    for (int base = 0; base < D_HIDDEN; base += 64) {
        const int j = base + lane;
        const bool d = u8mode ? (mask8[j] != 0) : (mask32[j] != 0);
        const unsigned long long b = __ballot(d);
        const int pre = __popcll(b & ((1ull << lane) - 1ull));
        if (d && (cnt + pre) < NDEAD) dead_idx[cnt + pre] = j;
        cnt += __popcll(b);
    }
    const int cc = cnt > NDEAD ? NDEAD : cnt;
    if (lane == 0) {
        *dead_cnt = cc;
        *out_last = (float)(*num_dead_in);
    }
    for (int t = cc + lane; t < NDEAD; t += 64) dead_idx[t] = 0;
}

// -------------------- A: xc -> bf16 --------------------
__global__ __launch_bounds__(256) void asplit_kernel(
    const float* __restrict__ x, const double* __restrict__ mu, const double* __restrict__ sinv,
    const float* __restrict__ b_pre, unsigned short* __restrict__ Ahp)
{
    const int row = blockIdx.x, tid = threadIdx.x;
    const double m = mu[row], si = sinv[row];
    const float* xr = x + (size_t)row * D_MODEL;
#pragma unroll
    for (int i = 0; i < 4; ++i) {
        const int j = (i * 256 + tid) * 4;
        const float4 xv = *(const float4*)(xr + j);
        const float4 bp = *(const float4*)(b_pre + j);
        float v[4];
        v[0] = (float)(((double)xv.x - m) * si) - bp.x;
        v[1] = (float)(((double)xv.y - m) * si) - bp.y;
        v[2] = (float)(((double)xv.z - m) * si) - bp.z;
        v[3] = (float)(((double)xv.w - m) * si) - bp.w;
        uint2 hw;
        hw.x = (unsigned)f2bf(v[0]) | ((unsigned)f2bf(v[1]) << 16);
        hw.y = (unsigned)f2bf(v[2]) | ((unsigned)f2bf(v[3]) << 16);
        *(uint2*)(Ahp + (size_t)row * D_MODEL + j) = hw;
    }
}

// -------------------- B: w_enc[k][n] -> Bh[n][k] bf16 --------------------
__global__ __launch_bounds__(256) void bsplit_kernel(
    const float* __restrict__ w_enc, unsigned short* __restrict__ Bhp)
{
    __shared__ float t[32][33];
    const int bk = blockIdx.x * 32;
    const int bn = blockIdx.y * 32;
    const int tid = threadIdx.x;
    const int lr = tid >> 3, lc4 = (tid & 7) * 4;
    const float4 v = *(const float4*)(w_enc + (size_t)(bk + lr) * D_HIDDEN + bn + lc4);
    t[lr][lc4 + 0] = v.x; t[lr][lc4 + 1] = v.y; t[lr][lc4 + 2] = v.z; t[lr][lc4 + 3] = v.w;
    __syncthreads();
    float o[4];
#pragma unroll
    for (int j = 0; j < 4; ++j) o[j] = t[lc4 + j][lr];
    uint2 hw;
    hw.x = (unsigned)f2bf(o[0]) | ((unsigned)f2bf(o[1]) << 16);
    hw.y = (unsigned)f2bf(o[2]) | ((unsigned)f2bf(o[3]) << 16);
    *(uint2*)(Bhp + (size_t)(bn + lr) * D_MODEL + bk + lc4) = hw;
}

// -------------------- w_enc transpose to fp32 [n][k] --------------------
__global__ __launch_bounds__(256) void wencT_kernel(
    const float* __restrict__ w_enc, float* __restrict__ wT)
{
    __shared__ float t[32][33];
    const int bk = blockIdx.x * 32;
    const int bn = blockIdx.y * 32;
    const int tid = threadIdx.x;
    const int lr = tid >> 3, lc4 = (tid & 7) * 4;
    const float4 v = *(const float4*)(w_enc + (size_t)(bk + lr) * D_HIDDEN + bn + lc4);
    t[lr][lc4 + 0] = v.x; t[lr][lc4 + 1] = v.y; t[lr][lc4 + 2] = v.z; t[lr][lc4 + 3] = v.w;
    __syncthreads();
    const int j = tid >> 3, i4 = (tid & 7) * 4;
    float4 o;
    o.x = t[i4 + 0][j]; o.y = t[i4 + 1][j]; o.z = t[i4 + 2][j]; o.w = t[i4 + 3][j];
    *(float4*)(wT + (size_t)(bn + j) * D_MODEL + bk + i4) = o;
}

// -------- bf16 MFMA GEMM: 128x128 tile, BK=32, 3-buffer ring, counted vmcnt ----
// Safety argument (race-free):
//  - stage(t+2) targets buf[(t+2)%3] == buf[(t-1)%3], last read during iter t-1;
//    every wave completes its iter t-1 ds_reads (lgkmcnt before MFMA) before
//    reaching the iter-t barrier, and stage(t+2) is issued after that barrier.
//  - vmcnt(4) at top of iter t waits this wave's stage(t) (stage(t+1)'s 4 loads
//    stay in flight); barrier then makes tile t globally visible.
template<int EPI>
__global__ __launch_bounds__(256) void mm_kernel(
    const unsigned short* __restrict__ A, const unsigned short* __restrict__ B,
    const int kdim, const int ntiles_x,
    const float* __restrict__ bias_n,
    const double* __restrict__ muv, const double* __restrict__ stdvv,
    void* __restrict__ outp, const long ostride)
{
    __shared__ unsigned short lds[3 * 2 * 128 * 32];  // 3 ring bufs x (A 8KB + B 8KB)
    const int tid = threadIdx.x;
    const int lane = tid & 63, wid = tid >> 6;
    // XCD-aware block swizzle (gridDim.x % 8 == 0)
    const int cpx = gridDim.x >> 3;
    const int orig = blockIdx.x;
    const int wg = (orig & 7) * cpx + (orig >> 3);
    const int m0 = (wg % ntiles_x) * 128;
    const int n0 = (wg / ntiles_x) * 128;
    const int wm = (wid >> 1) * 64, wn = (wid & 1) * 64;
    const int fr = lane & 15, kq = lane >> 4;
    const int swr = (fr >> 1) & 3;                    // read-side quad XOR
    const int qg = (lane & 3) ^ ((lane >> 3) & 3);    // write-side source quad
    const int qo = (kq ^ swr) * 8;

    f32x4 acc[4][4];
#pragma unroll
    for (int i = 0; i < 4; ++i)
#pragma unroll
        for (int j = 0; j < 4; ++j) acc[i][j] = (f32x4){0.f, 0.f, 0.f, 0.f};

    const unsigned short* srcs[4];
    int d0[4];
#pragma unroll
    for (int j = 0; j < 4; ++j) {
        const int s = wid * 4 + j;
        const int pl = s >> 3, sr = s & 7;
        const int r = sr * 16 + (lane >> 2);
        srcs[j] = (pl ? B : A) + (size_t)((pl ? n0 : m0) + r) * kdim + qg * 8;
        d0[j] = pl * 4096 + sr * 512;
    }

    const int NT = kdim >> 5;
    // prologue: stage tiles 0 and 1 into ring slots 0,1 (8 loads in flight/wave)
#pragma unroll
    for (int j = 0; j < 4; ++j) async_copy16(lds + 0 * 8192 + d0[j], srcs[j]);
#pragma unroll
    for (int j = 0; j < 4; ++j) async_copy16(lds + 1 * 8192 + d0[j], srcs[j] + 32);

    int cur = 0, nxt = 2;   // buf index of tile t, and of tile t+2
    for (int t = 0; t < NT; ++t) {
        // wait for THIS wave's stage(t); keep stage(t+1) in flight (never drain mid-loop)
        if (t < NT - 1) {
            asm volatile("s_waitcnt vmcnt(4)" ::: "memory");
        } else {
            asm volatile("s_waitcnt vmcnt(0)" ::: "memory");
        }
        __builtin_amdgcn_s_barrier();
        __builtin_amdgcn_sched_barrier(0);

        // issue prefetch of tile t+2 into ring slot nxt (safe: last read at t-1)
        if (t + 2 < NT) {
            const int k2 = (t + 2) << 5;
#pragma unroll
            for (int j = 0; j < 4; ++j) async_copy16(lds + nxt * 8192 + d0[j], srcs[j] + k2);
        }

        const unsigned short* la = lds + cur * 8192;
        const unsigned short* lb = la + 4096;
        s16x8 a[4], b[4];
#pragma unroll
        for (int i = 0; i < 4; ++i) {
            a[i] = *(const s16x8*)(la + (wm + i * 16 + fr) * 32 + qo);
            b[i] = *(const s16x8*)(lb + (wn + i * 16 + fr) * 32 + qo);
        }
#pragma unroll
        for (int mi = 0; mi < 4; ++mi)
#pragma unroll
            for (int ni = 0; ni < 4; ++ni)
                acc[mi][ni] = __builtin_amdgcn_mfma_f32_16x16x32_bf16(a[mi], b[ni], acc[mi][ni], 0, 0, 0);

        cur = cur == 2 ? 0 : cur + 1;
        nxt = nxt == 2 ? 0 : nxt + 1;
    }

#pragma unroll
    for (int ni = 0; ni < 4; ++ni) {
        const int col = n0 + wn + ni * 16 + fr;
        const float be = bias_n[col];
#pragma unroll
        for (int mi = 0; mi < 4; ++mi) {
            const int rb = m0 + wm + mi * 16 + kq * 4;
            if (EPI == 0) {
                unsigned short* O = (unsigned short*)outp;
#pragma unroll
                for (int r = 0; r < 4; ++r)
                    O[(size_t)(rb + r) * ostride + col] = f2bf(acc[mi][ni][r] + be);
            } else {
                float* O = (float*)outp;
#pragma unroll
                for (int r = 0; r < 4; ++r) {
                    const int m = rb + r;
                    O[(size_t)m * ostride + col] =
                        (acc[mi][ni][r] + be) * (float)stdvv[m] + (float)muv[m];
                }
            }
        }
    }
}

// ---------- topk phase 1: register keys + binary-search cutoff + classify ----
__global__ __launch_bounds__(256) void topk_sel_kernel(
    const unsigned short* __restrict__ p16,
    int* __restrict__ topk_idx, float* __restrict__ topk_val,
    int* __restrict__ sure_cnt, int* __restrict__ tie_cnt, int* __restrict__ cand_col)
{
    const int row = blockIdx.x;
    const int tid = threadIdx.x;
    const int lane = tid & 63, wid = tid >> 6;
    const unsigned short* pr = p16 + (size_t)row * D_HIDDEN;

    __shared__ int red[4];
    __shared__ int sh_sel, sh_tie;

    // load this thread's 128 keys into registers (single global sweep)
    uint4 kr[16];
#pragma unroll
    for (int i = 0; i < 16; ++i) {
        uint4 w = *(const uint4*)(pr + (i * 256 + tid) * 8);
        w.x = key16x2(w.x); w.y = key16x2(w.y); w.z = key16x2(w.z); w.w = key16x2(w.w);
        kr[i] = w;
    }
    if (tid == 0) { sh_sel = 0; sh_tie = 0; }

    // binary search: smallest t with #(keys > t) < KSEL  -> t = rank-128 key.
    unsigned int lo = 0, hi = 65535;
    while (lo < hi) {
        const unsigned int mid = (lo + hi) >> 1;
        int c = 0;
#pragma unroll
        for (int i = 0; i < 16; ++i) {
            const unsigned int u[4] = {kr[i].x, kr[i].y, kr[i].z, kr[i].w};
#pragma unroll
            for (int e = 0; e < 4; ++e) {
                c += (int)((u[e] & 0xFFFFu) > mid);
                c += (int)((u[e] >> 16) > mid);
            }
        }
#pragma unroll
        for (int off = 32; off > 0; off >>= 1) c += __shfl_down(c, off, 64);
        if (lane == 0) red[wid] = c;
        __syncthreads();
        const int total = red[0] + red[1] + red[2] + red[3];
        if (total < KSEL) hi = mid; else lo = mid + 1;
        __syncthreads();   // protect red[] before next iteration's write
    }
    const unsigned int K16 = lo;

    const float vc = unkey16(K16);           // rank-128 value on the bf16 grid
    const float DLT = 1.3e-2f;               // bounds |p16 - exact| near cutoff
    const float sureT = vc + 2.f * DLT;
    const float candT = vc - 2.f * DLT;
    const unsigned int sK = fkey(sureT) >> 16;
    const unsigned int cK = fkey(candT) >> 16;

    int* oidx = topk_idx + row * KSEL;
    float* oval = topk_val + row * KSEL;
    int* cc = cand_col + row * TIECAP;
#pragma unroll
    for (int i = 0; i < 16; ++i) {
        const int j0 = (i * 256 + tid) * 8;
        const unsigned int u[4] = {kr[i].x, kr[i].y, kr[i].z, kr[i].w};
#pragma unroll
        for (int e = 0; e < 8; ++e) {
            const unsigned int k = (e & 1) ? (u[e >> 1] >> 16) : (u[e >> 1] & 0xFFFFu);
            if (k < cK) continue;
            const float v = unkey16(k);
            if (k > sK && v > sureT) {
                const int pos = atomicAdd(&sh_sel, 1);
                oidx[pos] = j0 + e;
                oval[pos] = v > 0.f ? v : 0.f;
            } else if (v >= candT) {
                const int t = atomicAdd(&sh_tie, 1);
                if (t < TIECAP) cc[t] = j0 + e;
            }
        }
    }
    __syncthreads();
    if (tid == 0) {
        sure_cnt[row] = sh_sel;
        tie_cnt[row] = sh_tie > TIECAP ? TIECAP : sh_tie;
    }
}

// ---------- topk phase 2: exact fp64 refinement, one wave per candidate ----
__global__ __launch_bounds__(256) void topk_refine_kernel(
    const int* __restrict__ tie_cnt, const int* __restrict__ cand_col,
    double* __restrict__ cand_val,
    const float* __restrict__ x, const double* __restrict__ mu, const double* __restrict__ sinv,
    const float* __restrict__ b_pre, const float* __restrict__ wT, const float* __restrict__ b_enc)
{
    const int row = blockIdx.x;
    const int tid = threadIdx.x;
    const int lane = tid & 63, wid = tid >> 6;
    const int T = tie_cnt[row];
    const int base = (int)blockIdx.y * 4 + wid;   // gridDim.y = 16 -> base in [0,64)
    if (base >= T) return;
    const double m_ = mu[row], si = sinv[row];
    const float* xr = x + (size_t)row * D_MODEL;
    for (int slot = base; slot < T; slot += 64) {
        const int col = cand_col[row * TIECAP + slot];
        const float* wr = wT + (size_t)col * D_MODEL;
        double s0 = 0.0, s1 = 0.0;
        for (int k = lane * 4; k < D_MODEL; k += 512) {
            {
                const float4 xv = *(const float4*)(xr + k);
                const float4 bp = *(const float4*)(b_pre + k);
                const float4 wv4 = *(const float4*)(wr + k);
                s0 += (((double)xv.x - m_) * si - (double)bp.x) * (double)wv4.x;
                s0 += (((double)xv.y - m_) * si - (double)bp.y) * (double)wv4.y;
                s0 += (((double)xv.z - m_) * si - (double)bp.z) * (double)wv4.z;
                s0 += (((double)xv.w - m_) * si - (double)bp.w) * (double)wv4.w;
            }
            {
                const int k2 = k + 256;
                const float4 xv = *(const float4*)(xr + k2);
                const float4 bp = *(const float4*)(b_pre + k2);
                const float4 wv4 = *(const float4*)(wr + k2);
                s1 += (((double)xv.x - m_) * si - (double)bp.x) * (double)wv4.x;
                s1 += (((double)xv.y - m_) * si - (double)bp.y) * (double)wv4.y;
                s1 += (((double)xv.z - m_) * si - (double)bp.z) * (double)wv4.z;
                s1 += (((double)xv.w - m_) * si - (double)bp.w) * (double)wv4.w;
            }
        }
        double s = s0 + s1;
#pragma unroll
        for (int off = 32; off > 0; off >>= 1) s += __shfl_down(s, off, 64);
        if (lane == 0) cand_val[row * TIECAP + slot] = s + (double)b_enc[col];
    }
}

// ---------- topk phase 3: parallel rank among candidates, scatter outputs ----
__global__ __launch_bounds__(256) void topk_fin_kernel(
    const int* __restrict__ sure_cnt, const int* __restrict__ tie_cnt,
    const int* __restrict__ cand_col, const double* __restrict__ cand_val,
    int* __restrict__ topk_idx, float* __restrict__ topk_val)
{
    const int row = blockIdx.x;
    const int tid = threadIdx.x;
    __shared__ double vals[TIECAP];
    __shared__ int cols[TIECAP];
    const int G = sure_cnt[row];
    const int T = tie_cnt[row];
    const int R = KSEL - G;
    if (tid < T) {
        vals[tid] = cand_val[row * TIECAP + tid];
        cols[tid] = cand_col[row * TIECAP + tid];
    }
    __syncthreads();
    int* oidx = topk_idx + row * KSEL;
    float* oval = topk_val + row * KSEL;
    if (tid < T) {
        const double v = vals[tid];
        const int c = cols[tid];
        int rank = 0;
        for (int u = 0; u < T; ++u) {
            const double vu = vals[u];
            rank += (int)((vu > v) || (vu == v && cols[u] < c));
        }
        if (rank < R) {
            oidx[G + rank] = c;
            oval[G + rank] = v > 0.0 ? (float)v : 0.f;
        }
    }
    const int take = R < T ? R : T;
    if (tid >= take && tid < R) {
        oidx[G + tid] = (T > 0) ? cols[0] : 0;
        oval[G + tid] = 0.f;
    }
}

// -------------------- w_dec -> bf16 row-major copy --------------------
__global__ __launch_bounds__(256) void wdec2bf_kernel(
    const float* __restrict__ w_dec, unsigned short* __restrict__ wd16)
{
    const size_t gid = (size_t)blockIdx.x * 256 + threadIdx.x;
    const size_t base = gid * 8;
    const float4 a = *(const float4*)(w_dec + base);
    const float4 b = *(const float4*)(w_dec + base + 4);
    uint4 o;
    o.x = (unsigned)f2bf(a.x) | ((unsigned)f2bf(a.y) << 16);
    o.y = (unsigned)f2bf(a.z) | ((unsigned)f2bf(a.w) << 16);
    o.z = (unsigned)f2bf(b.x) | ((unsigned)f2bf(b.y) << 16);
    o.w = (unsigned)f2bf(b.z) | ((unsigned)f2bf(b.w) << 16);
    *(uint4*)(wd16 + base) = o;
}

// -------------------- sparse decode: recons (bf16 w_dec) --------------------
__global__ __launch_bounds__(256) void decode_kernel(
    const int* __restrict__ topk_idx, const float* __restrict__ topk_val,
    const unsigned short* __restrict__ wd16, const float* __restrict__ b_pre,
    const double* __restrict__ mu, const double* __restrict__ stdv,
    float* __restrict__ out0)
{
    const int row = blockIdx.x;
    const int tid = threadIdx.x;
    __shared__ int sidx[KSEL];
    __shared__ float sval[KSEL];
    if (tid < KSEL) {
        sidx[tid] = topk_idx[row * KSEL + tid];
        sval[tid] = topk_val[row * KSEL + tid];
    }
    __syncthreads();
    float acc[16];
#pragma unroll
    for (int i = 0; i < 16; ++i) acc[i] = 0.f;
    const int dbase = tid * 16;
    for (int k = 0; k < KSEL; ++k) {
        const float v = sval[k];
        if (v == 0.f) continue;
        const uint4* wr = (const uint4*)(wd16 + (size_t)sidx[k] * D_MODEL + dbase);
        const uint4 w0 = wr[0], w1 = wr[1];
        const unsigned int u[8] = {w0.x, w0.y, w0.z, w0.w, w1.x, w1.y, w1.z, w1.w};
#pragma unroll
        for (int i = 0; i < 8; ++i) {
            acc[2 * i]     += v * __uint_as_float(u[i] << 16);
            acc[2 * i + 1] += v * __uint_as_float(u[i] & 0xFFFF0000u);
        }
    }
    const float st = (float)stdv[row];
    const float mm = (float)mu[row];
    float* o = out0 + (size_t)row * D_MODEL + dbase;
#pragma unroll
    for (int i = 0; i < 16; ++i) {
        o[i] = (acc[i] + b_pre[dbase + i]) * st + mm;
    }
}

// -------------------- aux A gather+relu (bf16 passthrough) --------------------
__global__ __launch_bounds__(256) void auxg_kernel(
    const unsigned short* __restrict__ p16, const int* __restrict__ dead_idx,
    const int* __restrict__ dead_cnt, unsigned short* __restrict__ Ahd)
{
    const int r = blockIdx.x;
    const int tid = threadIdx.x;
    const int dc = *dead_cnt;
#pragma unroll
    for (int i = 0; i < 8; ++i) {
        const int c = i * 256 + tid;
        unsigned short v = 0;
        if (c < dc) {
            const unsigned short u = p16[(size_t)r * D_HIDDEN + dead_idx[c]];
            v = (u & 0x8000u) ? (unsigned short)0 : u;   // relu on bf16 bits
        }
        Ahd[(size_t)r * NDEAD + c] = v;
    }
}

// -------------------- aux B gather+transpose (bf16) --------------------
__global__ __launch_bounds__(256) void auxb_kernel(
    const float* __restrict__ w_dec, const int* __restrict__ dead_idx,
    unsigned short* __restrict__ Bhd)
{
    __shared__ float t[32][33];
    const int k0 = blockIdx.x * 32;
    const int n0 = blockIdx.y * 32;
    const int tid = threadIdx.x;
    const int i = tid >> 3, j4 = (tid & 7) * 4;
    const int srow = dead_idx[k0 + i];
    const float4 v = *(const float4*)(w_dec + (size_t)srow * D_MODEL + n0 + j4);
    t[i][j4 + 0] = v.x; t[i][j4 + 1] = v.y; t[i][j4 + 2] = v.z; t[i][j4 + 3] = v.w;
    __syncthreads();
    const int j = tid >> 3, i4 = (tid & 7) * 4;
    uint2 hw;
    hw.x = (unsigned)f2bf(t[i4 + 0][j]) | ((unsigned)f2bf(t[i4 + 1][j]) << 16);
    hw.y = (unsigned)f2bf(t[i4 + 2][j]) | ((unsigned)f2bf(t[i4 + 3][j]) << 16);
    *(uint2*)(Bhd + (size_t)(n0 + j) * NDEAD + k0 + i4) = hw;
}

// -------------------- launch --------------------
extern "C" void kernel_launch(void* const* d_in, const int* in_sizes, int n_in,
                              void* d_out, int out_size, void* d_ws, size_t ws_size,
                              hipStream_t stream)
{
    (void)in_sizes; (void)n_in; (void)out_size; (void)ws_size;
    const float* x      = (const float*)d_in[0];
    const float* w_enc  = (const float*)d_in[1];
    const float* w_dec  = (const float*)d_in[2];
    const float* b_enc  = (const float*)d_in[3];
    const float* b_pre  = (const float*)d_in[4];
    const unsigned char* dead_mask = (const unsigned char*)d_in[5];
    const int* num_dead = (const int*)d_in[6];
    float* out = (float*)d_out;

    char* base = (char*)d_ws;
    char* w = base;
    auto alloc = [&](size_t bytes) -> char* {
        char* p = w;
        w += (bytes + 255) & ~(size_t)255;
        return p;
    };
    unsigned short* p16 = (unsigned short*)alloc((size_t)BATCH * D_HIDDEN * 2); // 128 MB
    double* mu       = (double*)alloc((size_t)BATCH * 8);
    double* stdv     = (double*)alloc((size_t)BATCH * 8);
    double* sinv     = (double*)alloc((size_t)BATCH * 8);
    int* topk_idx    = (int*)alloc((size_t)BATCH * KSEL * 4);
    float* topk_val  = (float*)alloc((size_t)BATCH * KSEL * 4);
    int* dead_idx    = (int*)alloc((size_t)NDEAD * 4);
    int* dead_cnt    = (int*)alloc(256);
    int* sure_cnt    = (int*)alloc((size_t)BATCH * 4);
    int* tie_cnt     = (int*)alloc((size_t)BATCH * 4);
    int* cand_col    = (int*)alloc((size_t)BATCH * TIECAP * 4);      // 2 MB
    double* cand_val = (double*)alloc((size_t)BATCH * TIECAP * 8);   // 4 MB
    unsigned short* Ahp = (unsigned short*)alloc((size_t)BATCH * D_MODEL * 2);    // 16 MB
    char* region     = alloc((size_t)D_HIDDEN * D_MODEL * 4);                     // 512 MB

    // time-multiplexed region:
    unsigned short* Bhp = (unsigned short*)region;                 // 256 MB, enc phase
    float* wT   = (float*)region;                                  // 512 MB, topk phase
    unsigned short* wd16 = (unsigned short*)region;                // 256 MB, decode phase
    unsigned short* Bhd  = (unsigned short*)(region + (size_t)D_HIDDEN * D_MODEL * 2); // 16 MB
    unsigned short* Ahd  = Ahp;                                    // 8 MB (Ahp dead after enc)

    float* out0 = out;                                   // recons
    float* out1 = out + (size_t)BATCH * D_MODEL;         // auxk
    float* out_last = out + (size_t)2 * BATCH * D_MODEL; // num_dead

    ln_kernel<<<BATCH, 256, 0, stream>>>(x, mu, stdv, sinv);
    dead_scan_kernel<<<1, 64, 0, stream>>>(dead_mask, dead_idx, dead_cnt, num_dead, out_last);
    asplit_kernel<<<BATCH, 256, 0, stream>>>(x, mu, sinv, b_pre, Ahp);
    bsplit_kernel<<<dim3(D_MODEL / 32, D_HIDDEN / 32), 256, 0, stream>>>(w_enc, Bhp);
    mm_kernel<0><<<(BATCH / 128) * (D_HIDDEN / 128), 256, 0, stream>>>(
        Ahp, Bhp, D_MODEL, BATCH / 128, b_enc, nullptr, nullptr, p16, (long)D_HIDDEN);
    wencT_kernel<<<dim3(D_MODEL / 32, D_HIDDEN / 32), 256, 0, stream>>>(w_enc, wT);
    topk_sel_kernel<<<BATCH, 256, 0, stream>>>(p16, topk_idx, topk_val, sure_cnt, tie_cnt, cand_col);
    topk_refine_kernel<<<dim3(BATCH, 16), 256, 0, stream>>>(
        tie_cnt, cand_col, cand_val, x, mu, sinv, b_pre, wT, b_enc);
    topk_fin_kernel<<<BATCH, 256, 0, stream>>>(
        sure_cnt, tie_cnt, cand_col, cand_val, topk_idx, topk_val);
    auxg_kernel<<<BATCH, 256, 0, stream>>>(p16, dead_idx, dead_cnt, Ahd);
    auxb_kernel<<<dim3(NDEAD / 32, D_MODEL / 32), 256, 0, stream>>>(w_dec, dead_idx, Bhd);
    wdec2bf_kernel<<<(int)(((size_t)D_HIDDEN * D_MODEL) / (256 * 8)), 256, 0, stream>>>(w_dec, wd16);
    decode_kernel<<<BATCH, 256, 0, stream>>>(topk_idx, topk_val, wd16, b_pre, mu, stdv, out0);
    mm_kernel<1><<<(BATCH / 128) * (D_MODEL / 128), 256, 0, stream>>>(
        Ahd, Bhd, NDEAD, BATCH / 128, b_pre, mu, stdv, out1, (long)D_MODEL);
}

// Round 10
// 2294.342 us; speedup vs baseline: 1.6416x; 1.0481x over previous
//
#include <hip/hip_runtime.h>
#include <math.h>

#define D_MODEL  4096
#define D_HIDDEN 32768
#define BATCH    2048
#define KSEL     128
#define NDEAD    2048
#define TIECAP   256

typedef short s16x8 __attribute__((ext_vector_type(8)));
typedef float f32x4 __attribute__((ext_vector_type(4)));

// -------------------- helpers --------------------
__device__ __forceinline__ unsigned int fkey(float f) {
    unsigned int u = __float_as_uint(f);
    return (u & 0x80000000u) ? ~u : (u | 0x80000000u);
}
__device__ __forceinline__ unsigned short f2bf(float f) {  // RTNE
    unsigned int u = __float_as_uint(f);
    u += 0x7FFFu + ((u >> 16) & 1u);
    return (unsigned short)(u >> 16);
}
__device__ __forceinline__ float bf2f(unsigned short h) {
    return __uint_as_float(((unsigned int)h) << 16);
}
// per-16-bit-lane order-preserving key transform (packed pair)
__device__ __forceinline__ unsigned int key16x2(unsigned int u) {
    const unsigned int s = (u >> 15) & 0x10001u;
    const unsigned int mask = s * 0xFFFFu;
    return (u ^ mask) | (~mask & 0x80008000u);
}
__device__ __forceinline__ float unkey16(unsigned int k) {  // 16-bit key -> float
    const unsigned int u = (k & 0x8000u) ? (k & 0x7FFFu) : (~k & 0xFFFFu);
    return __uint_as_float(u << 16);
}
__device__ __forceinline__ void async_copy16(void* lds_dst, const void* gsrc) {
    __builtin_amdgcn_global_load_lds(
        (const __attribute__((address_space(1))) unsigned int*)gsrc,
        (__attribute__((address_space(3))) unsigned int*)lds_dst,
        16, 0, 0);
}

// -------------------- LayerNorm (fp64 stats) --------------------
__global__ __launch_bounds__(256) void ln_kernel(const float* __restrict__ x,
        double* __restrict__ mu, double* __restrict__ stdv, double* __restrict__ sinv)
{
    const int row = blockIdx.x;
    const int tid = threadIdx.x;
    const float* xr = x + (size_t)row * D_MODEL;
    float xv[16];
#pragma unroll
    for (int i = 0; i < 16; ++i) xv[i] = xr[tid + 256 * i];
    double s = 0.0;
#pragma unroll
    for (int i = 0; i < 16; ++i) s += (double)xv[i];
    __shared__ double red[4];
    __shared__ double sh_mu;
    const int lane = tid & 63, wid = tid >> 6;
#pragma unroll
    for (int off = 32; off > 0; off >>= 1) s += __shfl_down(s, off, 64);
    if (lane == 0) red[wid] = s;
    __syncthreads();
    if (tid == 0) sh_mu = (red[0] + red[1] + red[2] + red[3]) / (double)D_MODEL;
    __syncthreads();
    const double m = sh_mu;
    double s2 = 0.0;
#pragma unroll
    for (int i = 0; i < 16; ++i) { double d = (double)xv[i] - m; s2 += d * d; }
#pragma unroll
    for (int off = 32; off > 0; off >>= 1) s2 += __shfl_down(s2, off, 64);
    __syncthreads();
    if (lane == 0) red[wid] = s2;
    __syncthreads();
    if (tid == 0) {
        double var = (red[0] + red[1] + red[2] + red[3]) / (double)(D_MODEL - 1);
        double sd = sqrt(var);
        mu[row] = m;
        stdv[row] = sd;
        sinv[row] = 1.0 / (sd + 1e-5);
    }
}

// -------------------- dead-mask scan --------------------
__global__ void dead_scan_kernel(const unsigned char* __restrict__ mask8,
                                 int* __restrict__ dead_idx, int* __restrict__ dead_cnt,
                                 const int* __restrict__ num_dead_in, float* __restrict__ out_last)
{
    const int lane = threadIdx.x; // 64 threads, one wave
    int c = 0;
    for (int j = lane; j < D_HIDDEN; j += 64) c += (mask8[j] != 0);
#pragma unroll
    for (int off = 32; off > 0; off >>= 1) c += __shfl_down(c, off, 64);
    const int total_u8 = __shfl(c, 0, 64);
    const bool u8mode = (total_u8 == NDEAD);
    const int* mask32 = (const int*)mask8;
    int cnt = 0;
    for (int base = 0; base < D_HIDDEN; base += 64) {
        const int j = base + lane;
        const bool d = u8mode ? (mask8[j] != 0) : (mask32[j] != 0);
        const unsigned long long b = __ballot(d);
        const int pre = __popcll(b & ((1ull << lane) - 1ull));
        if (d && (cnt + pre) < NDEAD) dead_idx[cnt + pre] = j;
        cnt += __popcll(b);
    }
    const int cc = cnt > NDEAD ? NDEAD : cnt;
    if (lane == 0) {
        *dead_cnt = cc;
        *out_last = (float)(*num_dead_in);
    }
    for (int t = cc + lane; t < NDEAD; t += 64) dead_idx[t] = 0;
}

// -------------------- A: xc -> bf16 --------------------
__global__ __launch_bounds__(256) void asplit_kernel(
    const float* __restrict__ x, const double* __restrict__ mu, const double* __restrict__ sinv,
    const float* __restrict__ b_pre, unsigned short* __restrict__ Ahp)
{
    const int row = blockIdx.x, tid = threadIdx.x;
    const double m = mu[row], si = sinv[row];
    const float* xr = x + (size_t)row * D_MODEL;
#pragma unroll
    for (int i = 0; i < 4; ++i) {
        const int j = (i * 256 + tid) * 4;
        const float4 xv = *(const float4*)(xr + j);
        const float4 bp = *(const float4*)(b_pre + j);
        float v[4];
        v[0] = (float)(((double)xv.x - m) * si) - bp.x;
        v[1] = (float)(((double)xv.y - m) * si) - bp.y;
        v[2] = (float)(((double)xv.z - m) * si) - bp.z;
        v[3] = (float)(((double)xv.w - m) * si) - bp.w;
        uint2 hw;
        hw.x = (unsigned)f2bf(v[0]) | ((unsigned)f2bf(v[1]) << 16);
        hw.y = (unsigned)f2bf(v[2]) | ((unsigned)f2bf(v[3]) << 16);
        *(uint2*)(Ahp + (size_t)row * D_MODEL + j) = hw;
    }
}

// -------------------- B: w_enc[k][n] -> Bh[n][k] bf16 --------------------
__global__ __launch_bounds__(256) void bsplit_kernel(
    const float* __restrict__ w_enc, unsigned short* __restrict__ Bhp)
{
    __shared__ float t[32][33];
    const int bk = blockIdx.x * 32;
    const int bn = blockIdx.y * 32;
    const int tid = threadIdx.x;
    const int lr = tid >> 3, lc4 = (tid & 7) * 4;
    const float4 v = *(const float4*)(w_enc + (size_t)(bk + lr) * D_HIDDEN + bn + lc4);
    t[lr][lc4 + 0] = v.x; t[lr][lc4 + 1] = v.y; t[lr][lc4 + 2] = v.z; t[lr][lc4 + 3] = v.w;
    __syncthreads();
    float o[4];
#pragma unroll
    for (int j = 0; j < 4; ++j) o[j] = t[lc4 + j][lr];
    uint2 hw;
    hw.x = (unsigned)f2bf(o[0]) | ((unsigned)f2bf(o[1]) << 16);
    hw.y = (unsigned)f2bf(o[2]) | ((unsigned)f2bf(o[3]) << 16);
    *(uint2*)(Bhp + (size_t)(bn + lr) * D_MODEL + bk + lc4) = hw;
}

// -------------------- w_enc transpose to fp32 [n][k] --------------------
__global__ __launch_bounds__(256) void wencT_kernel(
    const float* __restrict__ w_enc, float* __restrict__ wT)
{
    __shared__ float t[32][33];
    const int bk = blockIdx.x * 32;
    const int bn = blockIdx.y * 32;
    const int tid = threadIdx.x;
    const int lr = tid >> 3, lc4 = (tid & 7) * 4;
    const float4 v = *(const float4*)(w_enc + (size_t)(bk + lr) * D_HIDDEN + bn + lc4);
    t[lr][lc4 + 0] = v.x; t[lr][lc4 + 1] = v.y; t[lr][lc4 + 2] = v.z; t[lr][lc4 + 3] = v.w;
    __syncthreads();
    const int j = tid >> 3, i4 = (tid & 7) * 4;
    float4 o;
    o.x = t[i4 + 0][j]; o.y = t[i4 + 1][j]; o.z = t[i4 + 2][j]; o.w = t[i4 + 3][j];
    *(float4*)(wT + (size_t)(bn + j) * D_MODEL + bk + i4) = o;
}

// ======== 256x256-tile bf16 MFMA GEMM: BK=64, 8 waves, 128KB LDS, counted vmcnt ====
// LDS per buf: 4 subplanes [256][32] bf16 (A-kk0, A-kk1, B-kk0, B-kk1), each
// structurally identical to the proven conflict-free 128x32 planes (quad-XOR).
// Schedule per K-tile t: issue stage(t+1) -> vmcnt(8) (stage(t) done, t+1 in
// flight) -> barrier -> compute kk0,kk1 -> barrier. Never drains mid-loop.
template<int EPI>
__global__ __launch_bounds__(512) void mm256_kernel(
    const unsigned short* __restrict__ A, const unsigned short* __restrict__ B,
    const int kdim, const int ntiles_x,
    const float* __restrict__ bias_n,
    const double* __restrict__ muv, const double* __restrict__ stdvv,
    void* __restrict__ outp, const long ostride)
{
    __shared__ unsigned short lds[2 * 4 * 8192];   // 128 KB: 2 bufs x 4 subplanes
    const int tid = threadIdx.x;
    const int lane = tid & 63, wid = tid >> 6;     // 8 waves
    const int cpx = gridDim.x >> 3;                // XCD swizzle (grid % 8 == 0)
    const int orig = blockIdx.x;
    const int wg = (orig & 7) * cpx + (orig >> 3);
    const int m0 = (wg % ntiles_x) * 256;
    const int n0 = (wg / ntiles_x) * 256;
    const int wm = (wid >> 2) * 128;               // 2 M-halves
    const int wn = (wid & 3) * 64;                 // 4 N-quarters
    const int fr = lane & 15, kq = lane >> 4;
    const int swr = (fr >> 1) & 3;                 // read-side quad XOR
    const int qg = (lane & 3) ^ ((lane >> 3) & 3); // write-side source quad
    const int qo = (kq ^ swr) * 8;

    f32x4 acc[8][4];
#pragma unroll
    for (int i = 0; i < 8; ++i)
#pragma unroll
        for (int j = 0; j < 4; ++j) acc[i][j] = (f32x4){0.f, 0.f, 0.f, 0.f};

    // 64 staging segs: sp = s>>4 (0:A-kk0,1:A-kk1,2:B-kk0,3:B-kk1), sr = s&15.
    // wave w stages segs w*8+j; each seg = 16 rows x 32 cols = 1KB (64 lanes x 16B).
    const unsigned short* srcs[8];
    int d0[8];
#pragma unroll
    for (int j = 0; j < 8; ++j) {
        const int s = wid * 8 + j;
        const int sp = s >> 4, sr = s & 15;
        const unsigned short* gp = (sp < 2) ? A : B;
        const int t0 = (sp < 2) ? m0 : n0;
        const int row = sr * 16 + (lane >> 2);
        srcs[j] = gp + (size_t)(t0 + row) * kdim + (sp & 1) * 32 + qg * 8;
        d0[j] = sp * 8192 + sr * 512;
    }

    const int NT = kdim >> 6;
    // prologue: tile 0 -> buf 0
#pragma unroll
    for (int j = 0; j < 8; ++j) async_copy16(lds + d0[j], srcs[j]);

    for (int t = 0; t < NT; ++t) {
        const int cur = t & 1;
        if (t + 1 < NT) {
            const int k1 = (t + 1) << 6;
#pragma unroll
            for (int j = 0; j < 8; ++j)
                async_copy16(lds + (cur ^ 1) * 32768 + d0[j], srcs[j] + k1);
            asm volatile("s_waitcnt vmcnt(8)" ::: "memory");
        } else {
            asm volatile("s_waitcnt vmcnt(0)" ::: "memory");
        }
        __builtin_amdgcn_s_barrier();
        __builtin_amdgcn_sched_barrier(0);

        const unsigned short* bb = lds + cur * 32768;
#pragma unroll
        for (int kk = 0; kk < 2; ++kk) {
            s16x8 a[8], b[4];
#pragma unroll
            for (int mi = 0; mi < 8; ++mi)
                a[mi] = *(const s16x8*)(bb + kk * 8192 + (wm + mi * 16 + fr) * 32 + qo);
#pragma unroll
            for (int ni = 0; ni < 4; ++ni)
                b[ni] = *(const s16x8*)(bb + (2 + kk) * 8192 + (wn + ni * 16 + fr) * 32 + qo);
            __builtin_amdgcn_s_setprio(1);
#pragma unroll
            for (int mi = 0; mi < 8; ++mi)
#pragma unroll
                for (int ni = 0; ni < 4; ++ni)
                    acc[mi][ni] = __builtin_amdgcn_mfma_f32_16x16x32_bf16(a[mi], b[ni], acc[mi][ni], 0, 0, 0);
            __builtin_amdgcn_s_setprio(0);
        }
        __builtin_amdgcn_sched_barrier(0);
        __builtin_amdgcn_s_barrier();
        __builtin_amdgcn_sched_barrier(0);
    }

#pragma unroll
    for (int ni = 0; ni < 4; ++ni) {
        const int col = n0 + wn + ni * 16 + fr;
        const float be = bias_n[col];
#pragma unroll
        for (int mi = 0; mi < 8; ++mi) {
            const int rb = m0 + wm + mi * 16 + kq * 4;
            if (EPI == 0) {
                unsigned short* O = (unsigned short*)outp;
#pragma unroll
                for (int r = 0; r < 4; ++r)
                    O[(size_t)(rb + r) * ostride + col] = f2bf(acc[mi][ni][r] + be);
            } else {
                float* O = (float*)outp;
#pragma unroll
                for (int r = 0; r < 4; ++r) {
                    const int m = rb + r;
                    O[(size_t)m * ostride + col] =
                        (acc[mi][ni][r] + be) * (float)stdvv[m] + (float)muv[m];
                }
            }
        }
    }
}

// -------- 128x128 bf16 MFMA GEMM (3-buffer ring) — used for the small aux GEMM ----
template<int EPI>
__global__ __launch_bounds__(256) void mm_kernel(
    const unsigned short* __restrict__ A, const unsigned short* __restrict__ B,
    const int kdim, const int ntiles_x,
    const float* __restrict__ bias_n,
    const double* __restrict__ muv, const double* __restrict__ stdvv,
    void* __restrict__ outp, const long ostride)
{
    __shared__ unsigned short lds[3 * 2 * 128 * 32];  // 3 ring bufs x (A 8KB + B 8KB)
    const int tid = threadIdx.x;
    const int lane = tid & 63, wid = tid >> 6;
    const int cpx = gridDim.x >> 3;
    const int orig = blockIdx.x;
    const int wg = (orig & 7) * cpx + (orig >> 3);
    const int m0 = (wg % ntiles_x) * 128;
    const int n0 = (wg / ntiles_x) * 128;
    const int wm = (wid >> 1) * 64, wn = (wid & 1) * 64;
    const int fr = lane & 15, kq = lane >> 4;
    const int swr = (fr >> 1) & 3;
    const int qg = (lane & 3) ^ ((lane >> 3) & 3);
    const int qo = (kq ^ swr) * 8;

    f32x4 acc[4][4];
#pragma unroll
    for (int i = 0; i < 4; ++i)
#pragma unroll
        for (int j = 0; j < 4; ++j) acc[i][j] = (f32x4){0.f, 0.f, 0.f, 0.f};

    const unsigned short* srcs[4];
    int d0[4];
#pragma unroll
    for (int j = 0; j < 4; ++j) {
        const int s = wid * 4 + j;
        const int pl = s >> 3, sr = s & 7;
        const int r = sr * 16 + (lane >> 2);
        srcs[j] = (pl ? B : A) + (size_t)((pl ? n0 : m0) + r) * kdim + qg * 8;
        d0[j] = pl * 4096 + sr * 512;
    }

    const int NT = kdim >> 5;
#pragma unroll
    for (int j = 0; j < 4; ++j) async_copy16(lds + 0 * 8192 + d0[j], srcs[j]);
#pragma unroll
    for (int j = 0; j < 4; ++j) async_copy16(lds + 1 * 8192 + d0[j], srcs[j] + 32);

    int cur = 0, nxt = 2;
    for (int t = 0; t < NT; ++t) {
        if (t < NT - 1) {
            asm volatile("s_waitcnt vmcnt(4)" ::: "memory");
        } else {
            asm volatile("s_waitcnt vmcnt(0)" ::: "memory");
        }
        __builtin_amdgcn_s_barrier();
        __builtin_amdgcn_sched_barrier(0);

        if (t + 2 < NT) {
            const int k2 = (t + 2) << 5;
#pragma unroll
            for (int j = 0; j < 4; ++j) async_copy16(lds + nxt * 8192 + d0[j], srcs[j] + k2);
        }

        const unsigned short* la = lds + cur * 8192;
        const unsigned short* lb = la + 4096;
        s16x8 a[4], b[4];
#pragma unroll
        for (int i = 0; i < 4; ++i) {
            a[i] = *(const s16x8*)(la + (wm + i * 16 + fr) * 32 + qo);
            b[i] = *(const s16x8*)(lb + (wn + i * 16 + fr) * 32 + qo);
        }
#pragma unroll
        for (int mi = 0; mi < 4; ++mi)
#pragma unroll
            for (int ni = 0; ni < 4; ++ni)
                acc[mi][ni] = __builtin_amdgcn_mfma_f32_16x16x32_bf16(a[mi], b[ni], acc[mi][ni], 0, 0, 0);

        cur = cur == 2 ? 0 : cur + 1;
        nxt = nxt == 2 ? 0 : nxt + 1;
    }

#pragma unroll
    for (int ni = 0; ni < 4; ++ni) {
        const int col = n0 + wn + ni * 16 + fr;
        const float be = bias_n[col];
#pragma unroll
        for (int mi = 0; mi < 4; ++mi) {
            const int rb = m0 + wm + mi * 16 + kq * 4;
            if (EPI == 0) {
                unsigned short* O = (unsigned short*)outp;
#pragma unroll
                for (int r = 0; r < 4; ++r)
                    O[(size_t)(rb + r) * ostride + col] = f2bf(acc[mi][ni][r] + be);
            } else {
                float* O = (float*)outp;
#pragma unroll
                for (int r = 0; r < 4; ++r) {
                    const int m = rb + r;
                    O[(size_t)m * ostride + col] =
                        (acc[mi][ni][r] + be) * (float)stdvv[m] + (float)muv[m];
                }
            }
        }
    }
}

// ---------- topk phase 1: register keys + binary-search cutoff + classify ----
__global__ __launch_bounds__(256) void topk_sel_kernel(
    const unsigned short* __restrict__ p16,
    int* __restrict__ topk_idx, float* __restrict__ topk_val,
    int* __restrict__ sure_cnt, int* __restrict__ tie_cnt, int* __restrict__ cand_col)
{
    const int row = blockIdx.x;
    const int tid = threadIdx.x;
    const int lane = tid & 63, wid = tid >> 6;
    const unsigned short* pr = p16 + (size_t)row * D_HIDDEN;

    __shared__ int red[4];
    __shared__ int sh_sel, sh_tie;

    uint4 kr[16];
#pragma unroll
    for (int i = 0; i < 16; ++i) {
        uint4 w = *(const uint4*)(pr + (i * 256 + tid) * 8);
        w.x = key16x2(w.x); w.y = key16x2(w.y); w.z = key16x2(w.z); w.w = key16x2(w.w);
        kr[i] = w;
    }
    if (tid == 0) { sh_sel = 0; sh_tie = 0; }

    unsigned int lo = 0, hi = 65535;
    while (lo < hi) {
        const unsigned int mid = (lo + hi) >> 1;
        int c = 0;
#pragma unroll
        for (int i = 0; i < 16; ++i) {
            const unsigned int u[4] = {kr[i].x, kr[i].y, kr[i].z, kr[i].w};
#pragma unroll
            for (int e = 0; e < 4; ++e) {
                c += (int)((u[e] & 0xFFFFu) > mid);
                c += (int)((u[e] >> 16) > mid);
            }
        }
#pragma unroll
        for (int off = 32; off > 0; off >>= 1) c += __shfl_down(c, off, 64);
        if (lane == 0) red[wid] = c;
        __syncthreads();
        const int total = red[0] + red[1] + red[2] + red[3];
        if (total < KSEL) hi = mid; else lo = mid + 1;
        __syncthreads();
    }
    const unsigned int K16 = lo;

    const float vc = unkey16(K16);
    const float DLT = 1.3e-2f;
    const float sureT = vc + 2.f * DLT;
    const float candT = vc - 2.f * DLT;
    const unsigned int sK = fkey(sureT) >> 16;
    const unsigned int cK = fkey(candT) >> 16;

    int* oidx = topk_idx + row * KSEL;
    float* oval = topk_val + row * KSEL;
    int* cc = cand_col + row * TIECAP;
#pragma unroll
    for (int i = 0; i < 16; ++i) {
        const int j0 = (i * 256 + tid) * 8;
        const unsigned int u[4] = {kr[i].x, kr[i].y, kr[i].z, kr[i].w};
#pragma unroll
        for (int e = 0; e < 8; ++e) {
            const unsigned int k = (e & 1) ? (u[e >> 1] >> 16) : (u[e >> 1] & 0xFFFFu);
            if (k < cK) continue;
            const float v = unkey16(k);
            if (k > sK && v > sureT) {
                const int pos = atomicAdd(&sh_sel, 1);
                oidx[pos] = j0 + e;
                oval[pos] = v > 0.f ? v : 0.f;
            } else if (v >= candT) {
                const int t = atomicAdd(&sh_tie, 1);
                if (t < TIECAP) cc[t] = j0 + e;
            }
        }
    }
    __syncthreads();
    if (tid == 0) {
        sure_cnt[row] = sh_sel;
        tie_cnt[row] = sh_tie > TIECAP ? TIECAP : sh_tie;
    }
}

// ---------- topk phase 2: exact fp64 refinement, one wave per candidate ----
__global__ __launch_bounds__(256) void topk_refine_kernel(
    const int* __restrict__ tie_cnt, const int* __restrict__ cand_col,
    double* __restrict__ cand_val,
    const float* __restrict__ x, const double* __restrict__ mu, const double* __restrict__ sinv,
    const float* __restrict__ b_pre, const float* __restrict__ wT, const float* __restrict__ b_enc)
{
    const int row = blockIdx.x;
    const int tid = threadIdx.x;
    const int lane = tid & 63, wid = tid >> 6;
    const int T = tie_cnt[row];
    const int base = (int)blockIdx.y * 4 + wid;   // gridDim.y = 16 -> base in [0,64)
    if (base >= T) return;
    const double m_ = mu[row], si = sinv[row];
    const float* xr = x + (size_t)row * D_MODEL;
    for (int slot = base; slot < T; slot += 64) {
        const int col = cand_col[row * TIECAP + slot];
        const float* wr = wT + (size_t)col * D_MODEL;
        double s0 = 0.0, s1 = 0.0;
        for (int k = lane * 4; k < D_MODEL; k += 512) {
            {
                const float4 xv = *(const float4*)(xr + k);
                const float4 bp = *(const float4*)(b_pre + k);
                const float4 wv4 = *(const float4*)(wr + k);
                s0 += (((double)xv.x - m_) * si - (double)bp.x) * (double)wv4.x;
                s0 += (((double)xv.y - m_) * si - (double)bp.y) * (double)wv4.y;
                s0 += (((double)xv.z - m_) * si - (double)bp.z) * (double)wv4.z;
                s0 += (((double)xv.w - m_) * si - (double)bp.w) * (double)wv4.w;
            }
            {
                const int k2 = k + 256;
                const float4 xv = *(const float4*)(xr + k2);
                const float4 bp = *(const float4*)(b_pre + k2);
                const float4 wv4 = *(const float4*)(wr + k2);
                s1 += (((double)xv.x - m_) * si - (double)bp.x) * (double)wv4.x;
                s1 += (((double)xv.y - m_) * si - (double)bp.y) * (double)wv4.y;
                s1 += (((double)xv.z - m_) * si - (double)bp.z) * (double)wv4.z;
                s1 += (((double)xv.w - m_) * si - (double)bp.w) * (double)wv4.w;
            }
        }
        double s = s0 + s1;
#pragma unroll
        for (int off = 32; off > 0; off >>= 1) s += __shfl_down(s, off, 64);
        if (lane == 0) cand_val[row * TIECAP + slot] = s + (double)b_enc[col];
    }
}

// ---------- topk phase 3: parallel rank among candidates, scatter outputs ----
__global__ __launch_bounds__(256) void topk_fin_kernel(
    const int* __restrict__ sure_cnt, const int* __restrict__ tie_cnt,
    const int* __restrict__ cand_col, const double* __restrict__ cand_val,
    int* __restrict__ topk_idx, float* __restrict__ topk_val)
{
    const int row = blockIdx.x;
    const int tid = threadIdx.x;
    __shared__ double vals[TIECAP];
    __shared__ int cols[TIECAP];
    const int G = sure_cnt[row];
    const int T = tie_cnt[row];
    const int R = KSEL - G;
    if (tid < T) {
        vals[tid] = cand_val[row * TIECAP + tid];
        cols[tid] = cand_col[row * TIECAP + tid];
    }
    __syncthreads();
    int* oidx = topk_idx + row * KSEL;
    float* oval = topk_val + row * KSEL;
    if (tid < T) {
        const double v = vals[tid];
        const int c = cols[tid];
        int rank = 0;
        for (int u = 0; u < T; ++u) {
            const double vu = vals[u];
            rank += (int)((vu > v) || (vu == v && cols[u] < c));
        }
        if (rank < R) {
            oidx[G + rank] = c;
            oval[G + rank] = v > 0.0 ? (float)v : 0.f;
        }
    }
    const int take = R < T ? R : T;
    if (tid >= take && tid < R) {
        oidx[G + tid] = (T > 0) ? cols[0] : 0;
        oval[G + tid] = 0.f;
    }
}

// -------------------- w_dec -> bf16 row-major copy --------------------
__global__ __launch_bounds__(256) void wdec2bf_kernel(
    const float* __restrict__ w_dec, unsigned short* __restrict__ wd16)
{
    const size_t gid = (size_t)blockIdx.x * 256 + threadIdx.x;
    const size_t base = gid * 8;
    const float4 a = *(const float4*)(w_dec + base);
    const float4 b = *(const float4*)(w_dec + base + 4);
    uint4 o;
    o.x = (unsigned)f2bf(a.x) | ((unsigned)f2bf(a.y) << 16);
    o.y = (unsigned)f2bf(a.z) | ((unsigned)f2bf(a.w) << 16);
    o.z = (unsigned)f2bf(b.x) | ((unsigned)f2bf(b.y) << 16);
    o.w = (unsigned)f2bf(b.z) | ((unsigned)f2bf(b.w) << 16);
    *(uint4*)(wd16 + base) = o;
}

// -------------------- sparse decode: recons (bf16 w_dec) --------------------
__global__ __launch_bounds__(256) void decode_kernel(
    const int* __restrict__ topk_idx, const float* __restrict__ topk_val,
    const unsigned short* __restrict__ wd16, const float* __restrict__ b_pre,
    const double* __restrict__ mu, const double* __restrict__ stdv,
    float* __restrict__ out0)
{
    const int row = blockIdx.x;
    const int tid = threadIdx.x;
    __shared__ int sidx[KSEL];
    __shared__ float sval[KSEL];
    if (tid < KSEL) {
        sidx[tid] = topk_idx[row * KSEL + tid];
        sval[tid] = topk_val[row * KSEL + tid];
    }
    __syncthreads();
    float acc[16];
#pragma unroll
    for (int i = 0; i < 16; ++i) acc[i] = 0.f;
    const int dbase = tid * 16;
    for (int k = 0; k < KSEL; ++k) {
        const float v = sval[k];
        if (v == 0.f) continue;
        const uint4* wr = (const uint4*)(wd16 + (size_t)sidx[k] * D_MODEL + dbase);
        const uint4 w0 = wr[0], w1 = wr[1];
        const unsigned int u[8] = {w0.x, w0.y, w0.z, w0.w, w1.x, w1.y, w1.z, w1.w};
#pragma unroll
        for (int i = 0; i < 8; ++i) {
            acc[2 * i]     += v * __uint_as_float(u[i] << 16);
            acc[2 * i + 1] += v * __uint_as_float(u[i] & 0xFFFF0000u);
        }
    }
    const float st = (float)stdv[row];
    const float mm = (float)mu[row];
    float* o = out0 + (size_t)row * D_MODEL + dbase;
#pragma unroll
    for (int i = 0; i < 16; ++i) {
        o[i] = (acc[i] + b_pre[dbase + i]) * st + mm;
    }
}

// -------------------- aux A gather+relu (bf16 passthrough) --------------------
__global__ __launch_bounds__(256) void auxg_kernel(
    const unsigned short* __restrict__ p16, const int* __restrict__ dead_idx,
    const int* __restrict__ dead_cnt, unsigned short* __restrict__ Ahd)
{
    const int r = blockIdx.x;
    const int tid = threadIdx.x;
    const int dc = *dead_cnt;
#pragma unroll
    for (int i = 0; i < 8; ++i) {
        const int c = i * 256 + tid;
        unsigned short v = 0;
        if (c < dc) {
            const unsigned short u = p16[(size_t)r * D_HIDDEN + dead_idx[c]];
            v = (u & 0x8000u) ? (unsigned short)0 : u;   // relu on bf16 bits
        }
        Ahd[(size_t)r * NDEAD + c] = v;
    }
}

// -------------------- aux B gather+transpose (bf16) --------------------
__global__ __launch_bounds__(256) void auxb_kernel(
    const float* __restrict__ w_dec, const int* __restrict__ dead_idx,
    unsigned short* __restrict__ Bhd)
{
    __shared__ float t[32][33];
    const int k0 = blockIdx.x * 32;
    const int n0 = blockIdx.y * 32;
    const int tid = threadIdx.x;
    const int i = tid >> 3, j4 = (tid & 7) * 4;
    const int srow = dead_idx[k0 + i];
    const float4 v = *(const float4*)(w_dec + (size_t)srow * D_MODEL + n0 + j4);
    t[i][j4 + 0] = v.x; t[i][j4 + 1] = v.y; t[i][j4 + 2] = v.z; t[i][j4 + 3] = v.w;
    __syncthreads();
    const int j = tid >> 3, i4 = (tid & 7) * 4;
    uint2 hw;
    hw.x = (unsigned)f2bf(t[i4 + 0][j]) | ((unsigned)f2bf(t[i4 + 1][j]) << 16);
    hw.y = (unsigned)f2bf(t[i4 + 2][j]) | ((unsigned)f2bf(t[i4 + 3][j]) << 16);
    *(uint2*)(Bhd + (size_t)(n0 + j) * NDEAD + k0 + i4) = hw;
}

// -------------------- launch --------------------
extern "C" void kernel_launch(void* const* d_in, const int* in_sizes, int n_in,
                              void* d_out, int out_size, void* d_ws, size_t ws_size,
                              hipStream_t stream)
{
    (void)in_sizes; (void)n_in; (void)out_size; (void)ws_size;
    const float* x      = (const float*)d_in[0];
    const float* w_enc  = (const float*)d_in[1];
    const float* w_dec  = (const float*)d_in[2];
    const float* b_enc  = (const float*)d_in[3];
    const float* b_pre  = (const float*)d_in[4];
    const unsigned char* dead_mask = (const unsigned char*)d_in[5];
    const int* num_dead = (const int*)d_in[6];
    float* out = (float*)d_out;

    char* base = (char*)d_ws;
    char* w = base;
    auto alloc = [&](size_t bytes) -> char* {
        char* p = w;
        w += (bytes + 255) & ~(size_t)255;
        return p;
    };
    unsigned short* p16 = (unsigned short*)alloc((size_t)BATCH * D_HIDDEN * 2); // 128 MB
    double* mu       = (double*)alloc((size_t)BATCH * 8);
    double* stdv     = (double*)alloc((size_t)BATCH * 8);
    double* sinv     = (double*)alloc((size_t)BATCH * 8);
    int* topk_idx    = (int*)alloc((size_t)BATCH * KSEL * 4);
    float* topk_val  = (float*)alloc((size_t)BATCH * KSEL * 4);
    int* dead_idx    = (int*)alloc((size_t)NDEAD * 4);
    int* dead_cnt    = (int*)alloc(256);
    int* sure_cnt    = (int*)alloc((size_t)BATCH * 4);
    int* tie_cnt     = (int*)alloc((size_t)BATCH * 4);
    int* cand_col    = (int*)alloc((size_t)BATCH * TIECAP * 4);      // 2 MB
    double* cand_val = (double*)alloc((size_t)BATCH * TIECAP * 8);   // 4 MB
    unsigned short* Ahp = (unsigned short*)alloc((size_t)BATCH * D_MODEL * 2);    // 16 MB
    char* region     = alloc((size_t)D_HIDDEN * D_MODEL * 4);                     // 512 MB

    // time-multiplexed region:
    unsigned short* Bhp = (unsigned short*)region;                 // 256 MB, enc phase
    float* wT   = (float*)region;                                  // 512 MB, topk phase
    unsigned short* wd16 = (unsigned short*)region;                // 256 MB, decode phase
    unsigned short* Bhd  = (unsigned short*)(region + (size_t)D_HIDDEN * D_MODEL * 2); // 16 MB
    unsigned short* Ahd  = Ahp;                                    // 8 MB (Ahp dead after enc)

    float* out0 = out;                                   // recons
    float* out1 = out + (size_t)BATCH * D_MODEL;         // auxk
    float* out_last = out + (size_t)2 * BATCH * D_MODEL; // num_dead

    ln_kernel<<<BATCH, 256, 0, stream>>>(x, mu, stdv, sinv);
    dead_scan_kernel<<<1, 64, 0, stream>>>(dead_mask, dead_idx, dead_cnt, num_dead, out_last);
    asplit_kernel<<<BATCH, 256, 0, stream>>>(x, mu, sinv, b_pre, Ahp);
    bsplit_kernel<<<dim3(D_MODEL / 32, D_HIDDEN / 32), 256, 0, stream>>>(w_enc, Bhp);
    mm256_kernel<0><<<(BATCH / 256) * (D_HIDDEN / 256), 512, 0, stream>>>(
        Ahp, Bhp, D_MODEL, BATCH / 256, b_enc, nullptr, nullptr, p16, (long)D_HIDDEN);
    wencT_kernel<<<dim3(D_MODEL / 32, D_HIDDEN / 32), 256, 0, stream>>>(w_enc, wT);
    topk_sel_kernel<<<BATCH, 256, 0, stream>>>(p16, topk_idx, topk_val, sure_cnt, tie_cnt, cand_col);
    topk_refine_kernel<<<dim3(BATCH, 16), 256, 0, stream>>>(
        tie_cnt, cand_col, cand_val, x, mu, sinv, b_pre, wT, b_enc);
    topk_fin_kernel<<<BATCH, 256, 0, stream>>>(
        sure_cnt, tie_cnt, cand_col, cand_val, topk_idx, topk_val);
    auxg_kernel<<<BATCH, 256, 0, stream>>>(p16, dead_idx, dead_cnt, Ahd);
    auxb_kernel<<<dim3(NDEAD / 32, D_MODEL / 32), 256, 0, stream>>>(w_dec, dead_idx, Bhd);
    wdec2bf_kernel<<<(int)(((size_t)D_HIDDEN * D_MODEL) / (256 * 8)), 256, 0, stream>>>(w_dec, wd16);
    decode_kernel<<<BATCH, 256, 0, stream>>>(topk_idx, topk_val, wd16, b_pre, mu, stdv, out0);
    mm_kernel<1><<<(BATCH / 128) * (D_MODEL / 128), 256, 0, stream>>>(
        Ahd, Bhd, NDEAD, BATCH / 128, b_pre, mu, stdv, out1, (long)D_MODEL);
}

// Round 11
// 2241.711 us; speedup vs baseline: 1.6801x; 1.0235x over previous
//
#include <hip/hip_runtime.h>
#include <math.h>

#define D_MODEL  4096
#define D_HIDDEN 32768
#define BATCH    2048
#define KSEL     128
#define NDEAD    2048
#define TIECAP   256

typedef short s16x8 __attribute__((ext_vector_type(8)));
typedef float f32x4 __attribute__((ext_vector_type(4)));

// -------------------- helpers --------------------
__device__ __forceinline__ unsigned int fkey(float f) {
    unsigned int u = __float_as_uint(f);
    return (u & 0x80000000u) ? ~u : (u | 0x80000000u);
}
__device__ __forceinline__ unsigned short f2bf(float f) {  // RTNE
    unsigned int u = __float_as_uint(f);
    u += 0x7FFFu + ((u >> 16) & 1u);
    return (unsigned short)(u >> 16);
}
__device__ __forceinline__ float bf2f(unsigned short h) {
    return __uint_as_float(((unsigned int)h) << 16);
}
// per-16-bit-lane order-preserving key transform (packed pair)
__device__ __forceinline__ unsigned int key16x2(unsigned int u) {
    const unsigned int s = (u >> 15) & 0x10001u;
    const unsigned int mask = s * 0xFFFFu;
    return (u ^ mask) | (~mask & 0x80008000u);
}
__device__ __forceinline__ float unkey16(unsigned int k) {  // 16-bit key -> float
    const unsigned int u = (k & 0x8000u) ? (k & 0x7FFFu) : (~k & 0xFFFFu);
    return __uint_as_float(u << 16);
}
__device__ __forceinline__ void async_copy16(void* lds_dst, const void* gsrc) {
    __builtin_amdgcn_global_load_lds(
        (const __attribute__((address_space(1))) unsigned int*)gsrc,
        (__attribute__((address_space(3))) unsigned int*)lds_dst,
        16, 0, 0);
}

// -------------------- LayerNorm (fp64 stats) --------------------
__global__ __launch_bounds__(256) void ln_kernel(const float* __restrict__ x,
        double* __restrict__ mu, double* __restrict__ stdv, double* __restrict__ sinv)
{
    const int row = blockIdx.x;
    const int tid = threadIdx.x;
    const float* xr = x + (size_t)row * D_MODEL;
    float xv[16];
#pragma unroll
    for (int i = 0; i < 16; ++i) xv[i] = xr[tid + 256 * i];
    double s = 0.0;
#pragma unroll
    for (int i = 0; i < 16; ++i) s += (double)xv[i];
    __shared__ double red[4];
    __shared__ double sh_mu;
    const int lane = tid & 63, wid = tid >> 6;
#pragma unroll
    for (int off = 32; off > 0; off >>= 1) s += __shfl_down(s, off, 64);
    if (lane == 0) red[wid] = s;
    __syncthreads();
    if (tid == 0) sh_mu = (red[0] + red[1] + red[2] + red[3]) / (double)D_MODEL;
    __syncthreads();
    const double m = sh_mu;
    double s2 = 0.0;
#pragma unroll
    for (int i = 0; i < 16; ++i) { double d = (double)xv[i] - m; s2 += d * d; }
#pragma unroll
    for (int off = 32; off > 0; off >>= 1) s2 += __shfl_down(s2, off, 64);
    __syncthreads();
    if (lane == 0) red[wid] = s2;
    __syncthreads();
    if (tid == 0) {
        double var = (red[0] + red[1] + red[2] + red[3]) / (double)(D_MODEL - 1);
        double sd = sqrt(var);
        mu[row] = m;
        stdv[row] = sd;
        sinv[row] = 1.0 / (sd + 1e-5);
    }
}

// -------------------- dead-mask scan --------------------
__global__ void dead_scan_kernel(const unsigned char* __restrict__ mask8,
                                 int* __restrict__ dead_idx, int* __restrict__ dead_cnt,
                                 const int* __restrict__ num_dead_in, float* __restrict__ out_last)
{
    const int lane = threadIdx.x; // 64 threads, one wave
    int c = 0;
    for (int j = lane; j < D_HIDDEN; j += 64) c += (mask8[j] != 0);
#pragma unroll
    for (int off = 32; off > 0; off >>= 1) c += __shfl_down(c, off, 64);
    const int total_u8 = __shfl(c, 0, 64);
    const bool u8mode = (total_u8 == NDEAD);
    const int* mask32 = (const int*)mask8;
    int cnt = 0;
    for (int base = 0; base < D_HIDDEN; base += 64) {
        const int j = base + lane;
        const bool d = u8mode ? (mask8[j] != 0) : (mask32[j] != 0);
        const unsigned long long b = __ballot(d);
        const int pre = __popcll(b & ((1ull << lane) - 1ull));
        if (d && (cnt + pre) < NDEAD) dead_idx[cnt + pre] = j;
        cnt += __popcll(b);
    }
    const int cc = cnt > NDEAD ? NDEAD : cnt;
    if (lane == 0) {
        *dead_cnt = cc;
        *out_last = (float)(*num_dead_in);
    }
    for (int t = cc + lane; t < NDEAD; t += 64) dead_idx[t] = 0;
}

// -------------------- A: xc -> bf16 --------------------
__global__ __launch_bounds__(256) void asplit_kernel(
    const float* __restrict__ x, const double* __restrict__ mu, const double* __restrict__ sinv,
    const float* __restrict__ b_pre, unsigned short* __restrict__ Ahp)
{
    const int row = blockIdx.x, tid = threadIdx.x;
    const double m = mu[row], si = sinv[row];
    const float* xr = x + (size_t)row * D_MODEL;
#pragma unroll
    for (int i = 0; i < 4; ++i) {
        const int j = (i * 256 + tid) * 4;
        const float4 xv = *(const float4*)(xr + j);
        const float4 bp = *(const float4*)(b_pre + j);
        float v[4];
        v[0] = (float)(((double)xv.x - m) * si) - bp.x;
        v[1] = (float)(((double)xv.y - m) * si) - bp.y;
        v[2] = (float)(((double)xv.z - m) * si) - bp.z;
        v[3] = (float)(((double)xv.w - m) * si) - bp.w;
        uint2 hw;
        hw.x = (unsigned)f2bf(v[0]) | ((unsigned)f2bf(v[1]) << 16);
        hw.y = (unsigned)f2bf(v[2]) | ((unsigned)f2bf(v[3]) << 16);
        *(uint2*)(Ahp + (size_t)row * D_MODEL + j) = hw;
    }
}

// -------------------- B: w_enc[k][n] -> Bh[n][k] bf16 --------------------
__global__ __launch_bounds__(256) void bsplit_kernel(
    const float* __restrict__ w_enc, unsigned short* __restrict__ Bhp)
{
    __shared__ float t[32][33];
    const int bk = blockIdx.x * 32;
    const int bn = blockIdx.y * 32;
    const int tid = threadIdx.x;
    const int lr = tid >> 3, lc4 = (tid & 7) * 4;
    const float4 v = *(const float4*)(w_enc + (size_t)(bk + lr) * D_HIDDEN + bn + lc4);
    t[lr][lc4 + 0] = v.x; t[lr][lc4 + 1] = v.y; t[lr][lc4 + 2] = v.z; t[lr][lc4 + 3] = v.w;
    __syncthreads();
    float o[4];
#pragma unroll
    for (int j = 0; j < 4; ++j) o[j] = t[lc4 + j][lr];
    uint2 hw;
    hw.x = (unsigned)f2bf(o[0]) | ((unsigned)f2bf(o[1]) << 16);
    hw.y = (unsigned)f2bf(o[2]) | ((unsigned)f2bf(o[3]) << 16);
    *(uint2*)(Bhp + (size_t)(bn + lr) * D_MODEL + bk + lc4) = hw;
}

// -------------------- w_enc transpose to fp32 [n][k] --------------------
__global__ __launch_bounds__(256) void wencT_kernel(
    const float* __restrict__ w_enc, float* __restrict__ wT)
{
    __shared__ float t[32][33];
    const int bk = blockIdx.x * 32;
    const int bn = blockIdx.y * 32;
    const int tid = threadIdx.x;
    const int lr = tid >> 3, lc4 = (tid & 7) * 4;
    const float4 v = *(const float4*)(w_enc + (size_t)(bk + lr) * D_HIDDEN + bn + lc4);
    t[lr][lc4 + 0] = v.x; t[lr][lc4 + 1] = v.y; t[lr][lc4 + 2] = v.z; t[lr][lc4 + 3] = v.w;
    __syncthreads();
    const int j = tid >> 3, i4 = (tid & 7) * 4;
    float4 o;
    o.x = t[i4 + 0][j]; o.y = t[i4 + 1][j]; o.z = t[i4 + 2][j]; o.w = t[i4 + 3][j];
    *(float4*)(wT + (size_t)(bn + j) * D_MODEL + bk + i4) = o;
}

// ======== 256x256 bf16 MFMA GEMM, BK=64, 8 waves, 4-phase/K-tile, half-tile pipe ====
// LDS per buf: 4 subplanes [256][32] bf16: sp0=A-kk0, sp1=A-kk1, sp2=B-kk0, sp3=B-kk1.
// Half-tiles: H0 = {sp0,sp2} (koff 0), H1 = {sp1,sp3} (koff 32); 4 loads/wave each.
// Pipeline ledger (per wave, issue order == completion order):
//   prologue: H0(0),H1(0),H0(1)  -> 12 in flight
//   tile t, kk0-boundary: vmcnt(8) waits H0(t)  [then issue H1(t+1) in phases A1,A2]
//   tile t, kk1-boundary: vmcnt(8) waits H1(t)  [then issue H0(t+2) in phases B1,B2]
//   H0(t+2) targets bb's sp0/sp2 -- disjoint from phB reads (sp1/sp3); all kk0 reads
//   completed before the kk1-boundary barrier. Last tiles: vmcnt(4)/vmcnt(0).
// MFMA per-fragment K-order identical to the 2-phase version -> bitwise-same output.
template<int EPI>
__global__ __launch_bounds__(512) void mm256_kernel(
    const unsigned short* __restrict__ A, const unsigned short* __restrict__ B,
    const int kdim, const int ntiles_x,
    const float* __restrict__ bias_n,
    const double* __restrict__ muv, const double* __restrict__ stdvv,
    void* __restrict__ outp, const long ostride)
{
    __shared__ unsigned short lds[2 * 4 * 8192];   // 128 KB: 2 bufs x 4 subplanes
    const int tid = threadIdx.x;
    const int lane = tid & 63, wid = tid >> 6;     // 8 waves
    const int cpx = gridDim.x >> 3;                // XCD swizzle (grid % 8 == 0)
    const int orig = blockIdx.x;
    const int wg = (orig & 7) * cpx + (orig >> 3);
    const int m0 = (wg % ntiles_x) * 256;
    const int n0 = (wg / ntiles_x) * 256;
    const int wm = (wid >> 2) * 128;               // 2 M-halves
    const int wn = (wid & 3) * 64;                 // 4 N-quarters
    const int fr = lane & 15, kq = lane >> 4;
    const int swr = (fr >> 1) & 3;                 // read-side quad XOR
    const int qg = (lane & 3) ^ ((lane >> 3) & 3); // write-side source quad
    const int qo = (kq ^ swr) * 8;

    f32x4 acc[8][4];
#pragma unroll
    for (int i = 0; i < 8; ++i)
#pragma unroll
        for (int j = 0; j < 4; ++j) acc[i][j] = (f32x4){0.f, 0.f, 0.f, 0.f};

    // H0 seg addressing: 32 segs (16 A + 16 B), 4 per wave; seg = 16 rows x 32 cols.
    const unsigned short* sH0[4];
    int dH0[4];
#pragma unroll
    for (int j = 0; j < 4; ++j) {
        const int g = wid * 4 + j;
        const int is_b = g >> 4;
        const int sr = g & 15;
        const unsigned short* gp = is_b ? B : A;
        const int t0 = is_b ? n0 : m0;
        sH0[j] = gp + (size_t)(t0 + sr * 16 + (lane >> 2)) * kdim + qg * 8;
        dH0[j] = (is_b ? 2 : 0) * 8192 + sr * 512;
    }
    // H1: src = sH0[j] + 32 (k offset), dst = dH0[j] + 8192 (sp0->sp1, sp2->sp3)

    const int NT = kdim >> 6;
    // prologue: H0(0), H1(0) -> buf0 ; H0(1) -> buf1   (12 loads/wave in flight)
#pragma unroll
    for (int j = 0; j < 4; ++j) async_copy16(lds + dH0[j], sH0[j]);
#pragma unroll
    for (int j = 0; j < 4; ++j) async_copy16(lds + 8192 + dH0[j], sH0[j] + 32);
    if (NT > 1) {
#pragma unroll
        for (int j = 0; j < 4; ++j) async_copy16(lds + 32768 + dH0[j], sH0[j] + 64);
    }

    for (int t = 0; t < NT; ++t) {
        const int cur = t & 1;
        unsigned short* bb = (unsigned short*)lds + cur * 32768;
        unsigned short* nb = (unsigned short*)lds + (cur ^ 1) * 32768;
        const int k1 = (t + 1) << 6;
        const int k2 = (t + 2) << 6;

        // ======== kk0 half: wait H0(t) ========
        if (t < NT - 1) { asm volatile("s_waitcnt vmcnt(8)" ::: "memory"); }
        else            { asm volatile("s_waitcnt vmcnt(4)" ::: "memory"); }
        asm volatile("s_barrier" ::: "memory");
        __builtin_amdgcn_sched_barrier(0);
        {
            // --- phase A1: lower-M quadrant, kk0 ---
            if (t + 1 < NT) {
                async_copy16(nb + 8192 + dH0[0], sH0[0] + k1 + 32);
                async_copy16(nb + 8192 + dH0[1], sH0[1] + k1 + 32);
            }
            s16x8 a[4], b[4];
#pragma unroll
            for (int mi = 0; mi < 4; ++mi)
                a[mi] = *(const s16x8*)(bb + (wm + mi * 16 + fr) * 32 + qo);
#pragma unroll
            for (int ni = 0; ni < 4; ++ni)
                b[ni] = *(const s16x8*)(bb + 2 * 8192 + (wn + ni * 16 + fr) * 32 + qo);
            __builtin_amdgcn_s_setprio(1);
#pragma unroll
            for (int mi = 0; mi < 4; ++mi)
#pragma unroll
                for (int ni = 0; ni < 4; ++ni)
                    acc[mi][ni] = __builtin_amdgcn_mfma_f32_16x16x32_bf16(a[mi], b[ni], acc[mi][ni], 0, 0, 0);
            __builtin_amdgcn_s_setprio(0);
            asm volatile("s_barrier" ::: "memory");
            __builtin_amdgcn_sched_barrier(0);
            // --- phase A2: upper-M quadrant, kk0 ---
            if (t + 1 < NT) {
                async_copy16(nb + 8192 + dH0[2], sH0[2] + k1 + 32);
                async_copy16(nb + 8192 + dH0[3], sH0[3] + k1 + 32);
            }
            s16x8 a2[4];
#pragma unroll
            for (int mi = 0; mi < 4; ++mi)
                a2[mi] = *(const s16x8*)(bb + (wm + (mi + 4) * 16 + fr) * 32 + qo);
            __builtin_amdgcn_s_setprio(1);
#pragma unroll
            for (int mi = 0; mi < 4; ++mi)
#pragma unroll
                for (int ni = 0; ni < 4; ++ni)
                    acc[mi + 4][ni] = __builtin_amdgcn_mfma_f32_16x16x32_bf16(a2[mi], b[ni], acc[mi + 4][ni], 0, 0, 0);
            __builtin_amdgcn_s_setprio(0);
        }
        // ======== kk1 half: wait H1(t) ========
        if (t < NT - 1) { asm volatile("s_waitcnt vmcnt(8)" ::: "memory"); }
        else            { asm volatile("s_waitcnt vmcnt(0)" ::: "memory"); }
        asm volatile("s_barrier" ::: "memory");
        __builtin_amdgcn_sched_barrier(0);
        {
            // --- phase B1: lower-M quadrant, kk1 ---
            if (t + 2 < NT) {
                async_copy16(bb + dH0[0], sH0[0] + k2);
                async_copy16(bb + dH0[1], sH0[1] + k2);
            }
            s16x8 a[4], b[4];
#pragma unroll
            for (int mi = 0; mi < 4; ++mi)
                a[mi] = *(const s16x8*)(bb + 8192 + (wm + mi * 16 + fr) * 32 + qo);
#pragma unroll
            for (int ni = 0; ni < 4; ++ni)
                b[ni] = *(const s16x8*)(bb + 3 * 8192 + (wn + ni * 16 + fr) * 32 + qo);
            __builtin_amdgcn_s_setprio(1);
#pragma unroll
            for (int mi = 0; mi < 4; ++mi)
#pragma unroll
                for (int ni = 0; ni < 4; ++ni)
                    acc[mi][ni] = __builtin_amdgcn_mfma_f32_16x16x32_bf16(a[mi], b[ni], acc[mi][ni], 0, 0, 0);
            __builtin_amdgcn_s_setprio(0);
            asm volatile("s_barrier" ::: "memory");
            __builtin_amdgcn_sched_barrier(0);
            // --- phase B2: upper-M quadrant, kk1 ---
            if (t + 2 < NT) {
                async_copy16(bb + dH0[2], sH0[2] + k2);
                async_copy16(bb + dH0[3], sH0[3] + k2);
            }
            s16x8 a2[4];
#pragma unroll
            for (int mi = 0; mi < 4; ++mi)
                a2[mi] = *(const s16x8*)(bb + 8192 + (wm + (mi + 4) * 16 + fr) * 32 + qo);
            __builtin_amdgcn_s_setprio(1);
#pragma unroll
            for (int mi = 0; mi < 4; ++mi)
#pragma unroll
                for (int ni = 0; ni < 4; ++ni)
                    acc[mi + 4][ni] = __builtin_amdgcn_mfma_f32_16x16x32_bf16(a2[mi], b[ni], acc[mi + 4][ni], 0, 0, 0);
            __builtin_amdgcn_s_setprio(0);
        }
        // next tile begins with vmcnt + barrier (no extra barrier needed here)
    }

#pragma unroll
    for (int ni = 0; ni < 4; ++ni) {
        const int col = n0 + wn + ni * 16 + fr;
        const float be = bias_n[col];
#pragma unroll
        for (int mi = 0; mi < 8; ++mi) {
            const int rb = m0 + wm + mi * 16 + kq * 4;
            if (EPI == 0) {
                unsigned short* O = (unsigned short*)outp;
#pragma unroll
                for (int r = 0; r < 4; ++r)
                    O[(size_t)(rb + r) * ostride + col] = f2bf(acc[mi][ni][r] + be);
            } else {
                float* O = (float*)outp;
#pragma unroll
                for (int r = 0; r < 4; ++r) {
                    const int m = rb + r;
                    O[(size_t)m * ostride + col] =
                        (acc[mi][ni][r] + be) * (float)stdvv[m] + (float)muv[m];
                }
            }
        }
    }
}

// -------- 128x128 bf16 MFMA GEMM (3-buffer ring) — used for the small aux GEMM ----
template<int EPI>
__global__ __launch_bounds__(256) void mm_kernel(
    const unsigned short* __restrict__ A, const unsigned short* __restrict__ B,
    const int kdim, const int ntiles_x,
    const float* __restrict__ bias_n,
    const double* __restrict__ muv, const double* __restrict__ stdvv,
    void* __restrict__ outp, const long ostride)
{
    __shared__ unsigned short lds[3 * 2 * 128 * 32];  // 3 ring bufs x (A 8KB + B 8KB)
    const int tid = threadIdx.x;
    const int lane = tid & 63, wid = tid >> 6;
    const int cpx = gridDim.x >> 3;
    const int orig = blockIdx.x;
    const int wg = (orig & 7) * cpx + (orig >> 3);
    const int m0 = (wg % ntiles_x) * 128;
    const int n0 = (wg / ntiles_x) * 128;
    const int wm = (wid >> 1) * 64, wn = (wid & 1) * 64;
    const int fr = lane & 15, kq = lane >> 4;
    const int swr = (fr >> 1) & 3;
    const int qg = (lane & 3) ^ ((lane >> 3) & 3);
    const int qo = (kq ^ swr) * 8;

    f32x4 acc[4][4];
#pragma unroll
    for (int i = 0; i < 4; ++i)
#pragma unroll
        for (int j = 0; j < 4; ++j) acc[i][j] = (f32x4){0.f, 0.f, 0.f, 0.f};

    const unsigned short* srcs[4];
    int d0[4];
#pragma unroll
    for (int j = 0; j < 4; ++j) {
        const int s = wid * 4 + j;
        const int pl = s >> 3, sr = s & 7;
        const int r = sr * 16 + (lane >> 2);
        srcs[j] = (pl ? B : A) + (size_t)((pl ? n0 : m0) + r) * kdim + qg * 8;
        d0[j] = pl * 4096 + sr * 512;
    }

    const int NT = kdim >> 5;
#pragma unroll
    for (int j = 0; j < 4; ++j) async_copy16(lds + 0 * 8192 + d0[j], srcs[j]);
#pragma unroll
    for (int j = 0; j < 4; ++j) async_copy16(lds + 1 * 8192 + d0[j], srcs[j] + 32);

    int cur = 0, nxt = 2;
    for (int t = 0; t < NT; ++t) {
        if (t < NT - 1) {
            asm volatile("s_waitcnt vmcnt(4)" ::: "memory");
        } else {
            asm volatile("s_waitcnt vmcnt(0)" ::: "memory");
        }
        __builtin_amdgcn_s_barrier();
        __builtin_amdgcn_sched_barrier(0);

        if (t + 2 < NT) {
            const int k2 = (t + 2) << 5;
#pragma unroll
            for (int j = 0; j < 4; ++j) async_copy16(lds + nxt * 8192 + d0[j], srcs[j] + k2);
        }

        const unsigned short* la = lds + cur * 8192;
        const unsigned short* lb = la + 4096;
        s16x8 a[4], b[4];
#pragma unroll
        for (int i = 0; i < 4; ++i) {
            a[i] = *(const s16x8*)(la + (wm + i * 16 + fr) * 32 + qo);
            b[i] = *(const s16x8*)(lb + (wn + i * 16 + fr) * 32 + qo);
        }
#pragma unroll
        for (int mi = 0; mi < 4; ++mi)
#pragma unroll
            for (int ni = 0; ni < 4; ++ni)
                acc[mi][ni] = __builtin_amdgcn_mfma_f32_16x16x32_bf16(a[mi], b[ni], acc[mi][ni], 0, 0, 0);

        cur = cur == 2 ? 0 : cur + 1;
        nxt = nxt == 2 ? 0 : nxt + 1;
    }

#pragma unroll
    for (int ni = 0; ni < 4; ++ni) {
        const int col = n0 + wn + ni * 16 + fr;
        const float be = bias_n[col];
#pragma unroll
        for (int mi = 0; mi < 4; ++mi) {
            const int rb = m0 + wm + mi * 16 + kq * 4;
            if (EPI == 0) {
                unsigned short* O = (unsigned short*)outp;
#pragma unroll
                for (int r = 0; r < 4; ++r)
                    O[(size_t)(rb + r) * ostride + col] = f2bf(acc[mi][ni][r] + be);
            } else {
                float* O = (float*)outp;
#pragma unroll
                for (int r = 0; r < 4; ++r) {
                    const int m = rb + r;
                    O[(size_t)m * ostride + col] =
                        (acc[mi][ni][r] + be) * (float)stdvv[m] + (float)muv[m];
                }
            }
        }
    }
}

// ---------- topk phase 1: register keys + binary-search cutoff + classify ----
__global__ __launch_bounds__(256) void topk_sel_kernel(
    const unsigned short* __restrict__ p16,
    int* __restrict__ topk_idx, float* __restrict__ topk_val,
    int* __restrict__ sure_cnt, int* __restrict__ tie_cnt, int* __restrict__ cand_col)
{
    const int row = blockIdx.x;
    const int tid = threadIdx.x;
    const int lane = tid & 63, wid = tid >> 6;
    const unsigned short* pr = p16 + (size_t)row * D_HIDDEN;

    __shared__ int red[4];
    __shared__ int sh_sel, sh_tie;

    uint4 kr[16];
#pragma unroll
    for (int i = 0; i < 16; ++i) {
        uint4 w = *(const uint4*)(pr + (i * 256 + tid) * 8);
        w.x = key16x2(w.x); w.y = key16x2(w.y); w.z = key16x2(w.z); w.w = key16x2(w.w);
        kr[i] = w;
    }
    if (tid == 0) { sh_sel = 0; sh_tie = 0; }

    unsigned int lo = 0, hi = 65535;
    while (lo < hi) {
        const unsigned int mid = (lo + hi) >> 1;
        int c = 0;
#pragma unroll
        for (int i = 0; i < 16; ++i) {
            const unsigned int u[4] = {kr[i].x, kr[i].y, kr[i].z, kr[i].w};
#pragma unroll
            for (int e = 0; e < 4; ++e) {
                c += (int)((u[e] & 0xFFFFu) > mid);
                c += (int)((u[e] >> 16) > mid);
            }
        }
#pragma unroll
        for (int off = 32; off > 0; off >>= 1) c += __shfl_down(c, off, 64);
        if (lane == 0) red[wid] = c;
        __syncthreads();
        const int total = red[0] + red[1] + red[2] + red[3];
        if (total < KSEL) hi = mid; else lo = mid + 1;
        __syncthreads();
    }
    const unsigned int K16 = lo;

    const float vc = unkey16(K16);
    const float DLT = 1.3e-2f;
    const float sureT = vc + 2.f * DLT;
    const float candT = vc - 2.f * DLT;
    const unsigned int sK = fkey(sureT) >> 16;
    const unsigned int cK = fkey(candT) >> 16;

    int* oidx = topk_idx + row * KSEL;
    float* oval = topk_val + row * KSEL;
    int* cc = cand_col + row * TIECAP;
#pragma unroll
    for (int i = 0; i < 16; ++i) {
        const int j0 = (i * 256 + tid) * 8;
        const unsigned int u[4] = {kr[i].x, kr[i].y, kr[i].z, kr[i].w};
#pragma unroll
        for (int e = 0; e < 8; ++e) {
            const unsigned int k = (e & 1) ? (u[e >> 1] >> 16) : (u[e >> 1] & 0xFFFFu);
            if (k < cK) continue;
            const float v = unkey16(k);
            if (k > sK && v > sureT) {
                const int pos = atomicAdd(&sh_sel, 1);
                oidx[pos] = j0 + e;
                oval[pos] = v > 0.f ? v : 0.f;
            } else if (v >= candT) {
                const int t = atomicAdd(&sh_tie, 1);
                if (t < TIECAP) cc[t] = j0 + e;
            }
        }
    }
    __syncthreads();
    if (tid == 0) {
        sure_cnt[row] = sh_sel;
        tie_cnt[row] = sh_tie > TIECAP ? TIECAP : sh_tie;
    }
}

// ---------- topk phase 2: exact fp64 refinement, one wave per candidate ----
__global__ __launch_bounds__(256) void topk_refine_kernel(
    const int* __restrict__ tie_cnt, const int* __restrict__ cand_col,
    double* __restrict__ cand_val,
    const float* __restrict__ x, const double* __restrict__ mu, const double* __restrict__ sinv,
    const float* __restrict__ b_pre, const float* __restrict__ wT, const float* __restrict__ b_enc)
{
    const int row = blockIdx.x;
    const int tid = threadIdx.x;
    const int lane = tid & 63, wid = tid >> 6;
    const int T = tie_cnt[row];
    const int base = (int)blockIdx.y * 4 + wid;   // gridDim.y = 16 -> base in [0,64)
    if (base >= T) return;
    const double m_ = mu[row], si = sinv[row];
    const float* xr = x + (size_t)row * D_MODEL;
    for (int slot = base; slot < T; slot += 64) {
        const int col = cand_col[row * TIECAP + slot];
        const float* wr = wT + (size_t)col * D_MODEL;
        double s0 = 0.0, s1 = 0.0;
        for (int k = lane * 4; k < D_MODEL; k += 512) {
            {
                const float4 xv = *(const float4*)(xr + k);
                const float4 bp = *(const float4*)(b_pre + k);
                const float4 wv4 = *(const float4*)(wr + k);
                s0 += (((double)xv.x - m_) * si - (double)bp.x) * (double)wv4.x;
                s0 += (((double)xv.y - m_) * si - (double)bp.y) * (double)wv4.y;
                s0 += (((double)xv.z - m_) * si - (double)bp.z) * (double)wv4.z;
                s0 += (((double)xv.w - m_) * si - (double)bp.w) * (double)wv4.w;
            }
            {
                const int k2 = k + 256;
                const float4 xv = *(const float4*)(xr + k2);
                const float4 bp = *(const float4*)(b_pre + k2);
                const float4 wv4 = *(const float4*)(wr + k2);
                s1 += (((double)xv.x - m_) * si - (double)bp.x) * (double)wv4.x;
                s1 += (((double)xv.y - m_) * si - (double)bp.y) * (double)wv4.y;
                s1 += (((double)xv.z - m_) * si - (double)bp.z) * (double)wv4.z;
                s1 += (((double)xv.w - m_) * si - (double)bp.w) * (double)wv4.w;
            }
        }
        double s = s0 + s1;
#pragma unroll
        for (int off = 32; off > 0; off >>= 1) s += __shfl_down(s, off, 64);
        if (lane == 0) cand_val[row * TIECAP + slot] = s + (double)b_enc[col];
    }
}

// ---------- topk phase 3: parallel rank among candidates, scatter outputs ----
__global__ __launch_bounds__(256) void topk_fin_kernel(
    const int* __restrict__ sure_cnt, const int* __restrict__ tie_cnt,
    const int* __restrict__ cand_col, const double* __restrict__ cand_val,
    int* __restrict__ topk_idx, float* __restrict__ topk_val)
{
    const int row = blockIdx.x;
    const int tid = threadIdx.x;
    __shared__ double vals[TIECAP];
    __shared__ int cols[TIECAP];
    const int G = sure_cnt[row];
    const int T = tie_cnt[row];
    const int R = KSEL - G;
    if (tid < T) {
        vals[tid] = cand_val[row * TIECAP + tid];
        cols[tid] = cand_col[row * TIECAP + tid];
    }
    __syncthreads();
    int* oidx = topk_idx + row * KSEL;
    float* oval = topk_val + row * KSEL;
    if (tid < T) {
        const double v = vals[tid];
        const int c = cols[tid];
        int rank = 0;
        for (int u = 0; u < T; ++u) {
            const double vu = vals[u];
            rank += (int)((vu > v) || (vu == v && cols[u] < c));
        }
        if (rank < R) {
            oidx[G + rank] = c;
            oval[G + rank] = v > 0.0 ? (float)v : 0.f;
        }
    }
    const int take = R < T ? R : T;
    if (tid >= take && tid < R) {
        oidx[G + tid] = (T > 0) ? cols[0] : 0;
        oval[G + tid] = 0.f;
    }
}

// -------------------- w_dec -> bf16 row-major copy --------------------
__global__ __launch_bounds__(256) void wdec2bf_kernel(
    const float* __restrict__ w_dec, unsigned short* __restrict__ wd16)
{
    const size_t gid = (size_t)blockIdx.x * 256 + threadIdx.x;
    const size_t base = gid * 8;
    const float4 a = *(const float4*)(w_dec + base);
    const float4 b = *(const float4*)(w_dec + base + 4);
    uint4 o;
    o.x = (unsigned)f2bf(a.x) | ((unsigned)f2bf(a.y) << 16);
    o.y = (unsigned)f2bf(a.z) | ((unsigned)f2bf(a.w) << 16);
    o.z = (unsigned)f2bf(b.x) | ((unsigned)f2bf(b.y) << 16);
    o.w = (unsigned)f2bf(b.z) | ((unsigned)f2bf(b.w) << 16);
    *(uint4*)(wd16 + base) = o;
}

// -------------------- sparse decode: recons (bf16 w_dec) --------------------
__global__ __launch_bounds__(256) void decode_kernel(
    const int* __restrict__ topk_idx, const float* __restrict__ topk_val,
    const unsigned short* __restrict__ wd16, const float* __restrict__ b_pre,
    const double* __restrict__ mu, const double* __restrict__ stdv,
    float* __restrict__ out0)
{
    const int row = blockIdx.x;
    const int tid = threadIdx.x;
    __shared__ int sidx[KSEL];
    __shared__ float sval[KSEL];
    if (tid < KSEL) {
        sidx[tid] = topk_idx[row * KSEL + tid];
        sval[tid] = topk_val[row * KSEL + tid];
    }
    __syncthreads();
    float acc[16];
#pragma unroll
    for (int i = 0; i < 16; ++i) acc[i] = 0.f;
    const int dbase = tid * 16;
    for (int k = 0; k < KSEL; ++k) {
        const float v = sval[k];
        if (v == 0.f) continue;
        const uint4* wr = (const uint4*)(wd16 + (size_t)sidx[k] * D_MODEL + dbase);
        const uint4 w0 = wr[0], w1 = wr[1];
        const unsigned int u[8] = {w0.x, w0.y, w0.z, w0.w, w1.x, w1.y, w1.z, w1.w};
#pragma unroll
        for (int i = 0; i < 8; ++i) {
            acc[2 * i]     += v * __uint_as_float(u[i] << 16);
            acc[2 * i + 1] += v * __uint_as_float(u[i] & 0xFFFF0000u);
        }
    }
    const float st = (float)stdv[row];
    const float mm = (float)mu[row];
    float* o = out0 + (size_t)row * D_MODEL + dbase;
#pragma unroll
    for (int i = 0; i < 16; ++i) {
        o[i] = (acc[i] + b_pre[dbase + i]) * st + mm;
    }
}

// -------------------- aux A gather+relu (bf16 passthrough) --------------------
__global__ __launch_bounds__(256) void auxg_kernel(
    const unsigned short* __restrict__ p16, const int* __restrict__ dead_idx,
    const int* __restrict__ dead_cnt, unsigned short* __restrict__ Ahd)
{
    const int r = blockIdx.x;
    const int tid = threadIdx.x;
    const int dc = *dead_cnt;
#pragma unroll
    for (int i = 0; i < 8; ++i) {
        const int c = i * 256 + tid;
        unsigned short v = 0;
        if (c < dc) {
            const unsigned short u = p16[(size_t)r * D_HIDDEN + dead_idx[c]];
            v = (u & 0x8000u) ? (unsigned short)0 : u;   // relu on bf16 bits
        }
        Ahd[(size_t)r * NDEAD + c] = v;
    }
}

// -------------------- aux B gather+transpose (bf16) --------------------
__global__ __launch_bounds__(256) void auxb_kernel(
    const float* __restrict__ w_dec, const int* __restrict__ dead_idx,
    unsigned short* __restrict__ Bhd)
{
    __shared__ float t[32][33];
    const int k0 = blockIdx.x * 32;
    const int n0 = blockIdx.y * 32;
    const int tid = threadIdx.x;
    const int i = tid >> 3, j4 = (tid & 7) * 4;
    const int srow = dead_idx[k0 + i];
    const float4 v = *(const float4*)(w_dec + (size_t)srow * D_MODEL + n0 + j4);
    t[i][j4 + 0] = v.x; t[i][j4 + 1] = v.y; t[i][j4 + 2] = v.z; t[i][j4 + 3] = v.w;
    __syncthreads();
    const int j = tid >> 3, i4 = (tid & 7) * 4;
    uint2 hw;
    hw.x = (unsigned)f2bf(t[i4 + 0][j]) | ((unsigned)f2bf(t[i4 + 1][j]) << 16);
    hw.y = (unsigned)f2bf(t[i4 + 2][j]) | ((unsigned)f2bf(t[i4 + 3][j]) << 16);
    *(uint2*)(Bhd + (size_t)(n0 + j) * NDEAD + k0 + i4) = hw;
}

// -------------------- launch --------------------
extern "C" void kernel_launch(void* const* d_in, const int* in_sizes, int n_in,
                              void* d_out, int out_size, void* d_ws, size_t ws_size,
                              hipStream_t stream)
{
    (void)in_sizes; (void)n_in; (void)out_size; (void)ws_size;
    const float* x      = (const float*)d_in[0];
    const float* w_enc  = (const float*)d_in[1];
    const float* w_dec  = (const float*)d_in[2];
    const float* b_enc  = (const float*)d_in[3];
    const float* b_pre  = (const float*)d_in[4];
    const unsigned char* dead_mask = (const unsigned char*)d_in[5];
    const int* num_dead = (const int*)d_in[6];
    float* out = (float*)d_out;

    char* base = (char*)d_ws;
    char* w = base;
    auto alloc = [&](size_t bytes) -> char* {
        char* p = w;
        w += (bytes + 255) & ~(size_t)255;
        return p;
    };
    unsigned short* p16 = (unsigned short*)alloc((size_t)BATCH * D_HIDDEN * 2); // 128 MB
    double* mu       = (double*)alloc((size_t)BATCH * 8);
    double* stdv     = (double*)alloc((size_t)BATCH * 8);
    double* sinv     = (double*)alloc((size_t)BATCH * 8);
    int* topk_idx    = (int*)alloc((size_t)BATCH * KSEL * 4);
    float* topk_val  = (float*)alloc((size_t)BATCH * KSEL * 4);
    int* dead_idx    = (int*)alloc((size_t)NDEAD * 4);
    int* dead_cnt    = (int*)alloc(256);
    int* sure_cnt    = (int*)alloc((size_t)BATCH * 4);
    int* tie_cnt     = (int*)alloc((size_t)BATCH * 4);
    int* cand_col    = (int*)alloc((size_t)BATCH * TIECAP * 4);      // 2 MB
    double* cand_val = (double*)alloc((size_t)BATCH * TIECAP * 8);   // 4 MB
    unsigned short* Ahp = (unsigned short*)alloc((size_t)BATCH * D_MODEL * 2);    // 16 MB
    char* region     = alloc((size_t)D_HIDDEN * D_MODEL * 4);                     // 512 MB

    // time-multiplexed region:
    unsigned short* Bhp = (unsigned short*)region;                 // 256 MB, enc phase
    float* wT   = (float*)region;                                  // 512 MB, topk phase
    unsigned short* wd16 = (unsigned short*)region;                // 256 MB, decode phase
    unsigned short* Bhd  = (unsigned short*)(region + (size_t)D_HIDDEN * D_MODEL * 2); // 16 MB
    unsigned short* Ahd  = Ahp;                                    // 8 MB (Ahp dead after enc)

    float* out0 = out;                                   // recons
    float* out1 = out + (size_t)BATCH * D_MODEL;         // auxk
    float* out_last = out + (size_t)2 * BATCH * D_MODEL; // num_dead

    ln_kernel<<<BATCH, 256, 0, stream>>>(x, mu, stdv, sinv);
    dead_scan_kernel<<<1, 64, 0, stream>>>(dead_mask, dead_idx, dead_cnt, num_dead, out_last);
    asplit_kernel<<<BATCH, 256, 0, stream>>>(x, mu, sinv, b_pre, Ahp);
    bsplit_kernel<<<dim3(D_MODEL / 32, D_HIDDEN / 32), 256, 0, stream>>>(w_enc, Bhp);
    mm256_kernel<0><<<(BATCH / 256) * (D_HIDDEN / 256), 512, 0, stream>>>(
        Ahp, Bhp, D_MODEL, BATCH / 256, b_enc, nullptr, nullptr, p16, (long)D_HIDDEN);
    wencT_kernel<<<dim3(D_MODEL / 32, D_HIDDEN / 32), 256, 0, stream>>>(w_enc, wT);
    topk_sel_kernel<<<BATCH, 256, 0, stream>>>(p16, topk_idx, topk_val, sure_cnt, tie_cnt, cand_col);
    topk_refine_kernel<<<dim3(BATCH, 16), 256, 0, stream>>>(
        tie_cnt, cand_col, cand_val, x, mu, sinv, b_pre, wT, b_enc);
    topk_fin_kernel<<<BATCH, 256, 0, stream>>>(
        sure_cnt, tie_cnt, cand_col, cand_val, topk_idx, topk_val);
    auxg_kernel<<<BATCH, 256, 0, stream>>>(p16, dead_idx, dead_cnt, Ahd);
    auxb_kernel<<<dim3(NDEAD / 32, D_MODEL / 32), 256, 0, stream>>>(w_dec, dead_idx, Bhd);
    wdec2bf_kernel<<<(int)(((size_t)D_HIDDEN * D_MODEL) / (256 * 8)), 256, 0, stream>>>(w_dec, wd16);
    decode_kernel<<<BATCH, 256, 0, stream>>>(topk_idx, topk_val, wd16, b_pre, mu, stdv, out0);
    mm_kernel<1><<<(BATCH / 128) * (D_MODEL / 128), 256, 0, stream>>>(
        Ahd, Bhd, NDEAD, BATCH / 128, b_pre, mu, stdv, out1, (long)D_MODEL);
}

// Round 12
// 2123.269 us; speedup vs baseline: 1.7738x; 1.0558x over previous
//
#include <hip/hip_runtime.h>
#include <math.h>

#define D_MODEL  4096
#define D_HIDDEN 32768
#define BATCH    2048
#define KSEL     128
#define NDEAD    2048
#define TIECAP   256

typedef short s16x8 __attribute__((ext_vector_type(8)));
typedef float f32x4 __attribute__((ext_vector_type(4)));

// -------------------- helpers --------------------
__device__ __forceinline__ unsigned int fkey(float f) {
    unsigned int u = __float_as_uint(f);
    return (u & 0x80000000u) ? ~u : (u | 0x80000000u);
}
__device__ __forceinline__ unsigned short f2bf(float f) {  // RTNE
    unsigned int u = __float_as_uint(f);
    u += 0x7FFFu + ((u >> 16) & 1u);
    return (unsigned short)(u >> 16);
}
__device__ __forceinline__ float bf2f(unsigned short h) {
    return __uint_as_float(((unsigned int)h) << 16);
}
// per-16-bit-lane order-preserving key transform (packed pair)
__device__ __forceinline__ unsigned int key16x2(unsigned int u) {
    const unsigned int s = (u >> 15) & 0x10001u;
    const unsigned int mask = s * 0xFFFFu;
    return (u ^ mask) | (~mask & 0x80008000u);
}
__device__ __forceinline__ float unkey16(unsigned int k) {  // 16-bit key -> float
    const unsigned int u = (k & 0x8000u) ? (k & 0x7FFFu) : (~k & 0xFFFFu);
    return __uint_as_float(u << 16);
}
__device__ __forceinline__ void async_copy16(void* lds_dst, const void* gsrc) {
    __builtin_amdgcn_global_load_lds(
        (const __attribute__((address_space(1))) unsigned int*)gsrc,
        (__attribute__((address_space(3))) unsigned int*)lds_dst,
        16, 0, 0);
}

// ---- prep: LayerNorm (fp64 stats, identical reduction) + xc->bf16 + Dekker pair ----
__global__ __launch_bounds__(256) void prep_kernel(
    const float* __restrict__ x, const float* __restrict__ b_pre,
    double* __restrict__ mu, double* __restrict__ stdv, double* __restrict__ sinv,
    unsigned short* __restrict__ Ahp, float* __restrict__ xch, float* __restrict__ xcl)
{
    const int row = blockIdx.x;
    const int tid = threadIdx.x;
    const float* xr = x + (size_t)row * D_MODEL;
    float xv[16];
#pragma unroll
    for (int i = 0; i < 16; ++i) xv[i] = xr[tid + 256 * i];
    double s = 0.0;
#pragma unroll
    for (int i = 0; i < 16; ++i) s += (double)xv[i];
    __shared__ double red[4];
    __shared__ double sh_mu, sh_si;
    const int lane = tid & 63, wid = tid >> 6;
#pragma unroll
    for (int off = 32; off > 0; off >>= 1) s += __shfl_down(s, off, 64);
    if (lane == 0) red[wid] = s;
    __syncthreads();
    if (tid == 0) sh_mu = (red[0] + red[1] + red[2] + red[3]) / (double)D_MODEL;
    __syncthreads();
    const double m = sh_mu;
    double s2 = 0.0;
#pragma unroll
    for (int i = 0; i < 16; ++i) { double d = (double)xv[i] - m; s2 += d * d; }
#pragma unroll
    for (int off = 32; off > 0; off >>= 1) s2 += __shfl_down(s2, off, 64);
    __syncthreads();
    if (lane == 0) red[wid] = s2;
    __syncthreads();
    if (tid == 0) {
        double var = (red[0] + red[1] + red[2] + red[3]) / (double)(D_MODEL - 1);
        double sd = sqrt(var);
        mu[row] = m;
        stdv[row] = sd;
        const double si = 1.0 / (sd + 1e-5);
        sinv[row] = si;
        sh_si = si;
    }
    __syncthreads();
    const double si = sh_si;
    // second phase: bf16 plane (bitwise-identical to old asplit) + exact fp32 pair
#pragma unroll
    for (int i = 0; i < 4; ++i) {
        const int j = (i * 256 + tid) * 4;
        const float4 x4 = *(const float4*)(xr + j);
        const float4 bp = *(const float4*)(b_pre + j);
        float vf[4], hi[4], lo[4];
        const float xe[4] = {x4.x, x4.y, x4.z, x4.w};
        const float be[4] = {bp.x, bp.y, bp.z, bp.w};
#pragma unroll
        for (int e = 0; e < 4; ++e) {
            const double t = ((double)xe[e] - m) * si;
            vf[e] = (float)t - be[e];                 // matches old asplit exactly
            const double a = t - (double)be[e];       // matches old refine exactly
            hi[e] = (float)a;
            lo[e] = (float)(a - (double)hi[e]);
        }
        uint2 hw;
        hw.x = (unsigned)f2bf(vf[0]) | ((unsigned)f2bf(vf[1]) << 16);
        hw.y = (unsigned)f2bf(vf[2]) | ((unsigned)f2bf(vf[3]) << 16);
        *(uint2*)(Ahp + (size_t)row * D_MODEL + j) = hw;
        *(float4*)(xch + (size_t)row * D_MODEL + j) = make_float4(hi[0], hi[1], hi[2], hi[3]);
        *(float4*)(xcl + (size_t)row * D_MODEL + j) = make_float4(lo[0], lo[1], lo[2], lo[3]);
    }
}

// -------------------- dead-mask scan --------------------
__global__ void dead_scan_kernel(const unsigned char* __restrict__ mask8,
                                 int* __restrict__ dead_idx, int* __restrict__ dead_cnt,
                                 const int* __restrict__ num_dead_in, float* __restrict__ out_last)
{
    const int lane = threadIdx.x; // 64 threads, one wave
    int c = 0;
    for (int j = lane; j < D_HIDDEN; j += 64) c += (mask8[j] != 0);
#pragma unroll
    for (int off = 32; off > 0; off >>= 1) c += __shfl_down(c, off, 64);
    const int total_u8 = __shfl(c, 0, 64);
    const bool u8mode = (total_u8 == NDEAD);
    const int* mask32 = (const int*)mask8;
    int cnt = 0;
    for (int base = 0; base < D_HIDDEN; base += 64) {
        const int j = base + lane;
        const bool d = u8mode ? (mask8[j] != 0) : (mask32[j] != 0);
        const unsigned long long b = __ballot(d);
        const int pre = __popcll(b & ((1ull << lane) - 1ull));
        if (d && (cnt + pre) < NDEAD) dead_idx[cnt + pre] = j;
        cnt += __popcll(b);
    }
    const int cc = cnt > NDEAD ? NDEAD : cnt;
    if (lane == 0) {
        *dead_cnt = cc;
        *out_last = (float)(*num_dead_in);
    }
    for (int t = cc + lane; t < NDEAD; t += 64) dead_idx[t] = 0;
}

// -------------------- B: w_enc[k][n] -> Bh[n][k] bf16 (fallback path) ---------
__global__ __launch_bounds__(256) void bsplit_kernel(
    const float* __restrict__ w_enc, unsigned short* __restrict__ Bhp)
{
    __shared__ float t[32][33];
    const int bk = blockIdx.x * 32;
    const int bn = blockIdx.y * 32;
    const int tid = threadIdx.x;
    const int lr = tid >> 3, lc4 = (tid & 7) * 4;
    const float4 v = *(const float4*)(w_enc + (size_t)(bk + lr) * D_HIDDEN + bn + lc4);
    t[lr][lc4 + 0] = v.x; t[lr][lc4 + 1] = v.y; t[lr][lc4 + 2] = v.z; t[lr][lc4 + 3] = v.w;
    __syncthreads();
    float o[4];
#pragma unroll
    for (int j = 0; j < 4; ++j) o[j] = t[lc4 + j][lr];
    uint2 hw;
    hw.x = (unsigned)f2bf(o[0]) | ((unsigned)f2bf(o[1]) << 16);
    hw.y = (unsigned)f2bf(o[2]) | ((unsigned)f2bf(o[3]) << 16);
    *(uint2*)(Bhp + (size_t)(bn + lr) * D_MODEL + bk + lc4) = hw;
}

// -------------------- w_enc transpose to fp32 [n][k] (fallback path) ----------
__global__ __launch_bounds__(256) void wencT_kernel(
    const float* __restrict__ w_enc, float* __restrict__ wT)
{
    __shared__ float t[32][33];
    const int bk = blockIdx.x * 32;
    const int bn = blockIdx.y * 32;
    const int tid = threadIdx.x;
    const int lr = tid >> 3, lc4 = (tid & 7) * 4;
    const float4 v = *(const float4*)(w_enc + (size_t)(bk + lr) * D_HIDDEN + bn + lc4);
    t[lr][lc4 + 0] = v.x; t[lr][lc4 + 1] = v.y; t[lr][lc4 + 2] = v.z; t[lr][lc4 + 3] = v.w;
    __syncthreads();
    const int j = tid >> 3, i4 = (tid & 7) * 4;
    float4 o;
    o.x = t[i4 + 0][j]; o.y = t[i4 + 1][j]; o.z = t[i4 + 2][j]; o.w = t[i4 + 3][j];
    *(float4*)(wT + (size_t)(bn + j) * D_MODEL + bk + i4) = o;
}

// ------- fused: one w_enc pass -> Bhp (bf16 T) + wT (fp32 T)  (bigws path) -----
__global__ __launch_bounds__(256) void wprep_kernel(
    const float* __restrict__ w_enc, unsigned short* __restrict__ Bhp,
    float* __restrict__ wT)
{
    __shared__ float t[32][33];
    const int bk = blockIdx.x * 32;
    const int bn = blockIdx.y * 32;
    const int tid = threadIdx.x;
    const int lr = tid >> 3, lc4 = (tid & 7) * 4;
    const float4 v = *(const float4*)(w_enc + (size_t)(bk + lr) * D_HIDDEN + bn + lc4);
    t[lr][lc4 + 0] = v.x; t[lr][lc4 + 1] = v.y; t[lr][lc4 + 2] = v.z; t[lr][lc4 + 3] = v.w;
    __syncthreads();
    float o[4];
#pragma unroll
    for (int j = 0; j < 4; ++j) o[j] = t[lc4 + j][lr];
    uint2 hw;
    hw.x = (unsigned)f2bf(o[0]) | ((unsigned)f2bf(o[1]) << 16);
    hw.y = (unsigned)f2bf(o[2]) | ((unsigned)f2bf(o[3]) << 16);
    *(uint2*)(Bhp + (size_t)(bn + lr) * D_MODEL + bk + lc4) = hw;
    *(float4*)(wT + (size_t)(bn + lr) * D_MODEL + bk + lc4) = make_float4(o[0], o[1], o[2], o[3]);
}

// ======== 256x256 bf16 MFMA GEMM, BK=64, 8 waves, 4-phase/K-tile, half-tile pipe ====
template<int EPI>
__global__ __launch_bounds__(512) void mm256_kernel(
    const unsigned short* __restrict__ A, const unsigned short* __restrict__ B,
    const int kdim, const int ntiles_x,
    const float* __restrict__ bias_n,
    const double* __restrict__ muv, const double* __restrict__ stdvv,
    void* __restrict__ outp, const long ostride)
{
    __shared__ unsigned short lds[2 * 4 * 8192];   // 128 KB: 2 bufs x 4 subplanes
    const int tid = threadIdx.x;
    const int lane = tid & 63, wid = tid >> 6;     // 8 waves
    const int cpx = gridDim.x >> 3;                // XCD swizzle (grid % 8 == 0)
    const int orig = blockIdx.x;
    const int wg = (orig & 7) * cpx + (orig >> 3);
    const int m0 = (wg % ntiles_x) * 256;
    const int n0 = (wg / ntiles_x) * 256;
    const int wm = (wid >> 2) * 128;               // 2 M-halves
    const int wn = (wid & 3) * 64;                 // 4 N-quarters
    const int fr = lane & 15, kq = lane >> 4;
    const int swr = (fr >> 1) & 3;                 // read-side quad XOR
    const int qg = (lane & 3) ^ ((lane >> 3) & 3); // write-side source quad
    const int qo = (kq ^ swr) * 8;

    f32x4 acc[8][4];
#pragma unroll
    for (int i = 0; i < 8; ++i)
#pragma unroll
        for (int j = 0; j < 4; ++j) acc[i][j] = (f32x4){0.f, 0.f, 0.f, 0.f};

    const unsigned short* sH0[4];
    int dH0[4];
#pragma unroll
    for (int j = 0; j < 4; ++j) {
        const int g = wid * 4 + j;
        const int is_b = g >> 4;
        const int sr = g & 15;
        const unsigned short* gp = is_b ? B : A;
        const int t0 = is_b ? n0 : m0;
        sH0[j] = gp + (size_t)(t0 + sr * 16 + (lane >> 2)) * kdim + qg * 8;
        dH0[j] = (is_b ? 2 : 0) * 8192 + sr * 512;
    }

    const int NT = kdim >> 6;
#pragma unroll
    for (int j = 0; j < 4; ++j) async_copy16(lds + dH0[j], sH0[j]);
#pragma unroll
    for (int j = 0; j < 4; ++j) async_copy16(lds + 8192 + dH0[j], sH0[j] + 32);
    if (NT > 1) {
#pragma unroll
        for (int j = 0; j < 4; ++j) async_copy16(lds + 32768 + dH0[j], sH0[j] + 64);
    }

    for (int t = 0; t < NT; ++t) {
        const int cur = t & 1;
        unsigned short* bb = (unsigned short*)lds + cur * 32768;
        unsigned short* nb = (unsigned short*)lds + (cur ^ 1) * 32768;
        const int k1 = (t + 1) << 6;
        const int k2 = (t + 2) << 6;

        // ======== kk0 half: wait H0(t) ========
        if (t < NT - 1) { asm volatile("s_waitcnt vmcnt(8)" ::: "memory"); }
        else            { asm volatile("s_waitcnt vmcnt(4)" ::: "memory"); }
        asm volatile("s_barrier" ::: "memory");
        __builtin_amdgcn_sched_barrier(0);
        {
            if (t + 1 < NT) {
                async_copy16(nb + 8192 + dH0[0], sH0[0] + k1 + 32);
                async_copy16(nb + 8192 + dH0[1], sH0[1] + k1 + 32);
            }
            s16x8 a[4], b[4];
#pragma unroll
            for (int mi = 0; mi < 4; ++mi)
                a[mi] = *(const s16x8*)(bb + (wm + mi * 16 + fr) * 32 + qo);
#pragma unroll
            for (int ni = 0; ni < 4; ++ni)
                b[ni] = *(const s16x8*)(bb + 2 * 8192 + (wn + ni * 16 + fr) * 32 + qo);
            __builtin_amdgcn_s_setprio(1);
#pragma unroll
            for (int mi = 0; mi < 4; ++mi)
#pragma unroll
                for (int ni = 0; ni < 4; ++ni)
                    acc[mi][ni] = __builtin_amdgcn_mfma_f32_16x16x32_bf16(a[mi], b[ni], acc[mi][ni], 0, 0, 0);
            __builtin_amdgcn_s_setprio(0);
            asm volatile("s_barrier" ::: "memory");
            __builtin_amdgcn_sched_barrier(0);
            if (t + 1 < NT) {
                async_copy16(nb + 8192 + dH0[2], sH0[2] + k1 + 32);
                async_copy16(nb + 8192 + dH0[3], sH0[3] + k1 + 32);
            }
            s16x8 a2[4];
#pragma unroll
            for (int mi = 0; mi < 4; ++mi)
                a2[mi] = *(const s16x8*)(bb + (wm + (mi + 4) * 16 + fr) * 32 + qo);
            __builtin_amdgcn_s_setprio(1);
#pragma unroll
            for (int mi = 0; mi < 4; ++mi)
#pragma unroll
                for (int ni = 0; ni < 4; ++ni)
                    acc[mi + 4][ni] = __builtin_amdgcn_mfma_f32_16x16x32_bf16(a2[mi], b[ni], acc[mi + 4][ni], 0, 0, 0);
            __builtin_amdgcn_s_setprio(0);
        }
        // ======== kk1 half: wait H1(t) ========
        if (t < NT - 1) { asm volatile("s_waitcnt vmcnt(8)" ::: "memory"); }
        else            { asm volatile("s_waitcnt vmcnt(0)" ::: "memory"); }
        asm volatile("s_barrier" ::: "memory");
        __builtin_amdgcn_sched_barrier(0);
        {
            if (t + 2 < NT) {
                async_copy16(bb + dH0[0], sH0[0] + k2);
                async_copy16(bb + dH0[1], sH0[1] + k2);
            }
            s16x8 a[4], b[4];
#pragma unroll
            for (int mi = 0; mi < 4; ++mi)
                a[mi] = *(const s16x8*)(bb + 8192 + (wm + mi * 16 + fr) * 32 + qo);
#pragma unroll
            for (int ni = 0; ni < 4; ++ni)
                b[ni] = *(const s16x8*)(bb + 3 * 8192 + (wn + ni * 16 + fr) * 32 + qo);
            __builtin_amdgcn_s_setprio(1);
#pragma unroll
            for (int mi = 0; mi < 4; ++mi)
#pragma unroll
                for (int ni = 0; ni < 4; ++ni)
                    acc[mi][ni] = __builtin_amdgcn_mfma_f32_16x16x32_bf16(a[mi], b[ni], acc[mi][ni], 0, 0, 0);
            __builtin_amdgcn_s_setprio(0);
            asm volatile("s_barrier" ::: "memory");
            __builtin_amdgcn_sched_barrier(0);
            if (t + 2 < NT) {
                async_copy16(bb + dH0[2], sH0[2] + k2);
                async_copy16(bb + dH0[3], sH0[3] + k2);
            }
            s16x8 a2[4];
#pragma unroll
            for (int mi = 0; mi < 4; ++mi)
                a2[mi] = *(const s16x8*)(bb + 8192 + (wm + (mi + 4) * 16 + fr) * 32 + qo);
            __builtin_amdgcn_s_setprio(1);
#pragma unroll
            for (int mi = 0; mi < 4; ++mi)
#pragma unroll
                for (int ni = 0; ni < 4; ++ni)
                    acc[mi + 4][ni] = __builtin_amdgcn_mfma_f32_16x16x32_bf16(a2[mi], b[ni], acc[mi + 4][ni], 0, 0, 0);
            __builtin_amdgcn_s_setprio(0);
        }
    }

#pragma unroll
    for (int ni = 0; ni < 4; ++ni) {
        const int col = n0 + wn + ni * 16 + fr;
        const float be = bias_n[col];
#pragma unroll
        for (int mi = 0; mi < 8; ++mi) {
            const int rb = m0 + wm + mi * 16 + kq * 4;
            if (EPI == 0) {
                unsigned short* O = (unsigned short*)outp;
#pragma unroll
                for (int r = 0; r < 4; ++r)
                    O[(size_t)(rb + r) * ostride + col] = f2bf(acc[mi][ni][r] + be);
            } else {
                float* O = (float*)outp;
#pragma unroll
                for (int r = 0; r < 4; ++r) {
                    const int m = rb + r;
                    O[(size_t)m * ostride + col] =
                        (acc[mi][ni][r] + be) * (float)stdvv[m] + (float)muv[m];
                }
            }
        }
    }
}

// -------- 128x128 bf16 MFMA GEMM (3-buffer ring) — used for the small aux GEMM ----
template<int EPI>
__global__ __launch_bounds__(256) void mm_kernel(
    const unsigned short* __restrict__ A, const unsigned short* __restrict__ B,
    const int kdim, const int ntiles_x,
    const float* __restrict__ bias_n,
    const double* __restrict__ muv, const double* __restrict__ stdvv,
    void* __restrict__ outp, const long ostride)
{
    __shared__ unsigned short lds[3 * 2 * 128 * 32];  // 3 ring bufs x (A 8KB + B 8KB)
    const int tid = threadIdx.x;
    const int lane = tid & 63, wid = tid >> 6;
    const int cpx = gridDim.x >> 3;
    const int orig = blockIdx.x;
    const int wg = (orig & 7) * cpx + (orig >> 3);
    const int m0 = (wg % ntiles_x) * 128;
    const int n0 = (wg / ntiles_x) * 128;
    const int wm = (wid >> 1) * 64, wn = (wid & 1) * 64;
    const int fr = lane & 15, kq = lane >> 4;
    const int swr = (fr >> 1) & 3;
    const int qg = (lane & 3) ^ ((lane >> 3) & 3);
    const int qo = (kq ^ swr) * 8;

    f32x4 acc[4][4];
#pragma unroll
    for (int i = 0; i < 4; ++i)
#pragma unroll
        for (int j = 0; j < 4; ++j) acc[i][j] = (f32x4){0.f, 0.f, 0.f, 0.f};

    const unsigned short* srcs[4];
    int d0[4];
#pragma unroll
    for (int j = 0; j < 4; ++j) {
        const int s = wid * 4 + j;
        const int pl = s >> 3, sr = s & 7;
        const int r = sr * 16 + (lane >> 2);
        srcs[j] = (pl ? B : A) + (size_t)((pl ? n0 : m0) + r) * kdim + qg * 8;
        d0[j] = pl * 4096 + sr * 512;
    }

    const int NT = kdim >> 5;
#pragma unroll
    for (int j = 0; j < 4; ++j) async_copy16(lds + 0 * 8192 + d0[j], srcs[j]);
#pragma unroll
    for (int j = 0; j < 4; ++j) async_copy16(lds + 1 * 8192 + d0[j], srcs[j] + 32);

    int cur = 0, nxt = 2;
    for (int t = 0; t < NT; ++t) {
        if (t < NT - 1) {
            asm volatile("s_waitcnt vmcnt(4)" ::: "memory");
        } else {
            asm volatile("s_waitcnt vmcnt(0)" ::: "memory");
        }
        __builtin_amdgcn_s_barrier();
        __builtin_amdgcn_sched_barrier(0);

        if (t + 2 < NT) {
            const int k2 = (t + 2) << 5;
#pragma unroll
            for (int j = 0; j < 4; ++j) async_copy16(lds + nxt * 8192 + d0[j], srcs[j] + k2);
        }

        const unsigned short* la = lds + cur * 8192;
        const unsigned short* lb = la + 4096;
        s16x8 a[4], b[4];
#pragma unroll
        for (int i = 0; i < 4; ++i) {
            a[i] = *(const s16x8*)(la + (wm + i * 16 + fr) * 32 + qo);
            b[i] = *(const s16x8*)(lb + (wn + i * 16 + fr) * 32 + qo);
        }
#pragma unroll
        for (int mi = 0; mi < 4; ++mi)
#pragma unroll
            for (int ni = 0; ni < 4; ++ni)
                acc[mi][ni] = __builtin_amdgcn_mfma_f32_16x16x32_bf16(a[mi], b[ni], acc[mi][ni], 0, 0, 0);

        cur = cur == 2 ? 0 : cur + 1;
        nxt = nxt == 2 ? 0 : nxt + 1;
    }

#pragma unroll
    for (int ni = 0; ni < 4; ++ni) {
        const int col = n0 + wn + ni * 16 + fr;
        const float be = bias_n[col];
#pragma unroll
        for (int mi = 0; mi < 4; ++mi) {
            const int rb = m0 + wm + mi * 16 + kq * 4;
            if (EPI == 0) {
                unsigned short* O = (unsigned short*)outp;
#pragma unroll
                for (int r = 0; r < 4; ++r)
                    O[(size_t)(rb + r) * ostride + col] = f2bf(acc[mi][ni][r] + be);
            } else {
                float* O = (float*)outp;
#pragma unroll
                for (int r = 0; r < 4; ++r) {
                    const int m = rb + r;
                    O[(size_t)m * ostride + col] =
                        (acc[mi][ni][r] + be) * (float)stdvv[m] + (float)muv[m];
                }
            }
        }
    }
}

// ---------- topk phase 1: register keys + binary-search cutoff + classify ----
__global__ __launch_bounds__(256) void topk_sel_kernel(
    const unsigned short* __restrict__ p16,
    int* __restrict__ topk_idx, float* __restrict__ topk_val,
    int* __restrict__ sure_cnt, int* __restrict__ tie_cnt, int* __restrict__ cand_col)
{
    const int row = blockIdx.x;
    const int tid = threadIdx.x;
    const int lane = tid & 63, wid = tid >> 6;
    const unsigned short* pr = p16 + (size_t)row * D_HIDDEN;

    __shared__ int red[4];
    __shared__ int sh_sel, sh_tie;

    uint4 kr[16];
#pragma unroll
    for (int i = 0; i < 16; ++i) {
        uint4 w = *(const uint4*)(pr + (i * 256 + tid) * 8);
        w.x = key16x2(w.x); w.y = key16x2(w.y); w.z = key16x2(w.z); w.w = key16x2(w.w);
        kr[i] = w;
    }
    if (tid == 0) { sh_sel = 0; sh_tie = 0; }

    unsigned int lo = 0, hi = 65535;
    while (lo < hi) {
        const unsigned int mid = (lo + hi) >> 1;
        int c = 0;
#pragma unroll
        for (int i = 0; i < 16; ++i) {
            const unsigned int u[4] = {kr[i].x, kr[i].y, kr[i].z, kr[i].w};
#pragma unroll
            for (int e = 0; e < 4; ++e) {
                c += (int)((u[e] & 0xFFFFu) > mid);
                c += (int)((u[e] >> 16) > mid);
            }
        }
#pragma unroll
        for (int off = 32; off > 0; off >>= 1) c += __shfl_down(c, off, 64);
        if (lane == 0) red[wid] = c;
        __syncthreads();
        const int total = red[0] + red[1] + red[2] + red[3];
        if (total < KSEL) hi = mid; else lo = mid + 1;
        __syncthreads();
    }
    const unsigned int K16 = lo;

    const float vc = unkey16(K16);
    const float DLT = 1.3e-2f;
    const float sureT = vc + 2.f * DLT;
    const float candT = vc - 2.f * DLT;
    const unsigned int sK = fkey(sureT) >> 16;
    const unsigned int cK = fkey(candT) >> 16;

    int* oidx = topk_idx + row * KSEL;
    float* oval = topk_val + row * KSEL;
    int* cc = cand_col + row * TIECAP;
#pragma unroll
    for (int i = 0; i < 16; ++i) {
        const int j0 = (i * 256 + tid) * 8;
        const unsigned int u[4] = {kr[i].x, kr[i].y, kr[i].z, kr[i].w};
#pragma unroll
        for (int e = 0; e < 8; ++e) {
            const unsigned int k = (e & 1) ? (u[e >> 1] >> 16) : (u[e >> 1] & 0xFFFFu);
            if (k < cK) continue;
            const float v = unkey16(k);
            if (k > sK && v > sureT) {
                const int pos = atomicAdd(&sh_sel, 1);
                oidx[pos] = j0 + e;
                oval[pos] = v > 0.f ? v : 0.f;
            } else if (v >= candT) {
                const int t = atomicAdd(&sh_tie, 1);
                if (t < TIECAP) cc[t] = j0 + e;
            }
        }
    }
    __syncthreads();
    if (tid == 0) {
        sure_cnt[row] = sh_sel;
        tie_cnt[row] = sh_tie > TIECAP ? TIECAP : sh_tie;
    }
}

// ---------- topk phase 2: exact fp64 refinement via Dekker xc pair ----------
__global__ __launch_bounds__(256) void topk_refine_kernel(
    const int* __restrict__ tie_cnt, const int* __restrict__ cand_col,
    double* __restrict__ cand_val,
    const float* __restrict__ xch, const float* __restrict__ xcl,
    const float* __restrict__ wT, const float* __restrict__ b_enc)
{
    const int row = blockIdx.x;
    const int tid = threadIdx.x;
    const int lane = tid & 63, wid = tid >> 6;
    const int T = tie_cnt[row];
    const int base = (int)blockIdx.y * 4 + wid;   // gridDim.y = 16 -> base in [0,64)
    if (base >= T) return;
    const float* hr = xch + (size_t)row * D_MODEL;
    const float* lr2 = xcl + (size_t)row * D_MODEL;
    for (int slot = base; slot < T; slot += 64) {
        const int col = cand_col[row * TIECAP + slot];
        const float* wr = wT + (size_t)col * D_MODEL;
        double s0 = 0.0, s1 = 0.0;
        for (int k = lane * 4; k < D_MODEL; k += 512) {
            {
                const float4 h = *(const float4*)(hr + k);
                const float4 l = *(const float4*)(lr2 + k);
                const float4 w4 = *(const float4*)(wr + k);
                s0 += ((double)h.x + (double)l.x) * (double)w4.x;
                s0 += ((double)h.y + (double)l.y) * (double)w4.y;
                s0 += ((double)h.z + (double)l.z) * (double)w4.z;
                s0 += ((double)h.w + (double)l.w) * (double)w4.w;
            }
            {
                const int k2 = k + 256;
                const float4 h = *(const float4*)(hr + k2);
                const float4 l = *(const float4*)(lr2 + k2);
                const float4 w4 = *(const float4*)(wr + k2);
                s1 += ((double)h.x + (double)l.x) * (double)w4.x;
                s1 += ((double)h.y + (double)l.y) * (double)w4.y;
                s1 += ((double)h.z + (double)l.z) * (double)w4.z;
                s1 += ((double)h.w + (double)l.w) * (double)w4.w;
            }
        }
        double s = s0 + s1;
#pragma unroll
        for (int off = 32; off > 0; off >>= 1) s += __shfl_down(s, off, 64);
        if (lane == 0) cand_val[row * TIECAP + slot] = s + (double)b_enc[col];
    }
}

// ---------- topk phase 3: parallel rank among candidates, scatter outputs ----
__global__ __launch_bounds__(256) void topk_fin_kernel(
    const int* __restrict__ sure_cnt, const int* __restrict__ tie_cnt,
    const int* __restrict__ cand_col, const double* __restrict__ cand_val,
    int* __restrict__ topk_idx, float* __restrict__ topk_val)
{
    const int row = blockIdx.x;
    const int tid = threadIdx.x;
    __shared__ double vals[TIECAP];
    __shared__ int cols[TIECAP];
    const int G = sure_cnt[row];
    const int T = tie_cnt[row];
    const int R = KSEL - G;
    if (tid < T) {
        vals[tid] = cand_val[row * TIECAP + tid];
        cols[tid] = cand_col[row * TIECAP + tid];
    }
    __syncthreads();
    int* oidx = topk_idx + row * KSEL;
    float* oval = topk_val + row * KSEL;
    if (tid < T) {
        const double v = vals[tid];
        const int c = cols[tid];
        int rank = 0;
        for (int u = 0; u < T; ++u) {
            const double vu = vals[u];
            rank += (int)((vu > v) || (vu == v && cols[u] < c));
        }
        if (rank < R) {
            oidx[G + rank] = c;
            oval[G + rank] = v > 0.0 ? (float)v : 0.f;
        }
    }
    const int take = R < T ? R : T;
    if (tid >= take && tid < R) {
        oidx[G + tid] = (T > 0) ? cols[0] : 0;
        oval[G + tid] = 0.f;
    }
}

// -------------------- w_dec -> bf16 row-major copy --------------------
__global__ __launch_bounds__(256) void wdec2bf_kernel(
    const float* __restrict__ w_dec, unsigned short* __restrict__ wd16)
{
    const size_t gid = (size_t)blockIdx.x * 256 + threadIdx.x;
    const size_t base = gid * 8;
    const float4 a = *(const float4*)(w_dec + base);
    const float4 b = *(const float4*)(w_dec + base + 4);
    uint4 o;
    o.x = (unsigned)f2bf(a.x) | ((unsigned)f2bf(a.y) << 16);
    o.y = (unsigned)f2bf(a.z) | ((unsigned)f2bf(a.w) << 16);
    o.z = (unsigned)f2bf(b.x) | ((unsigned)f2bf(b.y) << 16);
    o.w = (unsigned)f2bf(b.z) | ((unsigned)f2bf(b.w) << 16);
    *(uint4*)(wd16 + base) = o;
}

// -------------------- sparse decode: recons (bf16 w_dec) --------------------
__global__ __launch_bounds__(256) void decode_kernel(
    const int* __restrict__ topk_idx, const float* __restrict__ topk_val,
    const unsigned short* __restrict__ wd16, const float* __restrict__ b_pre,
    const double* __restrict__ mu, const double* __restrict__ stdv,
    float* __restrict__ out0)
{
    const int row = blockIdx.x;
    const int tid = threadIdx.x;
    __shared__ int sidx[KSEL];
    __shared__ float sval[KSEL];
    if (tid < KSEL) {
        sidx[tid] = topk_idx[row * KSEL + tid];
        sval[tid] = topk_val[row * KSEL + tid];
    }
    __syncthreads();
    float acc[16];
#pragma unroll
    for (int i = 0; i < 16; ++i) acc[i] = 0.f;
    const int dbase = tid * 16;
    for (int k = 0; k < KSEL; ++k) {
        const float v = sval[k];
        if (v == 0.f) continue;
        const uint4* wr = (const uint4*)(wd16 + (size_t)sidx[k] * D_MODEL + dbase);
        const uint4 w0 = wr[0], w1 = wr[1];
        const unsigned int u[8] = {w0.x, w0.y, w0.z, w0.w, w1.x, w1.y, w1.z, w1.w};
#pragma unroll
        for (int i = 0; i < 8; ++i) {
            acc[2 * i]     += v * __uint_as_float(u[i] << 16);
            acc[2 * i + 1] += v * __uint_as_float(u[i] & 0xFFFF0000u);
        }
    }
    const float st = (float)stdv[row];
    const float mm = (float)mu[row];
    float* o = out0 + (size_t)row * D_MODEL + dbase;
#pragma unroll
    for (int i = 0; i < 16; ++i) {
        o[i] = (acc[i] + b_pre[dbase + i]) * st + mm;
    }
}

// -------------------- aux A gather+relu (bf16 passthrough) --------------------
__global__ __launch_bounds__(256) void auxg_kernel(
    const unsigned short* __restrict__ p16, const int* __restrict__ dead_idx,
    const int* __restrict__ dead_cnt, unsigned short* __restrict__ Ahd)
{
    const int r = blockIdx.x;
    const int tid = threadIdx.x;
    const int dc = *dead_cnt;
#pragma unroll
    for (int i = 0; i < 8; ++i) {
        const int c = i * 256 + tid;
        unsigned short v = 0;
        if (c < dc) {
            const unsigned short u = p16[(size_t)r * D_HIDDEN + dead_idx[c]];
            v = (u & 0x8000u) ? (unsigned short)0 : u;   // relu on bf16 bits
        }
        Ahd[(size_t)r * NDEAD + c] = v;
    }
}

// -------------------- aux B gather+transpose (bf16) --------------------
__global__ __launch_bounds__(256) void auxb_kernel(
    const float* __restrict__ w_dec, const int* __restrict__ dead_idx,
    unsigned short* __restrict__ Bhd)
{
    __shared__ float t[32][33];
    const int k0 = blockIdx.x * 32;
    const int n0 = blockIdx.y * 32;
    const int tid = threadIdx.x;
    const int i = tid >> 3, j4 = (tid & 7) * 4;
    const int srow = dead_idx[k0 + i];
    const float4 v = *(const float4*)(w_dec + (size_t)srow * D_MODEL + n0 + j4);
    t[i][j4 + 0] = v.x; t[i][j4 + 1] = v.y; t[i][j4 + 2] = v.z; t[i][j4 + 3] = v.w;
    __syncthreads();
    const int j = tid >> 3, i4 = (tid & 7) * 4;
    uint2 hw;
    hw.x = (unsigned)f2bf(t[i4 + 0][j]) | ((unsigned)f2bf(t[i4 + 1][j]) << 16);
    hw.y = (unsigned)f2bf(t[i4 + 2][j]) | ((unsigned)f2bf(t[i4 + 3][j]) << 16);
    *(uint2*)(Bhd + (size_t)(n0 + j) * NDEAD + k0 + i4) = hw;
}

// -------------------- launch --------------------
extern "C" void kernel_launch(void* const* d_in, const int* in_sizes, int n_in,
                              void* d_out, int out_size, void* d_ws, size_t ws_size,
                              hipStream_t stream)
{
    (void)in_sizes; (void)n_in; (void)out_size;
    const float* x      = (const float*)d_in[0];
    const float* w_enc  = (const float*)d_in[1];
    const float* w_dec  = (const float*)d_in[2];
    const float* b_enc  = (const float*)d_in[3];
    const float* b_pre  = (const float*)d_in[4];
    const unsigned char* dead_mask = (const unsigned char*)d_in[5];
    const int* num_dead = (const int*)d_in[6];
    float* out = (float*)d_out;

    char* base = (char*)d_ws;
    char* w = base;
    auto alloc = [&](size_t bytes) -> char* {
        char* p = w;
        w += (bytes + 255) & ~(size_t)255;
        return p;
    };
    unsigned short* p16 = (unsigned short*)alloc((size_t)BATCH * D_HIDDEN * 2); // 128 MB
    double* mu       = (double*)alloc((size_t)BATCH * 8);
    double* stdv     = (double*)alloc((size_t)BATCH * 8);
    double* sinv     = (double*)alloc((size_t)BATCH * 8);
    int* topk_idx    = (int*)alloc((size_t)BATCH * KSEL * 4);
    float* topk_val  = (float*)alloc((size_t)BATCH * KSEL * 4);
    int* dead_idx    = (int*)alloc((size_t)NDEAD * 4);
    int* dead_cnt    = (int*)alloc(256);
    int* sure_cnt    = (int*)alloc((size_t)BATCH * 4);
    int* tie_cnt     = (int*)alloc((size_t)BATCH * 4);
    int* cand_col    = (int*)alloc((size_t)BATCH * TIECAP * 4);      // 2 MB
    double* cand_val = (double*)alloc((size_t)BATCH * TIECAP * 8);   // 4 MB
    float* xch       = (float*)alloc((size_t)BATCH * D_MODEL * 4);   // 32 MB
    float* xcl       = (float*)alloc((size_t)BATCH * D_MODEL * 4);   // 32 MB
    unsigned short* Ahp = (unsigned short*)alloc((size_t)BATCH * D_MODEL * 2);    // 16 MB
    char* region     = alloc((size_t)D_HIDDEN * D_MODEL * 4);                     // 512 MB
    const size_t need_small = (size_t)(w - base);
    // optional dedicated wT (bigws): one extra 512 MB block
    float* wT_big    = (float*)alloc((size_t)D_HIDDEN * D_MODEL * 4);
    const size_t need_big = (size_t)(w - base);
    const bool bigws = (ws_size >= need_big);
    (void)need_small;

    // time-multiplexed region:
    unsigned short* Bhp = (unsigned short*)region;                 // 256 MB, enc phase
    float* wT_small = (float*)region;                              // 512 MB (fallback, after enc)
    unsigned short* wd16 = (unsigned short*)region;                // 256 MB, decode phase
    unsigned short* Bhd  = (unsigned short*)(region + (size_t)D_HIDDEN * D_MODEL * 2); // 16 MB
    unsigned short* Ahd  = Ahp;                                    // 8 MB (Ahp dead after enc)
    float* wT = bigws ? wT_big : wT_small;

    float* out0 = out;                                   // recons
    float* out1 = out + (size_t)BATCH * D_MODEL;         // auxk
    float* out_last = out + (size_t)2 * BATCH * D_MODEL; // num_dead

    prep_kernel<<<BATCH, 256, 0, stream>>>(x, b_pre, mu, stdv, sinv, Ahp, xch, xcl);
    dead_scan_kernel<<<1, 64, 0, stream>>>(dead_mask, dead_idx, dead_cnt, num_dead, out_last);
    if (bigws) {
        wprep_kernel<<<dim3(D_MODEL / 32, D_HIDDEN / 32), 256, 0, stream>>>(w_enc, Bhp, wT);
    } else {
        bsplit_kernel<<<dim3(D_MODEL / 32, D_HIDDEN / 32), 256, 0, stream>>>(w_enc, Bhp);
    }
    mm256_kernel<0><<<(BATCH / 256) * (D_HIDDEN / 256), 512, 0, stream>>>(
        Ahp, Bhp, D_MODEL, BATCH / 256, b_enc, nullptr, nullptr, p16, (long)D_HIDDEN);
    if (!bigws) {
        wencT_kernel<<<dim3(D_MODEL / 32, D_HIDDEN / 32), 256, 0, stream>>>(w_enc, wT);
    }
    topk_sel_kernel<<<BATCH, 256, 0, stream>>>(p16, topk_idx, topk_val, sure_cnt, tie_cnt, cand_col);
    topk_refine_kernel<<<dim3(BATCH, 16), 256, 0, stream>>>(
        tie_cnt, cand_col, cand_val, xch, xcl, wT, b_enc);
    topk_fin_kernel<<<BATCH, 256, 0, stream>>>(
        sure_cnt, tie_cnt, cand_col, cand_val, topk_idx, topk_val);
    auxg_kernel<<<BATCH, 256, 0, stream>>>(p16, dead_idx, dead_cnt, Ahd);
    auxb_kernel<<<dim3(NDEAD / 32, D_MODEL / 32), 256, 0, stream>>>(w_dec, dead_idx, Bhd);
    wdec2bf_kernel<<<(int)(((size_t)D_HIDDEN * D_MODEL) / (256 * 8)), 256, 0, stream>>>(w_dec, wd16);
    decode_kernel<<<BATCH, 256, 0, stream>>>(topk_idx, topk_val, wd16, b_pre, mu, stdv, out0);
    mm_kernel<1><<<(BATCH / 128) * (D_MODEL / 128), 256, 0, stream>>>(
        Ahd, Bhd, NDEAD, BATCH / 128, b_pre, mu, stdv, out1, (long)D_MODEL);
}

// Round 13
// 2068.512 us; speedup vs baseline: 1.8208x; 1.0265x over previous
//
#include <hip/hip_runtime.h>
#include <math.h>

#define D_MODEL  4096
#define D_HIDDEN 32768
#define BATCH    2048
#define KSEL     128
#define NDEAD    2048
#define TIECAP   256

#define NB_SEL 2048
#define NB_AG  2048
#define NB_AB  8192
#define NB_WD  8192

typedef short s16x8 __attribute__((ext_vector_type(8)));
typedef float f32x4 __attribute__((ext_vector_type(4)));

// -------------------- helpers --------------------
__device__ __forceinline__ unsigned int fkey(float f) {
    unsigned int u = __float_as_uint(f);
    return (u & 0x80000000u) ? ~u : (u | 0x80000000u);
}
__device__ __forceinline__ unsigned short f2bf(float f) {  // RTNE
    unsigned int u = __float_as_uint(f);
    u += 0x7FFFu + ((u >> 16) & 1u);
    return (unsigned short)(u >> 16);
}
__device__ __forceinline__ float bf2f(unsigned short h) {
    return __uint_as_float(((unsigned int)h) << 16);
}
// per-16-bit-lane order-preserving key transform (packed pair)
__device__ __forceinline__ unsigned int key16x2(unsigned int u) {
    const unsigned int s = (u >> 15) & 0x10001u;
    const unsigned int mask = s * 0xFFFFu;
    return (u ^ mask) | (~mask & 0x80008000u);
}
__device__ __forceinline__ float unkey16(unsigned int k) {  // 16-bit key -> float
    const unsigned int u = (k & 0x8000u) ? (k & 0x7FFFu) : (~k & 0xFFFFu);
    return __uint_as_float(u << 16);
}
__device__ __forceinline__ void async_copy16(void* lds_dst, const void* gsrc) {
    __builtin_amdgcn_global_load_lds(
        (const __attribute__((address_space(1))) unsigned int*)gsrc,
        (__attribute__((address_space(3))) unsigned int*)lds_dst,
        16, 0, 0);
}

// ---- prep: LayerNorm + xc->bf16 + Dekker pair; block BATCH does the dead scan ----
__global__ __launch_bounds__(256) void prep_kernel(
    const float* __restrict__ x, const float* __restrict__ b_pre,
    double* __restrict__ mu, double* __restrict__ stdv, double* __restrict__ sinv,
    unsigned short* __restrict__ Ahp, float* __restrict__ xch, float* __restrict__ xcl,
    const unsigned char* __restrict__ mask8, int* __restrict__ dead_idx,
    int* __restrict__ dead_cnt, const int* __restrict__ num_dead_in,
    float* __restrict__ out_last)
{
    const int row = blockIdx.x;
    const int tid = threadIdx.x;
    if (row == BATCH) {
        // dead-mask scan on wave 0 (identical to old dead_scan_kernel)
        if (tid >= 64) return;
        const int lane = tid;
        int c = 0;
        for (int j = lane; j < D_HIDDEN; j += 64) c += (mask8[j] != 0);
#pragma unroll
        for (int off = 32; off > 0; off >>= 1) c += __shfl_down(c, off, 64);
        const int total_u8 = __shfl(c, 0, 64);
        const bool u8mode = (total_u8 == NDEAD);
        const int* mask32 = (const int*)mask8;
        int cnt = 0;
        for (int base = 0; base < D_HIDDEN; base += 64) {
            const int j = base + lane;
            const bool d = u8mode ? (mask8[j] != 0) : (mask32[j] != 0);
            const unsigned long long b = __ballot(d);
            const int pre = __popcll(b & ((1ull << lane) - 1ull));
            if (d && (cnt + pre) < NDEAD) dead_idx[cnt + pre] = j;
            cnt += __popcll(b);
        }
        const int cc = cnt > NDEAD ? NDEAD : cnt;
        if (lane == 0) {
            *dead_cnt = cc;
            *out_last = (float)(*num_dead_in);
        }
        for (int t = cc + lane; t < NDEAD; t += 64) dead_idx[t] = 0;
        return;
    }
    const float* xr = x + (size_t)row * D_MODEL;
    float xv[16];
#pragma unroll
    for (int i = 0; i < 16; ++i) xv[i] = xr[tid + 256 * i];
    double s = 0.0;
#pragma unroll
    for (int i = 0; i < 16; ++i) s += (double)xv[i];
    __shared__ double red[4];
    __shared__ double sh_mu, sh_si;
    const int lane = tid & 63, wid = tid >> 6;
#pragma unroll
    for (int off = 32; off > 0; off >>= 1) s += __shfl_down(s, off, 64);
    if (lane == 0) red[wid] = s;
    __syncthreads();
    if (tid == 0) sh_mu = (red[0] + red[1] + red[2] + red[3]) / (double)D_MODEL;
    __syncthreads();
    const double m = sh_mu;
    double s2 = 0.0;
#pragma unroll
    for (int i = 0; i < 16; ++i) { double d = (double)xv[i] - m; s2 += d * d; }
#pragma unroll
    for (int off = 32; off > 0; off >>= 1) s2 += __shfl_down(s2, off, 64);
    __syncthreads();
    if (lane == 0) red[wid] = s2;
    __syncthreads();
    if (tid == 0) {
        double var = (red[0] + red[1] + red[2] + red[3]) / (double)(D_MODEL - 1);
        double sd = sqrt(var);
        mu[row] = m;
        stdv[row] = sd;
        const double si = 1.0 / (sd + 1e-5);
        sinv[row] = si;
        sh_si = si;
    }
    __syncthreads();
    const double si = sh_si;
#pragma unroll
    for (int i = 0; i < 4; ++i) {
        const int j = (i * 256 + tid) * 4;
        const float4 x4 = *(const float4*)(xr + j);
        const float4 bp = *(const float4*)(b_pre + j);
        float vf[4], hi[4], lo[4];
        const float xe[4] = {x4.x, x4.y, x4.z, x4.w};
        const float be[4] = {bp.x, bp.y, bp.z, bp.w};
#pragma unroll
        for (int e = 0; e < 4; ++e) {
            const double t = ((double)xe[e] - m) * si;
            vf[e] = (float)t - be[e];
            const double a = t - (double)be[e];
            hi[e] = (float)a;
            lo[e] = (float)(a - (double)hi[e]);
        }
        uint2 hw;
        hw.x = (unsigned)f2bf(vf[0]) | ((unsigned)f2bf(vf[1]) << 16);
        hw.y = (unsigned)f2bf(vf[2]) | ((unsigned)f2bf(vf[3]) << 16);
        *(uint2*)(Ahp + (size_t)row * D_MODEL + j) = hw;
        *(float4*)(xch + (size_t)row * D_MODEL + j) = make_float4(hi[0], hi[1], hi[2], hi[3]);
        *(float4*)(xcl + (size_t)row * D_MODEL + j) = make_float4(lo[0], lo[1], lo[2], lo[3]);
    }
}

// -------------------- B: w_enc[k][n] -> Bh[n][k] bf16 (fallback path) ---------
__global__ __launch_bounds__(256) void bsplit_kernel(
    const float* __restrict__ w_enc, unsigned short* __restrict__ Bhp)
{
    __shared__ float t[32][33];
    const int bk = blockIdx.x * 32;
    const int bn = blockIdx.y * 32;
    const int tid = threadIdx.x;
    const int lr = tid >> 3, lc4 = (tid & 7) * 4;
    const float4 v = *(const float4*)(w_enc + (size_t)(bk + lr) * D_HIDDEN + bn + lc4);
    t[lr][lc4 + 0] = v.x; t[lr][lc4 + 1] = v.y; t[lr][lc4 + 2] = v.z; t[lr][lc4 + 3] = v.w;
    __syncthreads();
    float o[4];
#pragma unroll
    for (int j = 0; j < 4; ++j) o[j] = t[lc4 + j][lr];
    uint2 hw;
    hw.x = (unsigned)f2bf(o[0]) | ((unsigned)f2bf(o[1]) << 16);
    hw.y = (unsigned)f2bf(o[2]) | ((unsigned)f2bf(o[3]) << 16);
    *(uint2*)(Bhp + (size_t)(bn + lr) * D_MODEL + bk + lc4) = hw;
}

// -------------------- w_enc transpose to fp32 [n][k] (fallback path) ----------
__global__ __launch_bounds__(256) void wencT_kernel(
    const float* __restrict__ w_enc, float* __restrict__ wT)
{
    __shared__ float t[32][33];
    const int bk = blockIdx.x * 32;
    const int bn = blockIdx.y * 32;
    const int tid = threadIdx.x;
    const int lr = tid >> 3, lc4 = (tid & 7) * 4;
    const float4 v = *(const float4*)(w_enc + (size_t)(bk + lr) * D_HIDDEN + bn + lc4);
    t[lr][lc4 + 0] = v.x; t[lr][lc4 + 1] = v.y; t[lr][lc4 + 2] = v.z; t[lr][lc4 + 3] = v.w;
    __syncthreads();
    const int j = tid >> 3, i4 = (tid & 7) * 4;
    float4 o;
    o.x = t[i4 + 0][j]; o.y = t[i4 + 1][j]; o.z = t[i4 + 2][j]; o.w = t[i4 + 3][j];
    *(float4*)(wT + (size_t)(bn + j) * D_MODEL + bk + i4) = o;
}

// ------- fused: one w_enc pass -> Bhp (bf16 T) + wT (fp32 T)  (bigws path) -----
__global__ __launch_bounds__(256) void wprep_kernel(
    const float* __restrict__ w_enc, unsigned short* __restrict__ Bhp,
    float* __restrict__ wT)
{
    __shared__ float t[32][33];
    const int bk = blockIdx.x * 32;
    const int bn = blockIdx.y * 32;
    const int tid = threadIdx.x;
    const int lr = tid >> 3, lc4 = (tid & 7) * 4;
    const float4 v = *(const float4*)(w_enc + (size_t)(bk + lr) * D_HIDDEN + bn + lc4);
    t[lr][lc4 + 0] = v.x; t[lr][lc4 + 1] = v.y; t[lr][lc4 + 2] = v.z; t[lr][lc4 + 3] = v.w;
    __syncthreads();
    float o[4];
#pragma unroll
    for (int j = 0; j < 4; ++j) o[j] = t[lc4 + j][lr];
    uint2 hw;
    hw.x = (unsigned)f2bf(o[0]) | ((unsigned)f2bf(o[1]) << 16);
    hw.y = (unsigned)f2bf(o[2]) | ((unsigned)f2bf(o[3]) << 16);
    *(uint2*)(Bhp + (size_t)(bn + lr) * D_MODEL + bk + lc4) = hw;
    *(float4*)(wT + (size_t)(bn + lr) * D_MODEL + bk + lc4) = make_float4(o[0], o[1], o[2], o[3]);
}

// ======== 256x256 bf16 MFMA GEMM, BK=64, 8 waves, 4-phase/K-tile, half-tile pipe ====
template<int EPI>
__global__ __launch_bounds__(512) void mm256_kernel(
    const unsigned short* __restrict__ A, const unsigned short* __restrict__ B,
    const int kdim, const int ntiles_x,
    const float* __restrict__ bias_n,
    const double* __restrict__ muv, const double* __restrict__ stdvv,
    void* __restrict__ outp, const long ostride)
{
    __shared__ unsigned short lds[2 * 4 * 8192];   // 128 KB: 2 bufs x 4 subplanes
    const int tid = threadIdx.x;
    const int lane = tid & 63, wid = tid >> 6;     // 8 waves
    const int cpx = gridDim.x >> 3;                // XCD swizzle (grid % 8 == 0)
    const int orig = blockIdx.x;
    const int wg = (orig & 7) * cpx + (orig >> 3);
    const int m0 = (wg % ntiles_x) * 256;
    const int n0 = (wg / ntiles_x) * 256;
    const int wm = (wid >> 2) * 128;               // 2 M-halves
    const int wn = (wid & 3) * 64;                 // 4 N-quarters
    const int fr = lane & 15, kq = lane >> 4;
    const int swr = (fr >> 1) & 3;                 // read-side quad XOR
    const int qg = (lane & 3) ^ ((lane >> 3) & 3); // write-side source quad
    const int qo = (kq ^ swr) * 8;

    f32x4 acc[8][4];
#pragma unroll
    for (int i = 0; i < 8; ++i)
#pragma unroll
        for (int j = 0; j < 4; ++j) acc[i][j] = (f32x4){0.f, 0.f, 0.f, 0.f};

    const unsigned short* sH0[4];
    int dH0[4];
#pragma unroll
    for (int j = 0; j < 4; ++j) {
        const int g = wid * 4 + j;
        const int is_b = g >> 4;
        const int sr = g & 15;
        const unsigned short* gp = is_b ? B : A;
        const int t0 = is_b ? n0 : m0;
        sH0[j] = gp + (size_t)(t0 + sr * 16 + (lane >> 2)) * kdim + qg * 8;
        dH0[j] = (is_b ? 2 : 0) * 8192 + sr * 512;
    }

    const int NT = kdim >> 6;
#pragma unroll
    for (int j = 0; j < 4; ++j) async_copy16(lds + dH0[j], sH0[j]);
#pragma unroll
    for (int j = 0; j < 4; ++j) async_copy16(lds + 8192 + dH0[j], sH0[j] + 32);
    if (NT > 1) {
#pragma unroll
        for (int j = 0; j < 4; ++j) async_copy16(lds + 32768 + dH0[j], sH0[j] + 64);
    }

    for (int t = 0; t < NT; ++t) {
        const int cur = t & 1;
        unsigned short* bb = (unsigned short*)lds + cur * 32768;
        unsigned short* nb = (unsigned short*)lds + (cur ^ 1) * 32768;
        const int k1 = (t + 1) << 6;
        const int k2 = (t + 2) << 6;

        // ======== kk0 half: wait H0(t) ========
        if (t < NT - 1) { asm volatile("s_waitcnt vmcnt(8)" ::: "memory"); }
        else            { asm volatile("s_waitcnt vmcnt(4)" ::: "memory"); }
        asm volatile("s_barrier" ::: "memory");
        __builtin_amdgcn_sched_barrier(0);
        {
            if (t + 1 < NT) {
                async_copy16(nb + 8192 + dH0[0], sH0[0] + k1 + 32);
                async_copy16(nb + 8192 + dH0[1], sH0[1] + k1 + 32);
            }
            s16x8 a[4], b[4];
#pragma unroll
            for (int mi = 0; mi < 4; ++mi)
                a[mi] = *(const s16x8*)(bb + (wm + mi * 16 + fr) * 32 + qo);
#pragma unroll
            for (int ni = 0; ni < 4; ++ni)
                b[ni] = *(const s16x8*)(bb + 2 * 8192 + (wn + ni * 16 + fr) * 32 + qo);
            __builtin_amdgcn_s_setprio(1);
#pragma unroll
            for (int mi = 0; mi < 4; ++mi)
#pragma unroll
                for (int ni = 0; ni < 4; ++ni)
                    acc[mi][ni] = __builtin_amdgcn_mfma_f32_16x16x32_bf16(a[mi], b[ni], acc[mi][ni], 0, 0, 0);
            __builtin_amdgcn_s_setprio(0);
            asm volatile("s_barrier" ::: "memory");
            __builtin_amdgcn_sched_barrier(0);
            if (t + 1 < NT) {
                async_copy16(nb + 8192 + dH0[2], sH0[2] + k1 + 32);
                async_copy16(nb + 8192 + dH0[3], sH0[3] + k1 + 32);
            }
            s16x8 a2[4];
#pragma unroll
            for (int mi = 0; mi < 4; ++mi)
                a2[mi] = *(const s16x8*)(bb + (wm + (mi + 4) * 16 + fr) * 32 + qo);
            __builtin_amdgcn_s_setprio(1);
#pragma unroll
            for (int mi = 0; mi < 4; ++mi)
#pragma unroll
                for (int ni = 0; ni < 4; ++ni)
                    acc[mi + 4][ni] = __builtin_amdgcn_mfma_f32_16x16x32_bf16(a2[mi], b[ni], acc[mi + 4][ni], 0, 0, 0);
            __builtin_amdgcn_s_setprio(0);
        }
        // ======== kk1 half: wait H1(t) ========
        if (t < NT - 1) { asm volatile("s_waitcnt vmcnt(8)" ::: "memory"); }
        else            { asm volatile("s_waitcnt vmcnt(0)" ::: "memory"); }
        asm volatile("s_barrier" ::: "memory");
        __builtin_amdgcn_sched_barrier(0);
        {
            if (t + 2 < NT) {
                async_copy16(bb + dH0[0], sH0[0] + k2);
                async_copy16(bb + dH0[1], sH0[1] + k2);
            }
            s16x8 a[4], b[4];
#pragma unroll
            for (int mi = 0; mi < 4; ++mi)
                a[mi] = *(const s16x8*)(bb + 8192 + (wm + mi * 16 + fr) * 32 + qo);
#pragma unroll
            for (int ni = 0; ni < 4; ++ni)
                b[ni] = *(const s16x8*)(bb + 3 * 8192 + (wn + ni * 16 + fr) * 32 + qo);
            __builtin_amdgcn_s_setprio(1);
#pragma unroll
            for (int mi = 0; mi < 4; ++mi)
#pragma unroll
                for (int ni = 0; ni < 4; ++ni)
                    acc[mi][ni] = __builtin_amdgcn_mfma_f32_16x16x32_bf16(a[mi], b[ni], acc[mi][ni], 0, 0, 0);
            __builtin_amdgcn_s_setprio(0);
            asm volatile("s_barrier" ::: "memory");
            __builtin_amdgcn_sched_barrier(0);
            if (t + 2 < NT) {
                async_copy16(bb + dH0[2], sH0[2] + k2);
                async_copy16(bb + dH0[3], sH0[3] + k2);
            }
            s16x8 a2[4];
#pragma unroll
            for (int mi = 0; mi < 4; ++mi)
                a2[mi] = *(const s16x8*)(bb + 8192 + (wm + (mi + 4) * 16 + fr) * 32 + qo);
            __builtin_amdgcn_s_setprio(1);
#pragma unroll
            for (int mi = 0; mi < 4; ++mi)
#pragma unroll
                for (int ni = 0; ni < 4; ++ni)
                    acc[mi + 4][ni] = __builtin_amdgcn_mfma_f32_16x16x32_bf16(a2[mi], b[ni], acc[mi + 4][ni], 0, 0, 0);
            __builtin_amdgcn_s_setprio(0);
        }
    }

#pragma unroll
    for (int ni = 0; ni < 4; ++ni) {
        const int col = n0 + wn + ni * 16 + fr;
        const float be = bias_n[col];
#pragma unroll
        for (int mi = 0; mi < 8; ++mi) {
            const int rb = m0 + wm + mi * 16 + kq * 4;
            if (EPI == 0) {
                unsigned short* O = (unsigned short*)outp;
#pragma unroll
                for (int r = 0; r < 4; ++r)
                    O[(size_t)(rb + r) * ostride + col] = f2bf(acc[mi][ni][r] + be);
            } else {
                float* O = (float*)outp;
#pragma unroll
                for (int r = 0; r < 4; ++r) {
                    const int m = rb + r;
                    O[(size_t)m * ostride + col] =
                        (acc[mi][ni][r] + be) * (float)stdvv[m] + (float)muv[m];
                }
            }
        }
    }
}

// ======= comboA: [sel | auxg | auxb(nb_ab) | wdec2bf(nb_wd)] in one launch =======
__global__ __launch_bounds__(256) void comboA_kernel(
    const unsigned short* __restrict__ p16,
    int* __restrict__ topk_idx, float* __restrict__ topk_val,
    int* __restrict__ sure_cnt, int* __restrict__ tie_cnt, int* __restrict__ cand_col,
    const int* __restrict__ dead_idx, const int* __restrict__ dead_cnt,
    unsigned short* __restrict__ Ahd,
    const float* __restrict__ w_dec, unsigned short* __restrict__ Bhd,
    unsigned short* __restrict__ wd16,
    const int nb_ab, const int nb_wd)
{
    const int b = blockIdx.x;
    const int tid = threadIdx.x;
    __shared__ float tsm[32][33];   // auxb transpose buffer
    __shared__ int red[4];
    __shared__ int sh_sel, sh_tie;

    if (b < NB_SEL) {
        // ---------------- topk_sel (identical math) ----------------
        const int row = b;
        const int lane = tid & 63, wid = tid >> 6;
        const unsigned short* pr = p16 + (size_t)row * D_HIDDEN;
        uint4 kr[16];
#pragma unroll
        for (int i = 0; i < 16; ++i) {
            uint4 w = *(const uint4*)(pr + (i * 256 + tid) * 8);
            w.x = key16x2(w.x); w.y = key16x2(w.y); w.z = key16x2(w.z); w.w = key16x2(w.w);
            kr[i] = w;
        }
        if (tid == 0) { sh_sel = 0; sh_tie = 0; }
        unsigned int lo = 0, hi = 65535;
        while (lo < hi) {
            const unsigned int mid = (lo + hi) >> 1;
            int c = 0;
#pragma unroll
            for (int i = 0; i < 16; ++i) {
                const unsigned int u[4] = {kr[i].x, kr[i].y, kr[i].z, kr[i].w};
#pragma unroll
                for (int e = 0; e < 4; ++e) {
                    c += (int)((u[e] & 0xFFFFu) > mid);
                    c += (int)((u[e] >> 16) > mid);
                }
            }
#pragma unroll
            for (int off = 32; off > 0; off >>= 1) c += __shfl_down(c, off, 64);
            if (lane == 0) red[wid] = c;
            __syncthreads();
            const int total = red[0] + red[1] + red[2] + red[3];
            if (total < KSEL) hi = mid; else lo = mid + 1;
            __syncthreads();
        }
        const unsigned int K16 = lo;
        const float vc = unkey16(K16);
        const float DLT = 1.3e-2f;
        const float sureT = vc + 2.f * DLT;
        const float candT = vc - 2.f * DLT;
        const unsigned int sK = fkey(sureT) >> 16;
        const unsigned int cK = fkey(candT) >> 16;
        int* oidx = topk_idx + row * KSEL;
        float* oval = topk_val + row * KSEL;
        int* cc = cand_col + row * TIECAP;
#pragma unroll
        for (int i = 0; i < 16; ++i) {
            const int j0 = (i * 256 + tid) * 8;
            const unsigned int u[4] = {kr[i].x, kr[i].y, kr[i].z, kr[i].w};
#pragma unroll
            for (int e = 0; e < 8; ++e) {
                const unsigned int k = (e & 1) ? (u[e >> 1] >> 16) : (u[e >> 1] & 0xFFFFu);
                if (k < cK) continue;
                const float v = unkey16(k);
                if (k > sK && v > sureT) {
                    const int pos = atomicAdd(&sh_sel, 1);
                    oidx[pos] = j0 + e;
                    oval[pos] = v > 0.f ? v : 0.f;
                } else if (v >= candT) {
                    const int t = atomicAdd(&sh_tie, 1);
                    if (t < TIECAP) cc[t] = j0 + e;
                }
            }
        }
        __syncthreads();
        if (tid == 0) {
            sure_cnt[row] = sh_sel;
            tie_cnt[row] = sh_tie > TIECAP ? TIECAP : sh_tie;
        }
        return;
    }
    if (b < NB_SEL + NB_AG) {
        // ---------------- auxg: gather+relu p16 dead cols ----------------
        const int r = b - NB_SEL;
        const int dc = *dead_cnt;
#pragma unroll
        for (int i = 0; i < 8; ++i) {
            const int c = i * 256 + tid;
            unsigned short v = 0;
            if (c < dc) {
                const unsigned short u = p16[(size_t)r * D_HIDDEN + dead_idx[c]];
                v = (u & 0x8000u) ? (unsigned short)0 : u;
            }
            Ahd[(size_t)r * NDEAD + c] = v;
        }
        return;
    }
    if (b < NB_SEL + NB_AG + nb_ab) {
        // ---------------- auxb: w_dec[dead] gather+transpose -> bf16 ----------------
        const int idx = b - (NB_SEL + NB_AG);
        const int k0 = (idx & 63) * 32;          // NDEAD/32 = 64
        const int n0 = (idx >> 6) * 32;
        const int i = tid >> 3, j4 = (tid & 7) * 4;
        const int srow = dead_idx[k0 + i];
        const float4 v = *(const float4*)(w_dec + (size_t)srow * D_MODEL + n0 + j4);
        tsm[i][j4 + 0] = v.x; tsm[i][j4 + 1] = v.y; tsm[i][j4 + 2] = v.z; tsm[i][j4 + 3] = v.w;
        __syncthreads();
        const int j = tid >> 3, i4 = (tid & 7) * 4;
        uint2 hw;
        hw.x = (unsigned)f2bf(tsm[i4 + 0][j]) | ((unsigned)f2bf(tsm[i4 + 1][j]) << 16);
        hw.y = (unsigned)f2bf(tsm[i4 + 2][j]) | ((unsigned)f2bf(tsm[i4 + 3][j]) << 16);
        *(uint2*)(Bhd + (size_t)(n0 + j) * NDEAD + k0 + i4) = hw;
        return;
    }
    {
        // ---------------- wdec2bf: w_dec -> bf16 (block-strided) ----------------
        const int bb = b - (NB_SEL + NB_AG + nb_ab);
        (void)nb_wd;
        const size_t base0 = (size_t)bb * 16384;
#pragma unroll
        for (int it = 0; it < 8; ++it) {
            const size_t off = base0 + (size_t)it * 2048 + (size_t)tid * 8;
            const float4 a = *(const float4*)(w_dec + off);
            const float4 c = *(const float4*)(w_dec + off + 4);
            uint4 o;
            o.x = (unsigned)f2bf(a.x) | ((unsigned)f2bf(a.y) << 16);
            o.y = (unsigned)f2bf(a.z) | ((unsigned)f2bf(a.w) << 16);
            o.z = (unsigned)f2bf(c.x) | ((unsigned)f2bf(c.y) << 16);
            o.w = (unsigned)f2bf(c.z) | ((unsigned)f2bf(c.w) << 16);
            *(uint4*)(wd16 + off) = o;
        }
        return;
    }
}

// ---------- standalone auxb + wdec2bf (fallback ordering) ----------
__global__ __launch_bounds__(256) void auxb_kernel(
    const float* __restrict__ w_dec, const int* __restrict__ dead_idx,
    unsigned short* __restrict__ Bhd)
{
    __shared__ float t[32][33];
    const int k0 = blockIdx.x * 32;
    const int n0 = blockIdx.y * 32;
    const int tid = threadIdx.x;
    const int i = tid >> 3, j4 = (tid & 7) * 4;
    const int srow = dead_idx[k0 + i];
    const float4 v = *(const float4*)(w_dec + (size_t)srow * D_MODEL + n0 + j4);
    t[i][j4 + 0] = v.x; t[i][j4 + 1] = v.y; t[i][j4 + 2] = v.z; t[i][j4 + 3] = v.w;
    __syncthreads();
    const int j = tid >> 3, i4 = (tid & 7) * 4;
    uint2 hw;
    hw.x = (unsigned)f2bf(t[i4 + 0][j]) | ((unsigned)f2bf(t[i4 + 1][j]) << 16);
    hw.y = (unsigned)f2bf(t[i4 + 2][j]) | ((unsigned)f2bf(t[i4 + 3][j]) << 16);
    *(uint2*)(Bhd + (size_t)(n0 + j) * NDEAD + k0 + i4) = hw;
}

__global__ __launch_bounds__(256) void wdec2bf_kernel(
    const float* __restrict__ w_dec, unsigned short* __restrict__ wd16)
{
    const size_t gid = (size_t)blockIdx.x * 256 + threadIdx.x;
    const size_t base = gid * 8;
    const float4 a = *(const float4*)(w_dec + base);
    const float4 b = *(const float4*)(w_dec + base + 4);
    uint4 o;
    o.x = (unsigned)f2bf(a.x) | ((unsigned)f2bf(a.y) << 16);
    o.y = (unsigned)f2bf(a.z) | ((unsigned)f2bf(a.w) << 16);
    o.z = (unsigned)f2bf(b.x) | ((unsigned)f2bf(b.y) << 16);
    o.w = (unsigned)f2bf(b.z) | ((unsigned)f2bf(b.w) << 16);
    *(uint4*)(wd16 + base) = o;
}

// ---------- topk phase 2: exact fp64 refinement via Dekker xc pair ----------
__global__ __launch_bounds__(256) void topk_refine_kernel(
    const int* __restrict__ tie_cnt, const int* __restrict__ cand_col,
    double* __restrict__ cand_val,
    const float* __restrict__ xch, const float* __restrict__ xcl,
    const float* __restrict__ wT, const float* __restrict__ b_enc)
{
    const int row = blockIdx.x;
    const int tid = threadIdx.x;
    const int lane = tid & 63, wid = tid >> 6;
    const int T = tie_cnt[row];
    const int base = (int)blockIdx.y * 4 + wid;   // gridDim.y = 16 -> base in [0,64)
    if (base >= T) return;
    const float* hr = xch + (size_t)row * D_MODEL;
    const float* lr2 = xcl + (size_t)row * D_MODEL;
    for (int slot = base; slot < T; slot += 64) {
        const int col = cand_col[row * TIECAP + slot];
        const float* wr = wT + (size_t)col * D_MODEL;
        double s0 = 0.0, s1 = 0.0;
        for (int k = lane * 4; k < D_MODEL; k += 512) {
            {
                const float4 h = *(const float4*)(hr + k);
                const float4 l = *(const float4*)(lr2 + k);
                const float4 w4 = *(const float4*)(wr + k);
                s0 += ((double)h.x + (double)l.x) * (double)w4.x;
                s0 += ((double)h.y + (double)l.y) * (double)w4.y;
                s0 += ((double)h.z + (double)l.z) * (double)w4.z;
                s0 += ((double)h.w + (double)l.w) * (double)w4.w;
            }
            {
                const int k2 = k + 256;
                const float4 h = *(const float4*)(hr + k2);
                const float4 l = *(const float4*)(lr2 + k2);
                const float4 w4 = *(const float4*)(wr + k2);
                s1 += ((double)h.x + (double)l.x) * (double)w4.x;
                s1 += ((double)h.y + (double)l.y) * (double)w4.y;
                s1 += ((double)h.z + (double)l.z) * (double)w4.z;
                s1 += ((double)h.w + (double)l.w) * (double)w4.w;
            }
        }
        double s = s0 + s1;
#pragma unroll
        for (int off = 32; off > 0; off >>= 1) s += __shfl_down(s, off, 64);
        if (lane == 0) cand_val[row * TIECAP + slot] = s + (double)b_enc[col];
    }
}

// ---------- decode_fin: per-row candidate rank (fin) fused with sparse decode ----
__global__ __launch_bounds__(256) void decode_fin_kernel(
    const int* __restrict__ sure_cnt, const int* __restrict__ tie_cnt,
    const int* __restrict__ cand_col, const double* __restrict__ cand_val,
    const int* __restrict__ topk_idx, const float* __restrict__ topk_val,
    const unsigned short* __restrict__ wd16, const float* __restrict__ b_pre,
    const double* __restrict__ mu, const double* __restrict__ stdv,
    float* __restrict__ out0)
{
    const int row = blockIdx.x;
    const int tid = threadIdx.x;
    __shared__ double vals[TIECAP];
    __shared__ int cols[TIECAP];
    __shared__ int sidx[KSEL];
    __shared__ float sval[KSEL];
    const int G = sure_cnt[row];
    const int T = tie_cnt[row];
    const int R = KSEL - G;
    if (tid < T) {
        vals[tid] = cand_val[row * TIECAP + tid];
        cols[tid] = cand_col[row * TIECAP + tid];
    }
    if (tid < G) {
        sidx[tid] = topk_idx[row * KSEL + tid];
        sval[tid] = topk_val[row * KSEL + tid];
    }
    __syncthreads();
    if (tid < T) {
        const double v = vals[tid];
        const int c = cols[tid];
        int rank = 0;
        for (int u = 0; u < T; ++u) {
            const double vu = vals[u];
            rank += (int)((vu > v) || (vu == v && cols[u] < c));
        }
        if (rank < R) {
            sidx[G + rank] = c;
            sval[G + rank] = v > 0.0 ? (float)v : 0.f;
        }
    }
    const int take = R < T ? R : T;
    if (tid >= take && tid < R) {
        sidx[G + tid] = (T > 0) ? cols[0] : 0;
        sval[G + tid] = 0.f;
    }
    __syncthreads();
    float acc[16];
#pragma unroll
    for (int i = 0; i < 16; ++i) acc[i] = 0.f;
    const int dbase = tid * 16;
    for (int k = 0; k < KSEL; ++k) {
        const float v = sval[k];
        if (v == 0.f) continue;
        const uint4* wr = (const uint4*)(wd16 + (size_t)sidx[k] * D_MODEL + dbase);
        const uint4 w0 = wr[0], w1 = wr[1];
        const unsigned int u[8] = {w0.x, w0.y, w0.z, w0.w, w1.x, w1.y, w1.z, w1.w};
#pragma unroll
        for (int i = 0; i < 8; ++i) {
            acc[2 * i]     += v * __uint_as_float(u[i] << 16);
            acc[2 * i + 1] += v * __uint_as_float(u[i] & 0xFFFF0000u);
        }
    }
    const float st = (float)stdv[row];
    const float mm = (float)mu[row];
    float* o = out0 + (size_t)row * D_MODEL + dbase;
#pragma unroll
    for (int i = 0; i < 16; ++i) {
        o[i] = (acc[i] + b_pre[dbase + i]) * st + mm;
    }
}

// -------------------- launch --------------------
extern "C" void kernel_launch(void* const* d_in, const int* in_sizes, int n_in,
                              void* d_out, int out_size, void* d_ws, size_t ws_size,
                              hipStream_t stream)
{
    (void)in_sizes; (void)n_in; (void)out_size;
    const float* x      = (const float*)d_in[0];
    const float* w_enc  = (const float*)d_in[1];
    const float* w_dec  = (const float*)d_in[2];
    const float* b_enc  = (const float*)d_in[3];
    const float* b_pre  = (const float*)d_in[4];
    const unsigned char* dead_mask = (const unsigned char*)d_in[5];
    const int* num_dead = (const int*)d_in[6];
    float* out = (float*)d_out;

    char* base = (char*)d_ws;
    char* w = base;
    auto alloc = [&](size_t bytes) -> char* {
        char* p = w;
        w += (bytes + 255) & ~(size_t)255;
        return p;
    };
    unsigned short* p16 = (unsigned short*)alloc((size_t)BATCH * D_HIDDEN * 2); // 128 MB
    double* mu       = (double*)alloc((size_t)BATCH * 8);
    double* stdv     = (double*)alloc((size_t)BATCH * 8);
    double* sinv     = (double*)alloc((size_t)BATCH * 8);
    int* topk_idx    = (int*)alloc((size_t)BATCH * KSEL * 4);
    float* topk_val  = (float*)alloc((size_t)BATCH * KSEL * 4);
    int* dead_idx    = (int*)alloc((size_t)NDEAD * 4);
    int* dead_cnt    = (int*)alloc(256);
    int* sure_cnt    = (int*)alloc((size_t)BATCH * 4);
    int* tie_cnt     = (int*)alloc((size_t)BATCH * 4);
    int* cand_col    = (int*)alloc((size_t)BATCH * TIECAP * 4);      // 2 MB
    double* cand_val = (double*)alloc((size_t)BATCH * TIECAP * 8);   // 4 MB
    float* xch       = (float*)alloc((size_t)BATCH * D_MODEL * 4);   // 32 MB
    float* xcl       = (float*)alloc((size_t)BATCH * D_MODEL * 4);   // 32 MB
    unsigned short* Ahp = (unsigned short*)alloc((size_t)BATCH * D_MODEL * 2);    // 16 MB
    char* region     = alloc((size_t)D_HIDDEN * D_MODEL * 4);                     // 512 MB
    // optional dedicated wT (bigws): one extra 512 MB block
    float* wT_big    = (float*)alloc((size_t)D_HIDDEN * D_MODEL * 4);
    const size_t need_big = (size_t)(w - base);
    const bool bigws = (ws_size >= need_big);

    // time-multiplexed region:
    unsigned short* Bhp = (unsigned short*)region;                 // 256 MB, enc phase
    float* wT_small = (float*)region;                              // 512 MB (fallback, after enc)
    unsigned short* wd16 = (unsigned short*)region;                // 256 MB, decode phase
    unsigned short* Bhd  = (unsigned short*)(region + (size_t)D_HIDDEN * D_MODEL * 2); // 16 MB
    unsigned short* Ahd  = Ahp;                                    // 8 MB (Ahp dead after enc)
    float* wT = bigws ? wT_big : wT_small;

    float* out0 = out;                                   // recons
    float* out1 = out + (size_t)BATCH * D_MODEL;         // auxk
    float* out_last = out + (size_t)2 * BATCH * D_MODEL; // num_dead

    prep_kernel<<<BATCH + 1, 256, 0, stream>>>(x, b_pre, mu, stdv, sinv, Ahp, xch, xcl,
                                               dead_mask, dead_idx, dead_cnt, num_dead, out_last);
    if (bigws) {
        wprep_kernel<<<dim3(D_MODEL / 32, D_HIDDEN / 32), 256, 0, stream>>>(w_enc, Bhp, wT);
    } else {
        bsplit_kernel<<<dim3(D_MODEL / 32, D_HIDDEN / 32), 256, 0, stream>>>(w_enc, Bhp);
    }
    mm256_kernel<0><<<(BATCH / 256) * (D_HIDDEN / 256), 512, 0, stream>>>(
        Ahp, Bhp, D_MODEL, BATCH / 256, b_enc, nullptr, nullptr, p16, (long)D_HIDDEN);
    if (bigws) {
        // sel || auxg || auxb || wdec2bf in one launch (wd16/Bhd live in region, wT is separate)
        comboA_kernel<<<NB_SEL + NB_AG + NB_AB + NB_WD, 256, 0, stream>>>(
            p16, topk_idx, topk_val, sure_cnt, tie_cnt, cand_col,
            dead_idx, dead_cnt, Ahd, w_dec, Bhd, wd16, NB_AB, NB_WD);
        mm256_kernel<1><<<(BATCH / 256) * (D_MODEL / 256), 512, 0, stream>>>(
            Ahd, Bhd, NDEAD, BATCH / 256, b_pre, mu, stdv, out1, (long)D_MODEL);
        topk_refine_kernel<<<dim3(BATCH, 16), 256, 0, stream>>>(
            tie_cnt, cand_col, cand_val, xch, xcl, wT, b_enc);
    } else {
        // region holds wT_small until refine completes -> sequential ordering
        wencT_kernel<<<dim3(D_MODEL / 32, D_HIDDEN / 32), 256, 0, stream>>>(w_enc, wT);
        comboA_kernel<<<NB_SEL + NB_AG, 256, 0, stream>>>(
            p16, topk_idx, topk_val, sure_cnt, tie_cnt, cand_col,
            dead_idx, dead_cnt, Ahd, w_dec, Bhd, wd16, 0, 0);
        topk_refine_kernel<<<dim3(BATCH, 16), 256, 0, stream>>>(
            tie_cnt, cand_col, cand_val, xch, xcl, wT, b_enc);
        auxb_kernel<<<dim3(NDEAD / 32, D_MODEL / 32), 256, 0, stream>>>(w_dec, dead_idx, Bhd);
        wdec2bf_kernel<<<(int)(((size_t)D_HIDDEN * D_MODEL) / (256 * 8)), 256, 0, stream>>>(w_dec, wd16);
        mm256_kernel<1><<<(BATCH / 256) * (D_MODEL / 256), 512, 0, stream>>>(
            Ahd, Bhd, NDEAD, BATCH / 256, b_pre, mu, stdv, out1, (long)D_MODEL);
    }
    decode_fin_kernel<<<BATCH, 256, 0, stream>>>(
        sure_cnt, tie_cnt, cand_col, cand_val, topk_idx, topk_val,
        wd16, b_pre, mu, stdv, out0);
}

// Round 14
// 1977.220 us; speedup vs baseline: 1.9049x; 1.0462x over previous
//
#include <hip/hip_runtime.h>
#include <math.h>

#define D_MODEL  4096
#define D_HIDDEN 32768
#define BATCH    2048
#define KSEL     128
#define NDEAD    2048
#define TIECAP   256

#define NB_SEL 2048
#define NB_AG  2048
#define NB_AB  8192
#define NB_WD  8192
#define NB_MM  128          // aux mm256 blocks inside comboB
#define NB_WPREP (128 * 1024)  // (D_MODEL/32) * (D_HIDDEN/32)

typedef short s16x8 __attribute__((ext_vector_type(8)));
typedef float f32x4 __attribute__((ext_vector_type(4)));

// -------------------- helpers --------------------
__device__ __forceinline__ unsigned int fkey(float f) {
    unsigned int u = __float_as_uint(f);
    return (u & 0x80000000u) ? ~u : (u | 0x80000000u);
}
__device__ __forceinline__ unsigned short f2bf(float f) {  // RTNE
    unsigned int u = __float_as_uint(f);
    u += 0x7FFFu + ((u >> 16) & 1u);
    return (unsigned short)(u >> 16);
}
__device__ __forceinline__ float bf2f(unsigned short h) {
    return __uint_as_float(((unsigned int)h) << 16);
}
// per-16-bit-lane order-preserving key transform (packed pair)
__device__ __forceinline__ unsigned int key16x2(unsigned int u) {
    const unsigned int s = (u >> 15) & 0x10001u;
    const unsigned int mask = s * 0xFFFFu;
    return (u ^ mask) | (~mask & 0x80008000u);
}
__device__ __forceinline__ float unkey16(unsigned int k) {  // 16-bit key -> float
    const unsigned int u = (k & 0x8000u) ? (k & 0x7FFFu) : (~k & 0xFFFFu);
    return __uint_as_float(u << 16);
}
__device__ __forceinline__ void async_copy16(void* lds_dst, const void* gsrc) {
    __builtin_amdgcn_global_load_lds(
        (const __attribute__((address_space(1))) unsigned int*)gsrc,
        (__attribute__((address_space(3))) unsigned int*)lds_dst,
        16, 0, 0);
}

// ==== prepw: [rows 0..BATCH-1: LN+Ahp+Dekker | BATCH: dead scan | rest: wprep] ====
__global__ __launch_bounds__(256) void prepw_kernel(
    const float* __restrict__ x, const float* __restrict__ b_pre,
    double* __restrict__ mu, double* __restrict__ stdv, double* __restrict__ sinv,
    unsigned short* __restrict__ Ahp, float* __restrict__ xch, float* __restrict__ xcl,
    const unsigned char* __restrict__ mask8, int* __restrict__ dead_idx,
    int* __restrict__ dead_cnt, const int* __restrict__ num_dead_in,
    float* __restrict__ out_last,
    const float* __restrict__ w_enc, unsigned short* __restrict__ Bhp,
    float* __restrict__ wT, const int do_w)
{
    const int b = blockIdx.x;
    const int tid = threadIdx.x;
    __shared__ double red[4];
    __shared__ double sh_mu, sh_si;
    __shared__ float tsm[32][33];

    if (b > BATCH) {
        // ---------------- wprep tile (identical math to wprep_kernel) ----------
        const int wb = b - (BATCH + 1);
        const int bk = (wb & 127) * 32;          // D_MODEL/32 = 128 (x fastest)
        const int bn = (wb >> 7) * 32;
        const int lr = tid >> 3, lc4 = (tid & 7) * 4;
        const float4 v = *(const float4*)(w_enc + (size_t)(bk + lr) * D_HIDDEN + bn + lc4);
        tsm[lr][lc4 + 0] = v.x; tsm[lr][lc4 + 1] = v.y;
        tsm[lr][lc4 + 2] = v.z; tsm[lr][lc4 + 3] = v.w;
        __syncthreads();
        float o[4];
#pragma unroll
        for (int j = 0; j < 4; ++j) o[j] = tsm[lc4 + j][lr];
        uint2 hw;
        hw.x = (unsigned)f2bf(o[0]) | ((unsigned)f2bf(o[1]) << 16);
        hw.y = (unsigned)f2bf(o[2]) | ((unsigned)f2bf(o[3]) << 16);
        *(uint2*)(Bhp + (size_t)(bn + lr) * D_MODEL + bk + lc4) = hw;
        if (do_w)
            *(float4*)(wT + (size_t)(bn + lr) * D_MODEL + bk + lc4) =
                make_float4(o[0], o[1], o[2], o[3]);
        return;
    }
    if (b == BATCH) {
        // ---------------- dead-mask scan (wave 0) ----------------
        if (tid >= 64) return;
        const int lane = tid;
        int c = 0;
        for (int j = lane; j < D_HIDDEN; j += 64) c += (mask8[j] != 0);
#pragma unroll
        for (int off = 32; off > 0; off >>= 1) c += __shfl_down(c, off, 64);
        const int total_u8 = __shfl(c, 0, 64);
        const bool u8mode = (total_u8 == NDEAD);
        const int* mask32 = (const int*)mask8;
        int cnt = 0;
        for (int base = 0; base < D_HIDDEN; base += 64) {
            const int j = base + lane;
            const bool d = u8mode ? (mask8[j] != 0) : (mask32[j] != 0);
            const unsigned long long bm = __ballot(d);
            const int pre = __popcll(bm & ((1ull << lane) - 1ull));
            if (d && (cnt + pre) < NDEAD) dead_idx[cnt + pre] = j;
            cnt += __popcll(bm);
        }
        const int cc = cnt > NDEAD ? NDEAD : cnt;
        if (lane == 0) {
            *dead_cnt = cc;
            *out_last = (float)(*num_dead_in);
        }
        for (int t = cc + lane; t < NDEAD; t += 64) dead_idx[t] = 0;
        return;
    }
    // ---------------- prep row (identical math to prep_kernel) ----------------
    const int row = b;
    const float* xr = x + (size_t)row * D_MODEL;
    float xv[16];
#pragma unroll
    for (int i = 0; i < 16; ++i) xv[i] = xr[tid + 256 * i];
    double s = 0.0;
#pragma unroll
    for (int i = 0; i < 16; ++i) s += (double)xv[i];
    const int lane = tid & 63, wid = tid >> 6;
#pragma unroll
    for (int off = 32; off > 0; off >>= 1) s += __shfl_down(s, off, 64);
    if (lane == 0) red[wid] = s;
    __syncthreads();
    if (tid == 0) sh_mu = (red[0] + red[1] + red[2] + red[3]) / (double)D_MODEL;
    __syncthreads();
    const double m = sh_mu;
    double s2 = 0.0;
#pragma unroll
    for (int i = 0; i < 16; ++i) { double d = (double)xv[i] - m; s2 += d * d; }
#pragma unroll
    for (int off = 32; off > 0; off >>= 1) s2 += __shfl_down(s2, off, 64);
    __syncthreads();
    if (lane == 0) red[wid] = s2;
    __syncthreads();
    if (tid == 0) {
        double var = (red[0] + red[1] + red[2] + red[3]) / (double)(D_MODEL - 1);
        double sd = sqrt(var);
        mu[row] = m;
        stdv[row] = sd;
        const double si = 1.0 / (sd + 1e-5);
        sinv[row] = si;
        sh_si = si;
    }
    __syncthreads();
    const double si = sh_si;
#pragma unroll
    for (int i = 0; i < 4; ++i) {
        const int j = (i * 256 + tid) * 4;
        const float4 x4 = *(const float4*)(xr + j);
        const float4 bp = *(const float4*)(b_pre + j);
        float vf[4], hi[4], lo[4];
        const float xe[4] = {x4.x, x4.y, x4.z, x4.w};
        const float be[4] = {bp.x, bp.y, bp.z, bp.w};
#pragma unroll
        for (int e = 0; e < 4; ++e) {
            const double t = ((double)xe[e] - m) * si;
            vf[e] = (float)t - be[e];
            const double a = t - (double)be[e];
            hi[e] = (float)a;
            lo[e] = (float)(a - (double)hi[e]);
        }
        uint2 hw;
        hw.x = (unsigned)f2bf(vf[0]) | ((unsigned)f2bf(vf[1]) << 16);
        hw.y = (unsigned)f2bf(vf[2]) | ((unsigned)f2bf(vf[3]) << 16);
        *(uint2*)(Ahp + (size_t)row * D_MODEL + j) = hw;
        *(float4*)(xch + (size_t)row * D_MODEL + j) = make_float4(hi[0], hi[1], hi[2], hi[3]);
        *(float4*)(xcl + (size_t)row * D_MODEL + j) = make_float4(lo[0], lo[1], lo[2], lo[3]);
    }
}

// -------------------- bsplit (fallback) --------------------
__global__ __launch_bounds__(256) void bsplit_kernel(
    const float* __restrict__ w_enc, unsigned short* __restrict__ Bhp)
{
    __shared__ float t[32][33];
    const int bk = blockIdx.x * 32;
    const int bn = blockIdx.y * 32;
    const int tid = threadIdx.x;
    const int lr = tid >> 3, lc4 = (tid & 7) * 4;
    const float4 v = *(const float4*)(w_enc + (size_t)(bk + lr) * D_HIDDEN + bn + lc4);
    t[lr][lc4 + 0] = v.x; t[lr][lc4 + 1] = v.y; t[lr][lc4 + 2] = v.z; t[lr][lc4 + 3] = v.w;
    __syncthreads();
    float o[4];
#pragma unroll
    for (int j = 0; j < 4; ++j) o[j] = t[lc4 + j][lr];
    uint2 hw;
    hw.x = (unsigned)f2bf(o[0]) | ((unsigned)f2bf(o[1]) << 16);
    hw.y = (unsigned)f2bf(o[2]) | ((unsigned)f2bf(o[3]) << 16);
    *(uint2*)(Bhp + (size_t)(bn + lr) * D_MODEL + bk + lc4) = hw;
}

// -------------------- wencT (fallback) --------------------
__global__ __launch_bounds__(256) void wencT_kernel(
    const float* __restrict__ w_enc, float* __restrict__ wT)
{
    __shared__ float t[32][33];
    const int bk = blockIdx.x * 32;
    const int bn = blockIdx.y * 32;
    const int tid = threadIdx.x;
    const int lr = tid >> 3, lc4 = (tid & 7) * 4;
    const float4 v = *(const float4*)(w_enc + (size_t)(bk + lr) * D_HIDDEN + bn + lc4);
    t[lr][lc4 + 0] = v.x; t[lr][lc4 + 1] = v.y; t[lr][lc4 + 2] = v.z; t[lr][lc4 + 3] = v.w;
    __syncthreads();
    const int j = tid >> 3, i4 = (tid & 7) * 4;
    float4 o;
    o.x = t[i4 + 0][j]; o.y = t[i4 + 1][j]; o.z = t[i4 + 2][j]; o.w = t[i4 + 3][j];
    *(float4*)(wT + (size_t)(bn + j) * D_MODEL + bk + i4) = o;
}

// ======== 256x256 bf16 MFMA GEMM, BK=64, 8 waves, 4-phase/K-tile, half-tile pipe ====
template<int EPI>
__global__ __launch_bounds__(512) void mm256_kernel(
    const unsigned short* __restrict__ A, const unsigned short* __restrict__ B,
    const int kdim, const int ntiles_x,
    const float* __restrict__ bias_n,
    const double* __restrict__ muv, const double* __restrict__ stdvv,
    void* __restrict__ outp, const long ostride)
{
    __shared__ unsigned short lds[2 * 4 * 8192];   // 128 KB: 2 bufs x 4 subplanes
    const int tid = threadIdx.x;
    const int lane = tid & 63, wid = tid >> 6;     // 8 waves
    const int cpx = gridDim.x >> 3;                // XCD swizzle (grid % 8 == 0)
    const int orig = blockIdx.x;
    const int wg = (orig & 7) * cpx + (orig >> 3);
    const int m0 = (wg % ntiles_x) * 256;
    const int n0 = (wg / ntiles_x) * 256;
    const int wm = (wid >> 2) * 128;               // 2 M-halves
    const int wn = (wid & 3) * 64;                 // 4 N-quarters
    const int fr = lane & 15, kq = lane >> 4;
    const int swr = (fr >> 1) & 3;                 // read-side quad XOR
    const int qg = (lane & 3) ^ ((lane >> 3) & 3); // write-side source quad
    const int qo = (kq ^ swr) * 8;

    f32x4 acc[8][4];
#pragma unroll
    for (int i = 0; i < 8; ++i)
#pragma unroll
        for (int j = 0; j < 4; ++j) acc[i][j] = (f32x4){0.f, 0.f, 0.f, 0.f};

    const unsigned short* sH0[4];
    int dH0[4];
#pragma unroll
    for (int j = 0; j < 4; ++j) {
        const int g = wid * 4 + j;
        const int is_b = g >> 4;
        const int sr = g & 15;
        const unsigned short* gp = is_b ? B : A;
        const int t0 = is_b ? n0 : m0;
        sH0[j] = gp + (size_t)(t0 + sr * 16 + (lane >> 2)) * kdim + qg * 8;
        dH0[j] = (is_b ? 2 : 0) * 8192 + sr * 512;
    }

    const int NT = kdim >> 6;
#pragma unroll
    for (int j = 0; j < 4; ++j) async_copy16(lds + dH0[j], sH0[j]);
#pragma unroll
    for (int j = 0; j < 4; ++j) async_copy16(lds + 8192 + dH0[j], sH0[j] + 32);
    if (NT > 1) {
#pragma unroll
        for (int j = 0; j < 4; ++j) async_copy16(lds + 32768 + dH0[j], sH0[j] + 64);
    }

    for (int t = 0; t < NT; ++t) {
        const int cur = t & 1;
        unsigned short* bb = (unsigned short*)lds + cur * 32768;
        unsigned short* nb = (unsigned short*)lds + (cur ^ 1) * 32768;
        const int k1 = (t + 1) << 6;
        const int k2 = (t + 2) << 6;

        if (t < NT - 1) { asm volatile("s_waitcnt vmcnt(8)" ::: "memory"); }
        else            { asm volatile("s_waitcnt vmcnt(4)" ::: "memory"); }
        asm volatile("s_barrier" ::: "memory");
        __builtin_amdgcn_sched_barrier(0);
        {
            if (t + 1 < NT) {
                async_copy16(nb + 8192 + dH0[0], sH0[0] + k1 + 32);
                async_copy16(nb + 8192 + dH0[1], sH0[1] + k1 + 32);
            }
            s16x8 a[4], b[4];
#pragma unroll
            for (int mi = 0; mi < 4; ++mi)
                a[mi] = *(const s16x8*)(bb + (wm + mi * 16 + fr) * 32 + qo);
#pragma unroll
            for (int ni = 0; ni < 4; ++ni)
                b[ni] = *(const s16x8*)(bb + 2 * 8192 + (wn + ni * 16 + fr) * 32 + qo);
            __builtin_amdgcn_s_setprio(1);
#pragma unroll
            for (int mi = 0; mi < 4; ++mi)
#pragma unroll
                for (int ni = 0; ni < 4; ++ni)
                    acc[mi][ni] = __builtin_amdgcn_mfma_f32_16x16x32_bf16(a[mi], b[ni], acc[mi][ni], 0, 0, 0);
            __builtin_amdgcn_s_setprio(0);
            asm volatile("s_barrier" ::: "memory");
            __builtin_amdgcn_sched_barrier(0);
            if (t + 1 < NT) {
                async_copy16(nb + 8192 + dH0[2], sH0[2] + k1 + 32);
                async_copy16(nb + 8192 + dH0[3], sH0[3] + k1 + 32);
            }
            s16x8 a2[4];
#pragma unroll
            for (int mi = 0; mi < 4; ++mi)
                a2[mi] = *(const s16x8*)(bb + (wm + (mi + 4) * 16 + fr) * 32 + qo);
            __builtin_amdgcn_s_setprio(1);
#pragma unroll
            for (int mi = 0; mi < 4; ++mi)
#pragma unroll
                for (int ni = 0; ni < 4; ++ni)
                    acc[mi + 4][ni] = __builtin_amdgcn_mfma_f32_16x16x32_bf16(a2[mi], b[ni], acc[mi + 4][ni], 0, 0, 0);
            __builtin_amdgcn_s_setprio(0);
        }
        if (t < NT - 1) { asm volatile("s_waitcnt vmcnt(8)" ::: "memory"); }
        else            { asm volatile("s_waitcnt vmcnt(0)" ::: "memory"); }
        asm volatile("s_barrier" ::: "memory");
        __builtin_amdgcn_sched_barrier(0);
        {
            if (t + 2 < NT) {
                async_copy16(bb + dH0[0], sH0[0] + k2);
                async_copy16(bb + dH0[1], sH0[1] + k2);
            }
            s16x8 a[4], b[4];
#pragma unroll
            for (int mi = 0; mi < 4; ++mi)
                a[mi] = *(const s16x8*)(bb + 8192 + (wm + mi * 16 + fr) * 32 + qo);
#pragma unroll
            for (int ni = 0; ni < 4; ++ni)
                b[ni] = *(const s16x8*)(bb + 3 * 8192 + (wn + ni * 16 + fr) * 32 + qo);
            __builtin_amdgcn_s_setprio(1);
#pragma unroll
            for (int mi = 0; mi < 4; ++mi)
#pragma unroll
                for (int ni = 0; ni < 4; ++ni)
                    acc[mi][ni] = __builtin_amdgcn_mfma_f32_16x16x32_bf16(a[mi], b[ni], acc[mi][ni], 0, 0, 0);
            __builtin_amdgcn_s_setprio(0);
            asm volatile("s_barrier" ::: "memory");
            __builtin_amdgcn_sched_barrier(0);
            if (t + 2 < NT) {
                async_copy16(bb + dH0[2], sH0[2] + k2);
                async_copy16(bb + dH0[3], sH0[3] + k2);
            }
            s16x8 a2[4];
#pragma unroll
            for (int mi = 0; mi < 4; ++mi)
                a2[mi] = *(const s16x8*)(bb + 8192 + (wm + (mi + 4) * 16 + fr) * 32 + qo);
            __builtin_amdgcn_s_setprio(1);
#pragma unroll
            for (int mi = 0; mi < 4; ++mi)
#pragma unroll
                for (int ni = 0; ni < 4; ++ni)
                    acc[mi + 4][ni] = __builtin_amdgcn_mfma_f32_16x16x32_bf16(a2[mi], b[ni], acc[mi + 4][ni], 0, 0, 0);
            __builtin_amdgcn_s_setprio(0);
        }
    }

#pragma unroll
    for (int ni = 0; ni < 4; ++ni) {
        const int col = n0 + wn + ni * 16 + fr;
        const float be = bias_n[col];
#pragma unroll
        for (int mi = 0; mi < 8; ++mi) {
            const int rb = m0 + wm + mi * 16 + kq * 4;
            if (EPI == 0) {
                unsigned short* O = (unsigned short*)outp;
#pragma unroll
                for (int r = 0; r < 4; ++r)
                    O[(size_t)(rb + r) * ostride + col] = f2bf(acc[mi][ni][r] + be);
            } else {
                float* O = (float*)outp;
#pragma unroll
                for (int r = 0; r < 4; ++r) {
                    const int m = rb + r;
                    O[(size_t)m * ostride + col] =
                        (acc[mi][ni][r] + be) * (float)stdvv[m] + (float)muv[m];
                }
            }
        }
    }
}

// ======= comboA: [sel | auxg | auxb(nb_ab) | wdec2bf(nb_wd)] in one launch =======
__global__ __launch_bounds__(256) void comboA_kernel(
    const unsigned short* __restrict__ p16,
    int* __restrict__ topk_idx, float* __restrict__ topk_val,
    int* __restrict__ sure_cnt, int* __restrict__ tie_cnt, int* __restrict__ cand_col,
    const int* __restrict__ dead_idx, const int* __restrict__ dead_cnt,
    unsigned short* __restrict__ Ahd,
    const float* __restrict__ w_dec, unsigned short* __restrict__ Bhd,
    unsigned short* __restrict__ wd16,
    const int nb_ab, const int nb_wd)
{
    const int b = blockIdx.x;
    const int tid = threadIdx.x;
    __shared__ float tsm[32][33];
    __shared__ int red[4];
    __shared__ int sh_sel, sh_tie;

    if (b < NB_SEL) {
        const int row = b;
        const int lane = tid & 63, wid = tid >> 6;
        const unsigned short* pr = p16 + (size_t)row * D_HIDDEN;
        uint4 kr[16];
#pragma unroll
        for (int i = 0; i < 16; ++i) {
            uint4 w = *(const uint4*)(pr + (i * 256 + tid) * 8);
            w.x = key16x2(w.x); w.y = key16x2(w.y); w.z = key16x2(w.z); w.w = key16x2(w.w);
            kr[i] = w;
        }
        if (tid == 0) { sh_sel = 0; sh_tie = 0; }
        unsigned int lo = 0, hi = 65535;
        while (lo < hi) {
            const unsigned int mid = (lo + hi) >> 1;
            int c = 0;
#pragma unroll
            for (int i = 0; i < 16; ++i) {
                const unsigned int u[4] = {kr[i].x, kr[i].y, kr[i].z, kr[i].w};
#pragma unroll
                for (int e = 0; e < 4; ++e) {
                    c += (int)((u[e] & 0xFFFFu) > mid);
                    c += (int)((u[e] >> 16) > mid);
                }
            }
#pragma unroll
            for (int off = 32; off > 0; off >>= 1) c += __shfl_down(c, off, 64);
            if (lane == 0) red[wid] = c;
            __syncthreads();
            const int total = red[0] + red[1] + red[2] + red[3];
            if (total < KSEL) hi = mid; else lo = mid + 1;
            __syncthreads();
        }
        const unsigned int K16 = lo;
        const float vc = unkey16(K16);
        const float DLT = 1.3e-2f;
        const float sureT = vc + 2.f * DLT;
        const float candT = vc - 2.f * DLT;
        const unsigned int sK = fkey(sureT) >> 16;
        const unsigned int cK = fkey(candT) >> 16;
        int* oidx = topk_idx + row * KSEL;
        float* oval = topk_val + row * KSEL;
        int* cc = cand_col + row * TIECAP;
#pragma unroll
        for (int i = 0; i < 16; ++i) {
            const int j0 = (i * 256 + tid) * 8;
            const unsigned int u[4] = {kr[i].x, kr[i].y, kr[i].z, kr[i].w};
#pragma unroll
            for (int e = 0; e < 8; ++e) {
                const unsigned int k = (e & 1) ? (u[e >> 1] >> 16) : (u[e >> 1] & 0xFFFFu);
                if (k < cK) continue;
                const float v = unkey16(k);
                if (k > sK && v > sureT) {
                    const int pos = atomicAdd(&sh_sel, 1);
                    oidx[pos] = j0 + e;
                    oval[pos] = v > 0.f ? v : 0.f;
                } else if (v >= candT) {
                    const int t = atomicAdd(&sh_tie, 1);
                    if (t < TIECAP) cc[t] = j0 + e;
                }
            }
        }
        __syncthreads();
        if (tid == 0) {
            sure_cnt[row] = sh_sel;
            tie_cnt[row] = sh_tie > TIECAP ? TIECAP : sh_tie;
        }
        return;
    }
    if (b < NB_SEL + NB_AG) {
        const int r = b - NB_SEL;
        const int dc = *dead_cnt;
#pragma unroll
        for (int i = 0; i < 8; ++i) {
            const int c = i * 256 + tid;
            unsigned short v = 0;
            if (c < dc) {
                const unsigned short u = p16[(size_t)r * D_HIDDEN + dead_idx[c]];
                v = (u & 0x8000u) ? (unsigned short)0 : u;
            }
            Ahd[(size_t)r * NDEAD + c] = v;
        }
        return;
    }
    if (b < NB_SEL + NB_AG + nb_ab) {
        const int idx = b - (NB_SEL + NB_AG);
        const int k0 = (idx & 63) * 32;
        const int n0 = (idx >> 6) * 32;
        const int i = tid >> 3, j4 = (tid & 7) * 4;
        const int srow = dead_idx[k0 + i];
        const float4 v = *(const float4*)(w_dec + (size_t)srow * D_MODEL + n0 + j4);
        tsm[i][j4 + 0] = v.x; tsm[i][j4 + 1] = v.y; tsm[i][j4 + 2] = v.z; tsm[i][j4 + 3] = v.w;
        __syncthreads();
        const int j = tid >> 3, i4 = (tid & 7) * 4;
        uint2 hw;
        hw.x = (unsigned)f2bf(tsm[i4 + 0][j]) | ((unsigned)f2bf(tsm[i4 + 1][j]) << 16);
        hw.y = (unsigned)f2bf(tsm[i4 + 2][j]) | ((unsigned)f2bf(tsm[i4 + 3][j]) << 16);
        *(uint2*)(Bhd + (size_t)(n0 + j) * NDEAD + k0 + i4) = hw;
        return;
    }
    {
        const int bb = b - (NB_SEL + NB_AG + nb_ab);
        (void)nb_wd;
        const size_t base0 = (size_t)bb * 16384;
#pragma unroll
        for (int it = 0; it < 8; ++it) {
            const size_t off = base0 + (size_t)it * 2048 + (size_t)tid * 8;
            const float4 a = *(const float4*)(w_dec + off);
            const float4 c = *(const float4*)(w_dec + off + 4);
            uint4 o;
            o.x = (unsigned)f2bf(a.x) | ((unsigned)f2bf(a.y) << 16);
            o.y = (unsigned)f2bf(a.z) | ((unsigned)f2bf(a.w) << 16);
            o.z = (unsigned)f2bf(c.x) | ((unsigned)f2bf(c.y) << 16);
            o.w = (unsigned)f2bf(c.z) | ((unsigned)f2bf(c.w) << 16);
            *(uint4*)(wd16 + off) = o;
        }
        return;
    }
}

// ---------- standalone auxb + wdec2bf (fallback ordering) ----------
__global__ __launch_bounds__(256) void auxb_kernel(
    const float* __restrict__ w_dec, const int* __restrict__ dead_idx,
    unsigned short* __restrict__ Bhd)
{
    __shared__ float t[32][33];
    const int k0 = blockIdx.x * 32;
    const int n0 = blockIdx.y * 32;
    const int tid = threadIdx.x;
    const int i = tid >> 3, j4 = (tid & 7) * 4;
    const int srow = dead_idx[k0 + i];
    const float4 v = *(const float4*)(w_dec + (size_t)srow * D_MODEL + n0 + j4);
    t[i][j4 + 0] = v.x; t[i][j4 + 1] = v.y; t[i][j4 + 2] = v.z; t[i][j4 + 3] = v.w;
    __syncthreads();
    const int j = tid >> 3, i4 = (tid & 7) * 4;
    uint2 hw;
    hw.x = (unsigned)f2bf(t[i4 + 0][j]) | ((unsigned)f2bf(t[i4 + 1][j]) << 16);
    hw.y = (unsigned)f2bf(t[i4 + 2][j]) | ((unsigned)f2bf(t[i4 + 3][j]) << 16);
    *(uint2*)(Bhd + (size_t)(n0 + j) * NDEAD + k0 + i4) = hw;
}

__global__ __launch_bounds__(256) void wdec2bf_kernel(
    const float* __restrict__ w_dec, unsigned short* __restrict__ wd16)
{
    const size_t gid = (size_t)blockIdx.x * 256 + threadIdx.x;
    const size_t base = gid * 8;
    const float4 a = *(const float4*)(w_dec + base);
    const float4 b = *(const float4*)(w_dec + base + 4);
    uint4 o;
    o.x = (unsigned)f2bf(a.x) | ((unsigned)f2bf(a.y) << 16);
    o.y = (unsigned)f2bf(a.z) | ((unsigned)f2bf(a.w) << 16);
    o.z = (unsigned)f2bf(b.x) | ((unsigned)f2bf(b.y) << 16);
    o.w = (unsigned)f2bf(b.z) | ((unsigned)f2bf(b.w) << 16);
    *(uint4*)(wd16 + base) = o;
}

// ======= comboB: [aux mm256 (nb_mm blocks) | row-refine (BATCH blocks)] =========
// refine: one block per row, xch/xcl staged in LDS once, waves stream wT rows.
// Inner k-mapping and s0/s1 accumulation identical to the old refine -> bitwise
// identical cand_val.
__global__ __launch_bounds__(512) void comboB_kernel(
    // aux mm256 args
    const unsigned short* __restrict__ A, const unsigned short* __restrict__ B,
    const float* __restrict__ bias_n,
    const double* __restrict__ muv, const double* __restrict__ stdvv,
    float* __restrict__ out1,
    // refine args
    const int* __restrict__ tie_cnt, const int* __restrict__ cand_col,
    double* __restrict__ cand_val,
    const float* __restrict__ xch, const float* __restrict__ xcl,
    const float* __restrict__ wT, const float* __restrict__ b_enc,
    const int nb_mm)
{
    __shared__ unsigned short lds[2 * 4 * 8192];   // 128 KB (refine uses first 32 KB)
    const int tid = threadIdx.x;
    const int lane = tid & 63, wid = tid >> 6;

    if (blockIdx.x >= nb_mm) {
        // ---------------- row refine ----------------
        const int row = blockIdx.x - nb_mm;
        const int T = tie_cnt[row];
        if (T == 0) return;
        float* shh = (float*)lds;
        float* shl = shh + D_MODEL;
        const float* hr = xch + (size_t)row * D_MODEL;
        const float* lr2 = xcl + (size_t)row * D_MODEL;
        {
            const int o = tid * 8;
            *(float4*)(shh + o)     = *(const float4*)(hr + o);
            *(float4*)(shh + o + 4) = *(const float4*)(hr + o + 4);
            *(float4*)(shl + o)     = *(const float4*)(lr2 + o);
            *(float4*)(shl + o + 4) = *(const float4*)(lr2 + o + 4);
        }
        __syncthreads();
        for (int slot = wid; slot < T; slot += 8) {
            const int col = cand_col[row * TIECAP + slot];
            const float* wr = wT + (size_t)col * D_MODEL;
            double s0 = 0.0, s1 = 0.0;
            for (int k = lane * 4; k < D_MODEL; k += 512) {
                {
                    const float4 h = *(const float4*)(shh + k);
                    const float4 l = *(const float4*)(shl + k);
                    const float4 w4 = *(const float4*)(wr + k);
                    s0 += ((double)h.x + (double)l.x) * (double)w4.x;
                    s0 += ((double)h.y + (double)l.y) * (double)w4.y;
                    s0 += ((double)h.z + (double)l.z) * (double)w4.z;
                    s0 += ((double)h.w + (double)l.w) * (double)w4.w;
                }
                {
                    const int k2 = k + 256;
                    const float4 h = *(const float4*)(shh + k2);
                    const float4 l = *(const float4*)(shl + k2);
                    const float4 w4 = *(const float4*)(wr + k2);
                    s1 += ((double)h.x + (double)l.x) * (double)w4.x;
                    s1 += ((double)h.y + (double)l.y) * (double)w4.y;
                    s1 += ((double)h.z + (double)l.z) * (double)w4.z;
                    s1 += ((double)h.w + (double)l.w) * (double)w4.w;
                }
            }
            double s = s0 + s1;
#pragma unroll
            for (int off = 32; off > 0; off >>= 1) s += __shfl_down(s, off, 64);
            if (lane == 0) cand_val[row * TIECAP + slot] = s + (double)b_enc[col];
        }
        return;
    }

    // ---------------- aux mm256 (EPI=1), K = NDEAD, swizzle domain nb_mm ----------
    const int kdim = NDEAD;
    const int ntiles_x = BATCH / 256;
    const int cpx = nb_mm >> 3;
    const int orig = blockIdx.x;
    const int wg = (orig & 7) * cpx + (orig >> 3);
    const int m0 = (wg % ntiles_x) * 256;
    const int n0 = (wg / ntiles_x) * 256;
    const int wm = (wid >> 2) * 128;
    const int wn = (wid & 3) * 64;
    const int fr = lane & 15, kq = lane >> 4;
    const int swr = (fr >> 1) & 3;
    const int qg = (lane & 3) ^ ((lane >> 3) & 3);
    const int qo = (kq ^ swr) * 8;

    f32x4 acc[8][4];
#pragma unroll
    for (int i = 0; i < 8; ++i)
#pragma unroll
        for (int j = 0; j < 4; ++j) acc[i][j] = (f32x4){0.f, 0.f, 0.f, 0.f};

    const unsigned short* sH0[4];
    int dH0[4];
#pragma unroll
    for (int j = 0; j < 4; ++j) {
        const int g = wid * 4 + j;
        const int is_b = g >> 4;
        const int sr = g & 15;
        const unsigned short* gp = is_b ? B : A;
        const int t0 = is_b ? n0 : m0;
        sH0[j] = gp + (size_t)(t0 + sr * 16 + (lane >> 2)) * kdim + qg * 8;
        dH0[j] = (is_b ? 2 : 0) * 8192 + sr * 512;
    }

    const int NT = kdim >> 6;
#pragma unroll
    for (int j = 0; j < 4; ++j) async_copy16(lds + dH0[j], sH0[j]);
#pragma unroll
    for (int j = 0; j < 4; ++j) async_copy16(lds + 8192 + dH0[j], sH0[j] + 32);
    if (NT > 1) {
#pragma unroll
        for (int j = 0; j < 4; ++j) async_copy16(lds + 32768 + dH0[j], sH0[j] + 64);
    }

    for (int t = 0; t < NT; ++t) {
        const int cur = t & 1;
        unsigned short* bb = (unsigned short*)lds + cur * 32768;
        unsigned short* nb = (unsigned short*)lds + (cur ^ 1) * 32768;
        const int k1 = (t + 1) << 6;
        const int k2 = (t + 2) << 6;

        if (t < NT - 1) { asm volatile("s_waitcnt vmcnt(8)" ::: "memory"); }
        else            { asm volatile("s_waitcnt vmcnt(4)" ::: "memory"); }
        asm volatile("s_barrier" ::: "memory");
        __builtin_amdgcn_sched_barrier(0);
        {
            if (t + 1 < NT) {
                async_copy16(nb + 8192 + dH0[0], sH0[0] + k1 + 32);
                async_copy16(nb + 8192 + dH0[1], sH0[1] + k1 + 32);
            }
            s16x8 a[4], b[4];
#pragma unroll
            for (int mi = 0; mi < 4; ++mi)
                a[mi] = *(const s16x8*)(bb + (wm + mi * 16 + fr) * 32 + qo);
#pragma unroll
            for (int ni = 0; ni < 4; ++ni)
                b[ni] = *(const s16x8*)(bb + 2 * 8192 + (wn + ni * 16 + fr) * 32 + qo);
            __builtin_amdgcn_s_setprio(1);
#pragma unroll
            for (int mi = 0; mi < 4; ++mi)
#pragma unroll
                for (int ni = 0; ni < 4; ++ni)
                    acc[mi][ni] = __builtin_amdgcn_mfma_f32_16x16x32_bf16(a[mi], b[ni], acc[mi][ni], 0, 0, 0);
            __builtin_amdgcn_s_setprio(0);
            asm volatile("s_barrier" ::: "memory");
            __builtin_amdgcn_sched_barrier(0);
            if (t + 1 < NT) {
                async_copy16(nb + 8192 + dH0[2], sH0[2] + k1 + 32);
                async_copy16(nb + 8192 + dH0[3], sH0[3] + k1 + 32);
            }
            s16x8 a2[4];
#pragma unroll
            for (int mi = 0; mi < 4; ++mi)
                a2[mi] = *(const s16x8*)(bb + (wm + (mi + 4) * 16 + fr) * 32 + qo);
            __builtin_amdgcn_s_setprio(1);
#pragma unroll
            for (int mi = 0; mi < 4; ++mi)
#pragma unroll
                for (int ni = 0; ni < 4; ++ni)
                    acc[mi + 4][ni] = __builtin_amdgcn_mfma_f32_16x16x32_bf16(a2[mi], b[ni], acc[mi + 4][ni], 0, 0, 0);
            __builtin_amdgcn_s_setprio(0);
        }
        if (t < NT - 1) { asm volatile("s_waitcnt vmcnt(8)" ::: "memory"); }
        else            { asm volatile("s_waitcnt vmcnt(0)" ::: "memory"); }
        asm volatile("s_barrier" ::: "memory");
        __builtin_amdgcn_sched_barrier(0);
        {
            if (t + 2 < NT) {
                async_copy16(bb + dH0[0], sH0[0] + k2);
                async_copy16(bb + dH0[1], sH0[1] + k2);
            }
            s16x8 a[4], b[4];
#pragma unroll
            for (int mi = 0; mi < 4; ++mi)
                a[mi] = *(const s16x8*)(bb + 8192 + (wm + mi * 16 + fr) * 32 + qo);
#pragma unroll
            for (int ni = 0; ni < 4; ++ni)
                b[ni] = *(const s16x8*)(bb + 3 * 8192 + (wn + ni * 16 + fr) * 32 + qo);
            __builtin_amdgcn_s_setprio(1);
#pragma unroll
            for (int mi = 0; mi < 4; ++mi)
#pragma unroll
                for (int ni = 0; ni < 4; ++ni)
                    acc[mi][ni] = __builtin_amdgcn_mfma_f32_16x16x32_bf16(a[mi], b[ni], acc[mi][ni], 0, 0, 0);
            __builtin_amdgcn_s_setprio(0);
            asm volatile("s_barrier" ::: "memory");
            __builtin_amdgcn_sched_barrier(0);
            if (t + 2 < NT) {
                async_copy16(bb + dH0[2], sH0[2] + k2);
                async_copy16(bb + dH0[3], sH0[3] + k2);
            }
            s16x8 a2[4];
#pragma unroll
            for (int mi = 0; mi < 4; ++mi)
                a2[mi] = *(const s16x8*)(bb + 8192 + (wm + (mi + 4) * 16 + fr) * 32 + qo);
            __builtin_amdgcn_s_setprio(1);
#pragma unroll
            for (int mi = 0; mi < 4; ++mi)
#pragma unroll
                for (int ni = 0; ni < 4; ++ni)
                    acc[mi + 4][ni] = __builtin_amdgcn_mfma_f32_16x16x32_bf16(a2[mi], b[ni], acc[mi + 4][ni], 0, 0, 0);
            __builtin_amdgcn_s_setprio(0);
        }
    }

#pragma unroll
    for (int ni = 0; ni < 4; ++ni) {
        const int col = n0 + wn + ni * 16 + fr;
        const float be = bias_n[col];
#pragma unroll
        for (int mi = 0; mi < 8; ++mi) {
            const int rb = m0 + wm + mi * 16 + kq * 4;
#pragma unroll
            for (int r = 0; r < 4; ++r) {
                const int m = rb + r;
                out1[(size_t)m * D_MODEL + col] =
                    (acc[mi][ni][r] + be) * (float)stdvv[m] + (float)muv[m];
            }
        }
    }
}

// ---------- decode_fin: per-row candidate rank (fin) fused with sparse decode ----
__global__ __launch_bounds__(256) void decode_fin_kernel(
    const int* __restrict__ sure_cnt, const int* __restrict__ tie_cnt,
    const int* __restrict__ cand_col, const double* __restrict__ cand_val,
    const int* __restrict__ topk_idx, const float* __restrict__ topk_val,
    const unsigned short* __restrict__ wd16, const float* __restrict__ b_pre,
    const double* __restrict__ mu, const double* __restrict__ stdv,
    float* __restrict__ out0)
{
    const int row = blockIdx.x;
    const int tid = threadIdx.x;
    __shared__ double vals[TIECAP];
    __shared__ int cols[TIECAP];
    __shared__ int sidx[KSEL];
    __shared__ float sval[KSEL];
    const int G = sure_cnt[row];
    const int T = tie_cnt[row];
    const int R = KSEL - G;
    if (tid < T) {
        vals[tid] = cand_val[row * TIECAP + tid];
        cols[tid] = cand_col[row * TIECAP + tid];
    }
    if (tid < G) {
        sidx[tid] = topk_idx[row * KSEL + tid];
        sval[tid] = topk_val[row * KSEL + tid];
    }
    __syncthreads();
    if (tid < T) {
        const double v = vals[tid];
        const int c = cols[tid];
        int rank = 0;
        for (int u = 0; u < T; ++u) {
            const double vu = vals[u];
            rank += (int)((vu > v) || (vu == v && cols[u] < c));
        }
        if (rank < R) {
            sidx[G + rank] = c;
            sval[G + rank] = v > 0.0 ? (float)v : 0.f;
        }
    }
    const int take = R < T ? R : T;
    if (tid >= take && tid < R) {
        sidx[G + tid] = (T > 0) ? cols[0] : 0;
        sval[G + tid] = 0.f;
    }
    __syncthreads();
    float acc[16];
#pragma unroll
    for (int i = 0; i < 16; ++i) acc[i] = 0.f;
    const int dbase = tid * 16;
    for (int k = 0; k < KSEL; ++k) {
        const float v = sval[k];
        if (v == 0.f) continue;
        const uint4* wr = (const uint4*)(wd16 + (size_t)sidx[k] * D_MODEL + dbase);
        const uint4 w0 = wr[0], w1 = wr[1];
        const unsigned int u[8] = {w0.x, w0.y, w0.z, w0.w, w1.x, w1.y, w1.z, w1.w};
#pragma unroll
        for (int i = 0; i < 8; ++i) {
            acc[2 * i]     += v * __uint_as_float(u[i] << 16);
            acc[2 * i + 1] += v * __uint_as_float(u[i] & 0xFFFF0000u);
        }
    }
    const float st = (float)stdv[row];
    const float mm = (float)mu[row];
    float* o = out0 + (size_t)row * D_MODEL + dbase;
#pragma unroll
    for (int i = 0; i < 16; ++i) {
        o[i] = (acc[i] + b_pre[dbase + i]) * st + mm;
    }
}

// -------------------- launch --------------------
extern "C" void kernel_launch(void* const* d_in, const int* in_sizes, int n_in,
                              void* d_out, int out_size, void* d_ws, size_t ws_size,
                              hipStream_t stream)
{
    (void)in_sizes; (void)n_in; (void)out_size;
    const float* x      = (const float*)d_in[0];
    const float* w_enc  = (const float*)d_in[1];
    const float* w_dec  = (const float*)d_in[2];
    const float* b_enc  = (const float*)d_in[3];
    const float* b_pre  = (const float*)d_in[4];
    const unsigned char* dead_mask = (const unsigned char*)d_in[5];
    const int* num_dead = (const int*)d_in[6];
    float* out = (float*)d_out;

    char* base = (char*)d_ws;
    char* w = base;
    auto alloc = [&](size_t bytes) -> char* {
        char* p = w;
        w += (bytes + 255) & ~(size_t)255;
        return p;
    };
    unsigned short* p16 = (unsigned short*)alloc((size_t)BATCH * D_HIDDEN * 2); // 128 MB
    double* mu       = (double*)alloc((size_t)BATCH * 8);
    double* stdv     = (double*)alloc((size_t)BATCH * 8);
    double* sinv     = (double*)alloc((size_t)BATCH * 8);
    int* topk_idx    = (int*)alloc((size_t)BATCH * KSEL * 4);
    float* topk_val  = (float*)alloc((size_t)BATCH * KSEL * 4);
    int* dead_idx    = (int*)alloc((size_t)NDEAD * 4);
    int* dead_cnt    = (int*)alloc(256);
    int* sure_cnt    = (int*)alloc((size_t)BATCH * 4);
    int* tie_cnt     = (int*)alloc((size_t)BATCH * 4);
    int* cand_col    = (int*)alloc((size_t)BATCH * TIECAP * 4);      // 2 MB
    double* cand_val = (double*)alloc((size_t)BATCH * TIECAP * 8);   // 4 MB
    float* xch       = (float*)alloc((size_t)BATCH * D_MODEL * 4);   // 32 MB
    float* xcl       = (float*)alloc((size_t)BATCH * D_MODEL * 4);   // 32 MB
    unsigned short* Ahp = (unsigned short*)alloc((size_t)BATCH * D_MODEL * 2);    // 16 MB
    char* region     = alloc((size_t)D_HIDDEN * D_MODEL * 4);                     // 512 MB
    float* wT_big    = (float*)alloc((size_t)D_HIDDEN * D_MODEL * 4);             // 512 MB
    const size_t need_big = (size_t)(w - base);
    const bool bigws = (ws_size >= need_big);

    // time-multiplexed region:
    unsigned short* Bhp = (unsigned short*)region;                 // 256 MB, enc phase
    float* wT_small = (float*)region;                              // 512 MB (fallback, after enc)
    unsigned short* wd16 = (unsigned short*)region;                // 256 MB, decode phase
    unsigned short* Bhd  = (unsigned short*)(region + (size_t)D_HIDDEN * D_MODEL * 2); // 16 MB
    unsigned short* Ahd  = Ahp;                                    // 8 MB (Ahp dead after enc)
    float* wT = bigws ? wT_big : wT_small;

    float* out0 = out;                                   // recons
    float* out1 = out + (size_t)BATCH * D_MODEL;         // auxk
    float* out_last = out + (size_t)2 * BATCH * D_MODEL; // num_dead

    if (bigws) {
        prepw_kernel<<<BATCH + 1 + NB_WPREP, 256, 0, stream>>>(
            x, b_pre, mu, stdv, sinv, Ahp, xch, xcl,
            dead_mask, dead_idx, dead_cnt, num_dead, out_last,
            w_enc, Bhp, wT, 1);
        mm256_kernel<0><<<(BATCH / 256) * (D_HIDDEN / 256), 512, 0, stream>>>(
            Ahp, Bhp, D_MODEL, BATCH / 256, b_enc, nullptr, nullptr, p16, (long)D_HIDDEN);
        comboA_kernel<<<NB_SEL + NB_AG + NB_AB + NB_WD, 256, 0, stream>>>(
            p16, topk_idx, topk_val, sure_cnt, tie_cnt, cand_col,
            dead_idx, dead_cnt, Ahd, w_dec, Bhd, wd16, NB_AB, NB_WD);
        comboB_kernel<<<NB_MM + BATCH, 512, 0, stream>>>(
            Ahd, Bhd, b_pre, mu, stdv, out1,
            tie_cnt, cand_col, cand_val, xch, xcl, wT, b_enc, NB_MM);
    } else {
        prepw_kernel<<<BATCH + 1, 256, 0, stream>>>(
            x, b_pre, mu, stdv, sinv, Ahp, xch, xcl,
            dead_mask, dead_idx, dead_cnt, num_dead, out_last,
            w_enc, Bhp, nullptr, 0);
        bsplit_kernel<<<dim3(D_MODEL / 32, D_HIDDEN / 32), 256, 0, stream>>>(w_enc, Bhp);
        mm256_kernel<0><<<(BATCH / 256) * (D_HIDDEN / 256), 512, 0, stream>>>(
            Ahp, Bhp, D_MODEL, BATCH / 256, b_enc, nullptr, nullptr, p16, (long)D_HIDDEN);
        wencT_kernel<<<dim3(D_MODEL / 32, D_HIDDEN / 32), 256, 0, stream>>>(w_enc, wT);
        comboA_kernel<<<NB_SEL + NB_AG, 256, 0, stream>>>(
            p16, topk_idx, topk_val, sure_cnt, tie_cnt, cand_col,
            dead_idx, dead_cnt, Ahd, w_dec, Bhd, wd16, 0, 0);
        comboB_kernel<<<BATCH, 512, 0, stream>>>(
            Ahd, Bhd, b_pre, mu, stdv, out1,
            tie_cnt, cand_col, cand_val, xch, xcl, wT, b_enc, 0);
        auxb_kernel<<<dim3(NDEAD / 32, D_MODEL / 32), 256, 0, stream>>>(w_dec, dead_idx, Bhd);
        wdec2bf_kernel<<<(int)(((size_t)D_HIDDEN * D_MODEL) / (256 * 8)), 256, 0, stream>>>(w_dec, wd16);
        mm256_kernel<1><<<(BATCH / 256) * (D_MODEL / 256), 512, 0, stream>>>(
            Ahd, Bhd, NDEAD, BATCH / 256, b_pre, mu, stdv, out1, (long)D_MODEL);
    }
    decode_fin_kernel<<<BATCH, 256, 0, stream>>>(
        sure_cnt, tie_cnt, cand_col, cand_val, topk_idx, topk_val,
        wd16, b_pre, mu, stdv, out0);
}